// Round 4
// baseline (15735.431 us; speedup 1.0000x reference)
//
#include <hip/hip_runtime.h>
#include <cfloat>
#include <climits>
#include <cstdint>
#include <cstddef>

#define ZD    128
#define NQ    256      // 4*64 queries
#define NB    4
#define NT    64
#define KK    100
#define CAP   1024
#define NSAMP 4096
#define RANK  24
#define EPS   3.0f     // rigorous |d_bf16 - d_exact| bound (analysis: <= ~2.2)
#define SLABS 256
#define BKT   24       // per-(q,slab) bucket capacity; E[hits] ~ 2.3
#define TROWS 64
#define QROWS 128
#define LPAD  136      // bf16 row stride (272 B), keeps 16B alignment

typedef __attribute__((ext_vector_type(8))) short  short8;   // 8 bf16 (4 VGPRs)
typedef __attribute__((ext_vector_type(4))) float  floatx4;  // mfma acc
typedef unsigned long long u64;

__device__ inline unsigned short f2bf(float f) {   // RNE fp32 -> bf16
  unsigned u = __builtin_bit_cast(unsigned, f);
  unsigned r = u + 0x7fffu + ((u >> 16) & 1u);
  return (unsigned short)(r >> 16);
}
__device__ inline unsigned fkey(float f) {         // monotone float->uint
  unsigned u = __builtin_bit_cast(unsigned, f);
  unsigned m = (u & 0x80000000u) ? 0xFFFFFFFFu : 0x80000000u;
  return u ^ m;
}
__device__ inline float unfkey(unsigned k) {       // inverse
  unsigned u = (k & 0x80000000u) ? (k ^ 0x80000000u) : ~k;
  return __builtin_bit_cast(float, u);
}

// ---------------------------------------------------------------- k0: norms
__global__ __launch_bounds__(256) void k0_norms(
    const float* __restrict__ Q, const float* __restrict__ T, int M,
    float* __restrict__ qn, float* __restrict__ tn) {
  int gid = blockIdx.x * 256 + threadIdx.x;
  if (gid < M) {
    const float* r = T + (size_t)gid * ZD;
    float s = 0.f;
    #pragma unroll
    for (int z4 = 0; z4 < 32; ++z4) {
      float4 v = *(const float4*)&r[z4 * 4];
      s = fmaf(v.x, v.x, s); s = fmaf(v.y, v.y, s);
      s = fmaf(v.z, v.z, s); s = fmaf(v.w, v.w, s);
    }
    tn[gid] = s;
  } else if (gid < M + NQ) {
    int q = gid - M;
    const float* r = Q + (size_t)q * ZD;
    float s = 0.f;
    #pragma unroll
    for (int z4 = 0; z4 < 32; ++z4) {
      float4 v = *(const float4*)&r[z4 * 4];
      s = fmaf(v.x, v.x, s); s = fmaf(v.y, v.y, s);
      s = fmaf(v.z, v.z, s); s = fmaf(v.w, v.w, s);
    }
    qn[q] = s;
  }
}

// ---------------------------------------------------------------- k1: per-query threshold (heuristic only)
__global__ __launch_bounds__(256) void k1_thresh(
    const float* __restrict__ Q, const float* __restrict__ T, int M,
    const float* __restrict__ qn, const float* __restrict__ tn,
    float* __restrict__ thr) {
  __shared__ float qv[ZD];
  __shared__ float sd[NSAMP];
  __shared__ float red[256];
  __shared__ int   hist[256];
  const int q = blockIdx.x, tid = threadIdx.x;
  for (int z = tid; z < ZD; z += 256) qv[z] = Q[(size_t)q * ZD + z];
  __syncthreads();
  const float qnv = qn[q];
  for (int s = tid; s < NSAMP; s += 256) {
    const float* r = T + (size_t)s * ZD;
    float d0 = 0.f, d1 = 0.f, d2 = 0.f, d3 = 0.f;
    #pragma unroll 8
    for (int z4 = 0; z4 < 32; ++z4) {
      float4 v = *(const float4*)&r[z4 * 4];
      d0 = fmaf(qv[z4 * 4 + 0], v.x, d0);
      d1 = fmaf(qv[z4 * 4 + 1], v.y, d1);
      d2 = fmaf(qv[z4 * 4 + 2], v.z, d2);
      d3 = fmaf(qv[z4 * 4 + 3], v.w, d3);
    }
    float dot = (d0 + d1) + (d2 + d3);
    sd[s] = fmaf(-2.0f, dot, qnv + tn[s]);
  }
  __syncthreads();
  float lm = FLT_MAX;
  for (int s = tid; s < NSAMP; s += 256) lm = fminf(lm, sd[s]);
  red[tid] = lm;
  __syncthreads();
  for (int o = 128; o > 0; o >>= 1) {
    if (tid < o) red[tid] = fminf(red[tid], red[tid + o]);
    __syncthreads();
  }
  const float dmin = red[0];
  hist[tid] = 0;
  __syncthreads();
  for (int s = tid; s < NSAMP; s += 256) {
    int b = (int)((sd[s] - dmin) * 3.2f);     // bin width 0.3125 over [dmin, dmin+80]
    b = b < 0 ? 0 : (b > 255 ? 255 : b);
    atomicAdd(&hist[b], 1);
  }
  __syncthreads();
  if (tid == 0) {
    int cum = 0; float Tq = dmin + 80.0f;
    for (int b = 0; b < 256; ++b) {
      cum += hist[b];
      if (cum >= RANK) { Tq = dmin + (float)(b + 1) * 0.3125f; break; }
    }
    thr[q] = Tq;
  }
}

// ---------------------------------------------------------------- k2: bf16 MFMA filter, slab-bucketed
__global__ __launch_bounds__(256) void k2_mfma(
    const float* __restrict__ Q, const float* __restrict__ T, int M, int slabn,
    const float* __restrict__ qn, const float* __restrict__ tn,
    const float* __restrict__ thr,
    int* __restrict__ cnt2, int* __restrict__ sure2, int* __restrict__ cand) {
  __shared__ short Ts[TROWS * LPAD];
  __shared__ short Qs[QROWS * LPAD];
  __shared__ int   lcnt[QROWS];
  __shared__ int   lsure[QROWS];
  __shared__ int   lent[QROWS * BKT];
  const int tid = threadIdx.x;
  const int slab = blockIdx.x;
  const int qbase = blockIdx.y * QROWS;
  const int sbeg = slab * slabn;
  const int send = min(sbeg + slabn, M);

  #pragma unroll
  for (int it = 0; it < 16; ++it) {
    int li = tid + it * 256;
    int row = li >> 5, z4 = li & 31;
    float4 v = *(const float4*)&Q[(size_t)(qbase + row) * ZD + z4 * 4];
    unsigned lo = (unsigned)f2bf(v.x) | ((unsigned)f2bf(v.y) << 16);
    unsigned hi = (unsigned)f2bf(v.z) | ((unsigned)f2bf(v.w) << 16);
    *(uint2*)&Qs[row * LPAD + z4 * 4] = make_uint2(lo, hi);
  }
  if (tid < QROWS) { lcnt[tid] = 0; lsure[tid] = 0; }

  const int wave = tid >> 6;
  const int lane = tid & 63;
  const int quad = lane >> 4;
  const int n16  = lane & 15;

  for (int m0 = sbeg; m0 < send; m0 += TROWS) {
    __syncthreads();
    #pragma unroll
    for (int it = 0; it < 8; ++it) {
      int li = tid + it * 256;
      int row = li >> 5, z4 = li & 31;
      int m = m0 + row;
      float4 v = make_float4(0.f, 0.f, 0.f, 0.f);
      if (m < send) v = *(const float4*)&T[(size_t)m * ZD + z4 * 4];
      unsigned lo = (unsigned)f2bf(v.x) | ((unsigned)f2bf(v.y) << 16);
      unsigned hi = (unsigned)f2bf(v.z) | ((unsigned)f2bf(v.w) << 16);
      *(uint2*)&Ts[row * LPAD + z4 * 4] = make_uint2(lo, hi);
    }
    __syncthreads();

    floatx4 acc[8];
    #pragma unroll
    for (int qt = 0; qt < 8; ++qt) acc[qt] = (floatx4)0.f;
    #pragma unroll
    for (int ks = 0; ks < 4; ++ks) {
      short8 a = *(const short8*)&Ts[(wave * 16 + n16) * LPAD + ks * 32 + quad * 8];
      #pragma unroll
      for (int qt = 0; qt < 8; ++qt) {
        short8 b = *(const short8*)&Qs[(qt * 16 + n16) * LPAD + ks * 32 + quad * 8];
        acc[qt] = __builtin_amdgcn_mfma_f32_16x16x32_bf16(a, b, acc[qt], 0, 0, 0);
      }
    }

    const int mbase = m0 + wave * 16 + quad * 4;
    float4 tnv = make_float4(0.f, 0.f, 0.f, 0.f);
    if (mbase + 3 < M) tnv = *(const float4*)&tn[mbase];
    else {
      if (mbase + 0 < M) tnv.x = tn[mbase + 0];
      if (mbase + 1 < M) tnv.y = tn[mbase + 1];
      if (mbase + 2 < M) tnv.z = tn[mbase + 2];
    }
    const float tns[4] = {tnv.x, tnv.y, tnv.z, tnv.w};
    #pragma unroll
    for (int qt = 0; qt < 8; ++qt) {
      const int ql = qt * 16 + n16;
      const int q = qbase + ql;
      const float base = qn[q];
      const float Tq = thr[q];
      #pragma unroll
      for (int r = 0; r < 4; ++r) {
        const int m = mbase + r;
        float dap = fmaf(-2.0f, acc[qt][r], base + tns[r]);
        if (m < send && dap < Tq + EPS) {
          int pos = atomicAdd(&lcnt[ql], 1);
          if (pos < BKT) lent[ql * BKT + pos] = m;
          if (dap < Tq - EPS) atomicAdd(&lsure[ql], 1);
        }
      }
    }
  }
  __syncthreads();
  if (tid < QROWS) {
    cnt2 [(size_t)(qbase + tid) * SLABS + slab] = lcnt[tid];
    sure2[(size_t)(qbase + tid) * SLABS + slab] = lsure[tid];
  }
  for (int li = tid; li < QROWS * BKT; li += 256) {
    int ql = li / BKT, j = li % BKT;
    int c = lcnt[ql]; if (c > BKT) c = BKT;
    if (j < c)
      cand[((size_t)(qbase + ql) * SLABS + slab) * BKT + j] = lent[li];
  }
}

// ---------------------------------------------------------------- k3a: per-query slab scan + validity
__global__ __launch_bounds__(256) void k3a_scan(
    const int* __restrict__ cnt2, const int* __restrict__ sure2,
    int* __restrict__ scanx, int* __restrict__ totals, int* __restrict__ validf) {
  const int q = blockIdx.x, tid = threadIdx.x;
  __shared__ int sscan[256];
  __shared__ int ssure, sovf;
  int c = cnt2[(size_t)q * SLABS + tid];
  int su = sure2[(size_t)q * SLABS + tid];
  if (tid == 0) { ssure = 0; sovf = 0; }
  __syncthreads();
  atomicAdd(&ssure, su);
  if (c > BKT) atomicOr(&sovf, 1);
  int val = c;
  sscan[tid] = val;
  __syncthreads();
  for (int o = 1; o < 256; o <<= 1) {
    int add = (tid >= o) ? sscan[tid - o] : 0;
    __syncthreads();
    val += add;
    sscan[tid] = val;
    __syncthreads();
  }
  scanx[(size_t)q * SLABS + tid] = val - c;   // exclusive offset
  const int total = sscan[255];
  if (tid == 0) {
    totals[q] = total;
    validf[q] = (sovf == 0 && ssure >= KK && total <= CAP) ? 1 : 0;
  }
}

// ---------------------------------------------------------------- k3b: parallel exact rescore -> packed keys
__global__ __launch_bounds__(256) void k3b_rescore(
    const float* __restrict__ Q, const float* __restrict__ T,
    const float* __restrict__ qn, const float* __restrict__ tn,
    const int* __restrict__ cnt2, const int* __restrict__ cand,
    const int* __restrict__ scanx, const int* __restrict__ validf,
    u64* __restrict__ keys) {
  const int q = blockIdx.x, ch = blockIdx.y, tid = threadIdx.x;
  if (!validf[q]) return;                  // uniform
  __shared__ float qv[ZD];
  for (int z = tid; z < ZD; z += 256) qv[z] = Q[(size_t)q * ZD + z];
  __syncthreads();
  const float qnv = qn[q];
  const int slab = ch * 64 + (tid >> 2);
  const int lane = tid & 3;
  const int c = min(cnt2[(size_t)q * SLABS + slab], BKT);
  const int off = scanx[(size_t)q * SLABS + slab];
  for (int k = lane; k < c; k += 4) {
    int idx = cand[((size_t)q * SLABS + slab) * BKT + k];
    const float* r = T + (size_t)idx * ZD;
    float dot = 0.f;     // sequential fmaf chain — matches prior passing rescore
    #pragma unroll 4
    for (int z4 = 0; z4 < 32; ++z4) {
      float4 v = *(const float4*)&r[z4 * 4];
      dot = fmaf(qv[z4 * 4 + 0], v.x, dot);
      dot = fmaf(qv[z4 * 4 + 1], v.y, dot);
      dot = fmaf(qv[z4 * 4 + 2], v.z, dot);
      dot = fmaf(qv[z4 * 4 + 3], v.w, dot);
    }
    float d = fmaf(-2.0f, dot, qnv + tn[idx]);
    keys[(size_t)q * CAP + off + k] = ((u64)fkey(d) << 32) | (unsigned)idx;
  }
}

// ---------------------------------------------------------------- k3c: histogram-select + small sort + softmax
__global__ __launch_bounds__(256) void k3c_select(
    const float* __restrict__ Q, const float* __restrict__ T, int M,
    const float* __restrict__ qn, const float* __restrict__ tn,
    const int* __restrict__ totals, const int* __restrict__ validf,
    const u64* __restrict__ keys_g,
    int* __restrict__ topi, float* __restrict__ emit) {
  __shared__ u64 key[CAP];
  __shared__ u64 buf[256];
  __shared__ unsigned redA[256], redB[256];
  __shared__ int hist[256];
  __shared__ int hscan[256];
  __shared__ float qv[ZD];
  __shared__ float cd[256];
  __shared__ float sdF[KK];
  __shared__ int   siF[KK];
  __shared__ float ebuf[KK];
  __shared__ float ssum;
  __shared__ int Bb, C2, ccnt, srcFlag;
  __shared__ unsigned kminS; __shared__ int shiftS;
  const int q = blockIdx.x, tid = threadIdx.x;
  const int total = totals[q];
  const bool valid = validf[q] != 0;

  if (valid) {
    for (int i = tid; i < CAP; i += 256)
      key[i] = (i < total) ? keys_g[(size_t)q * CAP + i] : ~0ULL;
    // min/max of high-32 key over live entries
    unsigned lmin = 0xFFFFFFFFu, lmax = 0u;
    for (int i = tid; i < total; i += 256) {
      unsigned h = (unsigned)(key[i] >> 32);
      lmin = min(lmin, h); lmax = max(lmax, h);
    }
    redA[tid] = lmin; redB[tid] = lmax;
    hist[tid] = 0;
    __syncthreads();
    for (int o = 128; o > 0; o >>= 1) {
      if (tid < o) {
        redA[tid] = min(redA[tid], redA[tid + o]);
        redB[tid] = max(redB[tid], redB[tid + o]);
      }
      __syncthreads();
    }
    if (tid == 0) {
      unsigned range = redB[0] - redA[0];
      int s = 0;
      while ((range >> s) > 255u) ++s;
      kminS = redA[0]; shiftS = s;
      ccnt = 0;
    }
    __syncthreads();
    const unsigned kmin = kminS; const int sh = shiftS;
    for (int i = tid; i < total; i += 256) {
      int b = (int)(((unsigned)(key[i] >> 32) - kmin) >> sh);
      atomicAdd(&hist[b], 1);
    }
    __syncthreads();
    int v0 = hist[tid];
    hscan[tid] = v0;
    __syncthreads();
    for (int o = 1; o < 256; o <<= 1) {
      int add = (tid >= o) ? hscan[tid - o] : 0;
      __syncthreads();
      v0 += add;
      hscan[tid] = v0;
      __syncthreads();
    }
    if (hscan[tid] >= KK && (tid == 0 || hscan[tid - 1] < KK)) {
      Bb = tid; C2 = hscan[tid];
    }
    __syncthreads();
    const int B = Bb, c2 = C2;
    if (c2 <= 256) {
      for (int i = tid; i < total; i += 256) {
        int b = (int)(((unsigned)(key[i] >> 32) - kmin) >> sh);
        if (b <= B) { int pos = atomicAdd(&ccnt, 1); buf[pos] = key[i]; }
      }
      __syncthreads();
      if (tid >= c2) buf[tid] = ~0ULL;
      __syncthreads();
      // bitonic sort of 256 u64, 1 elem/thread
      for (int k = 2; k <= 256; k <<= 1) {
        for (int j = k >> 1; j > 0; j >>= 1) {
          int x = tid ^ j;
          if (x > tid) {
            u64 a = buf[tid], b2 = buf[x];
            bool asc = ((tid & k) == 0);
            if ((a > b2) == asc) { buf[tid] = b2; buf[x] = a; }
          }
          __syncthreads();
        }
      }
      if (tid == 0) srcFlag = 0;
    } else {
      // rare: sort all CAP entries in place
      for (int k = 2; k <= CAP; k <<= 1) {
        for (int j = k >> 1; j > 0; j >>= 1) {
          for (int t = tid; t < CAP; t += 256) {
            int x = t ^ j;
            if (x > t) {
              u64 a = key[t], b2 = key[x];
              bool asc = ((t & k) == 0);
              if ((a > b2) == asc) { key[t] = b2; key[x] = a; }
            }
          }
          __syncthreads();
        }
      }
      if (tid == 0) srcFlag = 1;
    }
    __syncthreads();
  } else {
    // brute-force exact fallback (correctness net; ~never taken)
    for (int z = tid; z < ZD; z += 256) qv[z] = Q[(size_t)q * ZD + z];
    if (tid == 0) {
      for (int k = 0; k < KK; ++k) { sdF[k] = FLT_MAX; siF[k] = INT_MAX; }
      srcFlag = 0;
    }
    __syncthreads();
    const float qnv = qn[q];
    for (int base = 0; base < M; base += 256) {
      int m = base + tid; float d = FLT_MAX;
      if (m < M) {
        const float* r = T + (size_t)m * ZD;
        float dot = 0.f;
        for (int z = 0; z < ZD; ++z) dot = fmaf(qv[z], r[z], dot);
        d = fmaf(-2.0f, dot, qnv + tn[m]);
      }
      cd[tid] = d;
      __syncthreads();
      if (tid == 0) {
        for (int e = 0; e < 256; ++e) {
          float dd = cd[e]; int mm = base + e;
          if (dd < sdF[KK - 1] || (dd == sdF[KK - 1] && mm < siF[KK - 1])) {
            int pos = KK - 1;
            while (pos > 0 && (sdF[pos - 1] > dd || (sdF[pos - 1] == dd && siF[pos - 1] > mm))) {
              sdF[pos] = sdF[pos - 1]; siF[pos] = siF[pos - 1]; --pos;
            }
            sdF[pos] = dd; siF[pos] = mm;
          }
        }
      }
      __syncthreads();
    }
    if (tid < KK) buf[tid] = ((u64)fkey(sdF[tid]) << 32) | (unsigned)siF[tid];
    __syncthreads();
  }

  // epilogue: softmax over sorted top-100 (source: buf or key)
  const int sf = srcFlag;
  if (tid == 0) {
    u64 k0v = sf ? key[0] : buf[0];
    float d0 = unfkey((unsigned)(k0v >> 32));
    float sum = 0.f;
    for (int k = 0; k < KK; ++k) {
      u64 kk = sf ? key[k] : buf[k];
      float e = expf(d0 - unfkey((unsigned)(kk >> 32)));
      ebuf[k] = e; sum += e;
    }
    ssum = sum;
  }
  __syncthreads();
  if (tid < KK) {
    u64 kk = sf ? key[tid] : buf[tid];
    emit[(size_t)q * KK + tid] = ebuf[tid] / ssum;
    topi[(size_t)q * KK + tid] = (int)(kk & 0xFFFFFFFFu);
  }
}

// ---------------------------------------------------------------- k4: transition matrices exp(-d)
__global__ __launch_bounds__(256) void k4_trans(
    const float* __restrict__ T, const int* __restrict__ topi,
    float* __restrict__ trans) {
  const int bt = blockIdx.x;                 // 0..251
  const int b = bt / (NT - 1), t = bt % (NT - 1);
  const int* iA = topi + (size_t)(b * NT + t) * KK;
  const int* iB = topi + (size_t)(b * NT + t + 1) * KK;
  __shared__ float As[KK * 132];
  __shared__ float Bs[20 * 132];
  __shared__ float an[KK];
  __shared__ float bn[20];
  const int tid = threadIdx.x;
  for (int li = tid; li < KK * 32; li += 256) {
    int row = li >> 5, z4 = li & 31;
    float4 v = *(const float4*)&T[(size_t)iA[row] * ZD + z4 * 4];
    *(float4*)&As[row * 132 + z4 * 4] = v;
  }
  __syncthreads();
  if (tid < KK) {
    float s = 0.f;
    for (int z = 0; z < ZD; ++z) s = fmaf(As[tid * 132 + z], As[tid * 132 + z], s);
    an[tid] = s;
  }
  for (int c = 0; c < 5; ++c) {
    __syncthreads();
    for (int li = tid; li < 20 * 32; li += 256) {
      int row = li >> 5, z4 = li & 31;
      float4 v = *(const float4*)&T[(size_t)iB[c * 20 + row] * ZD + z4 * 4];
      *(float4*)&Bs[row * 132 + z4 * 4] = v;
    }
    __syncthreads();
    if (tid < 20) {
      float s = 0.f;
      for (int z = 0; z < ZD; ++z) s = fmaf(Bs[tid * 132 + z], Bs[tid * 132 + z], s);
      bn[tid] = s;
    }
    __syncthreads();
    if (tid < 125) {
      const int i0 = (tid / 5) * 4, j0 = (tid % 5) * 4;
      float acc[16];
      #pragma unroll
      for (int x = 0; x < 16; ++x) acc[x] = 0.f;
      for (int z4 = 0; z4 < 32; ++z4) {
        float4 a[4], bb[4];
        #pragma unroll
        for (int r = 0; r < 4; ++r) a[r] = *(const float4*)&As[(i0 + r) * 132 + z4 * 4];
        #pragma unroll
        for (int s = 0; s < 4; ++s) bb[s] = *(const float4*)&Bs[(j0 + s) * 132 + z4 * 4];
        #pragma unroll
        for (int r = 0; r < 4; ++r) {
          #pragma unroll
          for (int s = 0; s < 4; ++s) {
            acc[r * 4 + s] = fmaf(a[r].x, bb[s].x, acc[r * 4 + s]);
            acc[r * 4 + s] = fmaf(a[r].y, bb[s].y, acc[r * 4 + s]);
            acc[r * 4 + s] = fmaf(a[r].z, bb[s].z, acc[r * 4 + s]);
            acc[r * 4 + s] = fmaf(a[r].w, bb[s].w, acc[r * 4 + s]);
          }
        }
      }
      float* trow = trans + (size_t)bt * KK * KK;
      #pragma unroll
      for (int r = 0; r < 4; ++r)
        for (int s = 0; s < 4; ++s) {
          float d = fmaf(-2.0f, acc[r * 4 + s], an[i0 + r] + bn[j0 + s]);
          trow[(i0 + r) * KK + c * 20 + j0 + s] = expf(-d);
        }
    }
  }
}

// ---------------------------------------------------------------- k5: Viterbi (prefetched trans, LDS backptrs)
__global__ __launch_bounds__(256) void k5_viterbi(
    const float* __restrict__ T, const int* __restrict__ topi,
    const float* __restrict__ emit, const float* __restrict__ trans,
    float* __restrict__ out) {
  const int b = blockIdx.x, tid = threadIdx.x;
  __shared__ float trS[KK * KK];
  __shared__ float v[KK], vn[KK];
  __shared__ float pb[200];
  __shared__ int   pi[200];
  __shared__ int   bpS[(NT - 1) * KK];   // 25.2 KB backptrs in LDS
  __shared__ int   path[NT];
  __shared__ float maxsh;

  // preload tile 0 into registers
  float4 r[10];
  {
    const float* tr0 = trans + (size_t)(b * (NT - 1)) * KK * KK;
    #pragma unroll
    for (int i = 0; i < 10; ++i) {
      int li = tid + i * 256;
      if (li < 2500) r[i] = *(const float4*)&tr0[li * 4];
    }
  }
  if (tid < KK) v[tid] = emit[(size_t)(b * NT) * KK + tid];

  for (int t = 1; t < NT; ++t) {
    // commit prefetched tile (t-1) to LDS
    #pragma unroll
    for (int i = 0; i < 10; ++i) {
      int li = tid + i * 256;
      if (li < 2500) *(float4*)&trS[li * 4] = r[i];
    }
    __syncthreads();
    // issue loads for next tile while computing this one
    if (t < NT - 1) {
      const float* trn = trans + (size_t)(b * (NT - 1) + t) * KK * KK;
      #pragma unroll
      for (int i = 0; i < 10; ++i) {
        int li = tid + i * 256;
        if (li < 2500) r[i] = *(const float4*)&trn[li * 4];
      }
    }
    if (tid < 200) {
      const int j = tid % 100, half = tid / 100;
      const int ia = half * 50, ibnd = ia + 50;
      float best = -FLT_MAX; int bi = ia;
      for (int i = ia; i < ibnd; ++i) {
        float s = v[i] * trS[i * KK + j];
        if (s > best) { best = s; bi = i; }     // strict > == argmax-first
      }
      pb[tid] = best; pi[tid] = bi;
    }
    __syncthreads();
    if (tid < KK) {
      float b0 = pb[tid], b1 = pb[100 + tid];
      int   i0 = pi[tid], i1 = pi[100 + tid];
      float best = b0; int bi = i0;
      if (b1 > b0) { best = b1; bi = i1; }      // half-1 indices all larger
      vn[tid] = best * emit[(size_t)(b * NT + t) * KK + tid];
      bpS[(t - 1) * KK + tid] = bi;
    }
    __syncthreads();
    if (tid == 0) {
      float m = vn[0];
      for (int j = 1; j < KK; ++j) m = fmaxf(m, vn[j]);
      maxsh = m;
    }
    __syncthreads();
    if (tid < KK) v[tid] = vn[tid] / fmaxf(maxsh, 1e-30f);
    __syncthreads();
  }
  if (tid == 0) {
    float best = -FLT_MAX; int last = 0;
    for (int j = 0; j < KK; ++j) if (v[j] > best) { best = v[j]; last = j; }
    path[NT - 1] = last;
    for (int tt = NT - 2; tt >= 0; --tt)
      path[tt] = bpS[tt * KK + path[tt + 1]];
  }
  __syncthreads();
  for (int li = tid; li < NT * ZD; li += 256) {
    int t = li >> 7, z = li & 127;
    out[(size_t)(b * NT + t) * ZD + z] =
        T[(size_t)topi[(size_t)(b * NT + t) * KK + path[t]] * ZD + z];
  }
}

// ---------------------------------------------------------------- host
extern "C" void kernel_launch(void* const* d_in, const int* in_sizes, int n_in,
                              void* d_out, int out_size, void* d_ws, size_t ws_size,
                              hipStream_t stream) {
  const float* Q = (const float*)d_in[0];     // (4,64,128) fp32
  const float* T = (const float*)d_in[1];     // (100000,128) fp32
  float* out = (float*)d_out;                 // (4,64,128) fp32
  const int M = in_sizes[1] / ZD;
  const int slabn = (M + SLABS - 1) / SLABS;  // 391 for M=100000

  char* p = (char*)d_ws;
  auto alloc = [&](size_t bytes) -> char* {
    char* r = p; p += (bytes + 511) & ~(size_t)511; return r;
  };
  float* qn     = (float*)alloc((size_t)NQ * 4);
  float* tn     = (float*)alloc((size_t)M * 4);
  float* thr    = (float*)alloc((size_t)NQ * 4);
  int*   cnt2   = (int*)  alloc((size_t)NQ * SLABS * 4);
  int*   sure2  = (int*)  alloc((size_t)NQ * SLABS * 4);
  int*   cand   = (int*)  alloc((size_t)NQ * SLABS * BKT * 4);
  int*   scanx  = (int*)  alloc((size_t)NQ * SLABS * 4);
  int*   totals = (int*)  alloc((size_t)NQ * 4);
  int*   validf = (int*)  alloc((size_t)NQ * 4);
  u64*   keys   = (u64*)  alloc((size_t)NQ * CAP * 8);
  int*   topi   = (int*)  alloc((size_t)NQ * KK * 4);
  float* emit   = (float*)alloc((size_t)NQ * KK * 4);
  float* trans  = (float*)alloc((size_t)NB * (NT - 1) * KK * KK * 4);

  const int g0 = (M + NQ + 255) / 256;
  k0_norms<<<g0, 256, 0, stream>>>(Q, T, M, qn, tn);
  k1_thresh<<<NQ, 256, 0, stream>>>(Q, T, M, qn, tn, thr);
  dim3 g2(SLABS, NQ / QROWS);
  k2_mfma<<<g2, 256, 0, stream>>>(Q, T, M, slabn, qn, tn, thr, cnt2, sure2, cand);
  k3a_scan<<<NQ, 256, 0, stream>>>(cnt2, sure2, scanx, totals, validf);
  dim3 g3b(NQ, 4);
  k3b_rescore<<<g3b, 256, 0, stream>>>(Q, T, qn, tn, cnt2, cand, scanx, validf, keys);
  k3c_select<<<NQ, 256, 0, stream>>>(Q, T, M, qn, tn, totals, validf, keys, topi, emit);
  k4_trans<<<NB * (NT - 1), 256, 0, stream>>>(T, topi, trans);
  k5_viterbi<<<NB, 256, 0, stream>>>(T, topi, emit, trans, out);
}

// Round 5
// 662.022 us; speedup vs baseline: 23.7687x; 23.7687x over previous
//
#include <hip/hip_runtime.h>
#include <cfloat>
#include <climits>
#include <cstdint>
#include <cstddef>

#define ZD    128
#define NQ    256      // 4*64 queries
#define NB    4
#define NT    64
#define KK    100
#define CAP   2048     // R3-verified: per-query candidate totals stay <= 2048 (1024 was too tight -> fallback storm)
#define NSAMP 4096
#define RANK  24
#define EPS   3.0f     // rigorous |d_bf16 - d_exact| bound (analysis: <= ~2.2)
#define SLABS 256
#define BKT   24       // per-(q,slab) bucket capacity
#define TROWS 64
#define QROWS 128
#define LPAD  136      // bf16 row stride (272 B), keeps 16B alignment

typedef __attribute__((ext_vector_type(8))) short  short8;   // 8 bf16 (4 VGPRs)
typedef __attribute__((ext_vector_type(4))) float  floatx4;  // mfma acc
typedef unsigned long long u64;

__device__ inline unsigned short f2bf(float f) {   // RNE fp32 -> bf16
  unsigned u = __builtin_bit_cast(unsigned, f);
  unsigned r = u + 0x7fffu + ((u >> 16) & 1u);
  return (unsigned short)(r >> 16);
}
__device__ inline unsigned fkey(float f) {         // monotone float->uint
  unsigned u = __builtin_bit_cast(unsigned, f);
  unsigned m = (u & 0x80000000u) ? 0xFFFFFFFFu : 0x80000000u;
  return u ^ m;
}
__device__ inline float unfkey(unsigned k) {       // inverse
  unsigned u = (k & 0x80000000u) ? (k ^ 0x80000000u) : ~k;
  return __builtin_bit_cast(float, u);
}

// ---------------------------------------------------------------- k0: norms
__global__ __launch_bounds__(256) void k0_norms(
    const float* __restrict__ Q, const float* __restrict__ T, int M,
    float* __restrict__ qn, float* __restrict__ tn) {
  int gid = blockIdx.x * 256 + threadIdx.x;
  if (gid < M) {
    const float* r = T + (size_t)gid * ZD;
    float s = 0.f;
    #pragma unroll
    for (int z4 = 0; z4 < 32; ++z4) {
      float4 v = *(const float4*)&r[z4 * 4];
      s = fmaf(v.x, v.x, s); s = fmaf(v.y, v.y, s);
      s = fmaf(v.z, v.z, s); s = fmaf(v.w, v.w, s);
    }
    tn[gid] = s;
  } else if (gid < M + NQ) {
    int q = gid - M;
    const float* r = Q + (size_t)q * ZD;
    float s = 0.f;
    #pragma unroll
    for (int z4 = 0; z4 < 32; ++z4) {
      float4 v = *(const float4*)&r[z4 * 4];
      s = fmaf(v.x, v.x, s); s = fmaf(v.y, v.y, s);
      s = fmaf(v.z, v.z, s); s = fmaf(v.w, v.w, s);
    }
    qn[q] = s;
  }
}

// ---------------------------------------------------------------- k1: per-query threshold (heuristic only)
__global__ __launch_bounds__(256) void k1_thresh(
    const float* __restrict__ Q, const float* __restrict__ T, int M,
    const float* __restrict__ qn, const float* __restrict__ tn,
    float* __restrict__ thr) {
  __shared__ float qv[ZD];
  __shared__ float sd[NSAMP];
  __shared__ float red[256];
  __shared__ int   hist[256];
  const int q = blockIdx.x, tid = threadIdx.x;
  for (int z = tid; z < ZD; z += 256) qv[z] = Q[(size_t)q * ZD + z];
  __syncthreads();
  const float qnv = qn[q];
  for (int s = tid; s < NSAMP; s += 256) {
    const float* r = T + (size_t)s * ZD;
    float d0 = 0.f, d1 = 0.f, d2 = 0.f, d3 = 0.f;
    #pragma unroll 8
    for (int z4 = 0; z4 < 32; ++z4) {
      float4 v = *(const float4*)&r[z4 * 4];
      d0 = fmaf(qv[z4 * 4 + 0], v.x, d0);
      d1 = fmaf(qv[z4 * 4 + 1], v.y, d1);
      d2 = fmaf(qv[z4 * 4 + 2], v.z, d2);
      d3 = fmaf(qv[z4 * 4 + 3], v.w, d3);
    }
    float dot = (d0 + d1) + (d2 + d3);
    sd[s] = fmaf(-2.0f, dot, qnv + tn[s]);
  }
  __syncthreads();
  float lm = FLT_MAX;
  for (int s = tid; s < NSAMP; s += 256) lm = fminf(lm, sd[s]);
  red[tid] = lm;
  __syncthreads();
  for (int o = 128; o > 0; o >>= 1) {
    if (tid < o) red[tid] = fminf(red[tid], red[tid + o]);
    __syncthreads();
  }
  const float dmin = red[0];
  hist[tid] = 0;
  __syncthreads();
  for (int s = tid; s < NSAMP; s += 256) {
    int b = (int)((sd[s] - dmin) * 3.2f);     // bin width 0.3125 over [dmin, dmin+80]
    b = b < 0 ? 0 : (b > 255 ? 255 : b);
    atomicAdd(&hist[b], 1);
  }
  __syncthreads();
  if (tid == 0) {
    int cum = 0; float Tq = dmin + 80.0f;
    for (int b = 0; b < 256; ++b) {
      cum += hist[b];
      if (cum >= RANK) { Tq = dmin + (float)(b + 1) * 0.3125f; break; }
    }
    thr[q] = Tq;
  }
}

// ---------------------------------------------------------------- k2: bf16 MFMA filter, slab-bucketed
__global__ __launch_bounds__(256) void k2_mfma(
    const float* __restrict__ Q, const float* __restrict__ T, int M, int slabn,
    const float* __restrict__ qn, const float* __restrict__ tn,
    const float* __restrict__ thr,
    int* __restrict__ cnt2, int* __restrict__ sure2, int* __restrict__ cand) {
  __shared__ short Ts[TROWS * LPAD];
  __shared__ short Qs[QROWS * LPAD];
  __shared__ int   lcnt[QROWS];
  __shared__ int   lsure[QROWS];
  __shared__ int   lent[QROWS * BKT];
  const int tid = threadIdx.x;
  const int slab = blockIdx.x;
  const int qbase = blockIdx.y * QROWS;
  const int sbeg = slab * slabn;
  const int send = min(sbeg + slabn, M);

  #pragma unroll
  for (int it = 0; it < 16; ++it) {
    int li = tid + it * 256;
    int row = li >> 5, z4 = li & 31;
    float4 v = *(const float4*)&Q[(size_t)(qbase + row) * ZD + z4 * 4];
    unsigned lo = (unsigned)f2bf(v.x) | ((unsigned)f2bf(v.y) << 16);
    unsigned hi = (unsigned)f2bf(v.z) | ((unsigned)f2bf(v.w) << 16);
    *(uint2*)&Qs[row * LPAD + z4 * 4] = make_uint2(lo, hi);
  }
  if (tid < QROWS) { lcnt[tid] = 0; lsure[tid] = 0; }

  const int wave = tid >> 6;
  const int lane = tid & 63;
  const int quad = lane >> 4;
  const int n16  = lane & 15;

  for (int m0 = sbeg; m0 < send; m0 += TROWS) {
    __syncthreads();
    #pragma unroll
    for (int it = 0; it < 8; ++it) {
      int li = tid + it * 256;
      int row = li >> 5, z4 = li & 31;
      int m = m0 + row;
      float4 v = make_float4(0.f, 0.f, 0.f, 0.f);
      if (m < send) v = *(const float4*)&T[(size_t)m * ZD + z4 * 4];
      unsigned lo = (unsigned)f2bf(v.x) | ((unsigned)f2bf(v.y) << 16);
      unsigned hi = (unsigned)f2bf(v.z) | ((unsigned)f2bf(v.w) << 16);
      *(uint2*)&Ts[row * LPAD + z4 * 4] = make_uint2(lo, hi);
    }
    __syncthreads();

    floatx4 acc[8];
    #pragma unroll
    for (int qt = 0; qt < 8; ++qt) acc[qt] = (floatx4)0.f;
    #pragma unroll
    for (int ks = 0; ks < 4; ++ks) {
      short8 a = *(const short8*)&Ts[(wave * 16 + n16) * LPAD + ks * 32 + quad * 8];
      #pragma unroll
      for (int qt = 0; qt < 8; ++qt) {
        short8 b = *(const short8*)&Qs[(qt * 16 + n16) * LPAD + ks * 32 + quad * 8];
        acc[qt] = __builtin_amdgcn_mfma_f32_16x16x32_bf16(a, b, acc[qt], 0, 0, 0);
      }
    }

    const int mbase = m0 + wave * 16 + quad * 4;
    float4 tnv = make_float4(0.f, 0.f, 0.f, 0.f);
    if (mbase + 3 < M) tnv = *(const float4*)&tn[mbase];
    else {
      if (mbase + 0 < M) tnv.x = tn[mbase + 0];
      if (mbase + 1 < M) tnv.y = tn[mbase + 1];
      if (mbase + 2 < M) tnv.z = tn[mbase + 2];
    }
    const float tns[4] = {tnv.x, tnv.y, tnv.z, tnv.w};
    #pragma unroll
    for (int qt = 0; qt < 8; ++qt) {
      const int ql = qt * 16 + n16;
      const int q = qbase + ql;
      const float base = qn[q];
      const float Tq = thr[q];
      #pragma unroll
      for (int r = 0; r < 4; ++r) {
        const int m = mbase + r;
        float dap = fmaf(-2.0f, acc[qt][r], base + tns[r]);
        if (m < send && dap < Tq + EPS) {
          int pos = atomicAdd(&lcnt[ql], 1);
          if (pos < BKT) lent[ql * BKT + pos] = m;
          if (dap < Tq - EPS) atomicAdd(&lsure[ql], 1);
        }
      }
    }
  }
  __syncthreads();
  if (tid < QROWS) {
    cnt2 [(size_t)(qbase + tid) * SLABS + slab] = lcnt[tid];
    sure2[(size_t)(qbase + tid) * SLABS + slab] = lsure[tid];
  }
  for (int li = tid; li < QROWS * BKT; li += 256) {
    int ql = li / BKT, j = li % BKT;
    int c = lcnt[ql]; if (c > BKT) c = BKT;
    if (j < c)
      cand[((size_t)(qbase + ql) * SLABS + slab) * BKT + j] = lent[li];
  }
}

// ---------------------------------------------------------------- k3a: per-query slab scan + validity
__global__ __launch_bounds__(256) void k3a_scan(
    const int* __restrict__ cnt2, const int* __restrict__ sure2,
    int* __restrict__ scanx, int* __restrict__ totals, int* __restrict__ validf) {
  const int q = blockIdx.x, tid = threadIdx.x;
  __shared__ int sscan[256];
  __shared__ int ssure, sovf;
  int c = cnt2[(size_t)q * SLABS + tid];
  int su = sure2[(size_t)q * SLABS + tid];
  if (tid == 0) { ssure = 0; sovf = 0; }
  __syncthreads();
  atomicAdd(&ssure, su);
  if (c > BKT) atomicOr(&sovf, 1);
  int val = c;
  sscan[tid] = val;
  __syncthreads();
  for (int o = 1; o < 256; o <<= 1) {
    int add = (tid >= o) ? sscan[tid - o] : 0;
    __syncthreads();
    val += add;
    sscan[tid] = val;
    __syncthreads();
  }
  scanx[(size_t)q * SLABS + tid] = val - c;   // exclusive offset
  const int total = sscan[255];
  if (tid == 0) {
    totals[q] = total;
    validf[q] = (sovf == 0 && ssure >= KK && total <= CAP) ? 1 : 0;
  }
}

// ---------------------------------------------------------------- k3b: parallel exact rescore -> packed keys
__global__ __launch_bounds__(256) void k3b_rescore(
    const float* __restrict__ Q, const float* __restrict__ T,
    const float* __restrict__ qn, const float* __restrict__ tn,
    const int* __restrict__ cnt2, const int* __restrict__ cand,
    const int* __restrict__ scanx, const int* __restrict__ validf,
    u64* __restrict__ keys) {
  const int q = blockIdx.x, ch = blockIdx.y, tid = threadIdx.x;
  if (!validf[q]) return;                  // uniform
  __shared__ float qv[ZD];
  for (int z = tid; z < ZD; z += 256) qv[z] = Q[(size_t)q * ZD + z];
  __syncthreads();
  const float qnv = qn[q];
  const int slab = ch * 64 + (tid >> 2);
  const int lane = tid & 3;
  const int c = min(cnt2[(size_t)q * SLABS + slab], BKT);
  const int off = scanx[(size_t)q * SLABS + slab];
  for (int k = lane; k < c; k += 4) {
    int idx = cand[((size_t)q * SLABS + slab) * BKT + k];
    const float* r = T + (size_t)idx * ZD;
    float dot = 0.f;     // sequential fmaf chain — matches prior passing rescore
    #pragma unroll 4
    for (int z4 = 0; z4 < 32; ++z4) {
      float4 v = *(const float4*)&r[z4 * 4];
      dot = fmaf(qv[z4 * 4 + 0], v.x, dot);
      dot = fmaf(qv[z4 * 4 + 1], v.y, dot);
      dot = fmaf(qv[z4 * 4 + 2], v.z, dot);
      dot = fmaf(qv[z4 * 4 + 3], v.w, dot);
    }
    float d = fmaf(-2.0f, dot, qnv + tn[idx]);
    keys[(size_t)q * CAP + off + k] = ((u64)fkey(d) << 32) | (unsigned)idx;
  }
}

// ---------------------------------------------------------------- k3c: histogram-select + small sort + softmax
__global__ __launch_bounds__(256) void k3c_select(
    const float* __restrict__ Q, const float* __restrict__ T, int M,
    const float* __restrict__ qn, const float* __restrict__ tn,
    const int* __restrict__ totals, const int* __restrict__ validf,
    const u64* __restrict__ keys_g,
    int* __restrict__ topi, float* __restrict__ emit) {
  __shared__ u64 key[CAP];
  __shared__ u64 buf[256];
  __shared__ unsigned redA[256], redB[256];
  __shared__ int hist[256];
  __shared__ int hscan[256];
  __shared__ float qv[ZD];
  __shared__ float cd[256];
  __shared__ float sdF[KK];
  __shared__ int   siF[KK];
  __shared__ float ebuf[KK];
  __shared__ float ssum;
  __shared__ int Bb, C2, ccnt, srcFlag;
  __shared__ unsigned kminS; __shared__ int shiftS;
  const int q = blockIdx.x, tid = threadIdx.x;
  const int total = totals[q];
  const bool valid = validf[q] != 0;

  if (valid) {
    for (int i = tid; i < CAP; i += 256)
      key[i] = (i < total) ? keys_g[(size_t)q * CAP + i] : ~0ULL;
    unsigned lmin = 0xFFFFFFFFu, lmax = 0u;
    for (int i = tid; i < total; i += 256) {
      unsigned h = (unsigned)(key[i] >> 32);
      lmin = min(lmin, h); lmax = max(lmax, h);
    }
    redA[tid] = lmin; redB[tid] = lmax;
    hist[tid] = 0;
    __syncthreads();
    for (int o = 128; o > 0; o >>= 1) {
      if (tid < o) {
        redA[tid] = min(redA[tid], redA[tid + o]);
        redB[tid] = max(redB[tid], redB[tid + o]);
      }
      __syncthreads();
    }
    if (tid == 0) {
      unsigned range = redB[0] - redA[0];
      int s = 0;
      while ((range >> s) > 255u) ++s;
      kminS = redA[0]; shiftS = s;
      ccnt = 0;
    }
    __syncthreads();
    const unsigned kmin = kminS; const int sh = shiftS;
    for (int i = tid; i < total; i += 256) {
      int b = (int)(((unsigned)(key[i] >> 32) - kmin) >> sh);
      atomicAdd(&hist[b], 1);
    }
    __syncthreads();
    int v0 = hist[tid];
    hscan[tid] = v0;
    __syncthreads();
    for (int o = 1; o < 256; o <<= 1) {
      int add = (tid >= o) ? hscan[tid - o] : 0;
      __syncthreads();
      v0 += add;
      hscan[tid] = v0;
      __syncthreads();
    }
    if (hscan[tid] >= KK && (tid == 0 || hscan[tid - 1] < KK)) {
      Bb = tid; C2 = hscan[tid];
    }
    __syncthreads();
    const int B = Bb, c2 = C2;
    if (c2 <= 256) {
      for (int i = tid; i < total; i += 256) {
        int b = (int)(((unsigned)(key[i] >> 32) - kmin) >> sh);
        if (b <= B) { int pos = atomicAdd(&ccnt, 1); buf[pos] = key[i]; }
      }
      __syncthreads();
      if (tid >= c2) buf[tid] = ~0ULL;
      __syncthreads();
      for (int k = 2; k <= 256; k <<= 1) {
        for (int j = k >> 1; j > 0; j >>= 1) {
          int x = tid ^ j;
          if (x > tid) {
            u64 a = buf[tid], b2 = buf[x];
            bool asc = ((tid & k) == 0);
            if ((a > b2) == asc) { buf[tid] = b2; buf[x] = a; }
          }
          __syncthreads();
        }
      }
      if (tid == 0) srcFlag = 0;
    } else {
      for (int k = 2; k <= CAP; k <<= 1) {
        for (int j = k >> 1; j > 0; j >>= 1) {
          for (int t = tid; t < CAP; t += 256) {
            int x = t ^ j;
            if (x > t) {
              u64 a = key[t], b2 = key[x];
              bool asc = ((t & k) == 0);
              if ((a > b2) == asc) { key[t] = b2; key[x] = a; }
            }
          }
          __syncthreads();
        }
      }
      if (tid == 0) srcFlag = 1;
    }
    __syncthreads();
  } else {
    // brute-force exact fallback (correctness net; ~never taken)
    for (int z = tid; z < ZD; z += 256) qv[z] = Q[(size_t)q * ZD + z];
    if (tid == 0) {
      for (int k = 0; k < KK; ++k) { sdF[k] = FLT_MAX; siF[k] = INT_MAX; }
      srcFlag = 0;
    }
    __syncthreads();
    const float qnv = qn[q];
    for (int base = 0; base < M; base += 256) {
      int m = base + tid; float d = FLT_MAX;
      if (m < M) {
        const float* r = T + (size_t)m * ZD;
        float dot = 0.f;
        for (int z = 0; z < ZD; ++z) dot = fmaf(qv[z], r[z], dot);
        d = fmaf(-2.0f, dot, qnv + tn[m]);
      }
      cd[tid] = d;
      __syncthreads();
      if (tid == 0) {
        for (int e = 0; e < 256; ++e) {
          float dd = cd[e]; int mm = base + e;
          if (dd < sdF[KK - 1] || (dd == sdF[KK - 1] && mm < siF[KK - 1])) {
            int pos = KK - 1;
            while (pos > 0 && (sdF[pos - 1] > dd || (sdF[pos - 1] == dd && siF[pos - 1] > mm))) {
              sdF[pos] = sdF[pos - 1]; siF[pos] = siF[pos - 1]; --pos;
            }
            sdF[pos] = dd; siF[pos] = mm;
          }
        }
      }
      __syncthreads();
    }
    if (tid < KK) buf[tid] = ((u64)fkey(sdF[tid]) << 32) | (unsigned)siF[tid];
    __syncthreads();
  }

  const int sf = srcFlag;
  if (tid == 0) {
    u64 k0v = sf ? key[0] : buf[0];
    float d0 = unfkey((unsigned)(k0v >> 32));
    float sum = 0.f;
    for (int k = 0; k < KK; ++k) {
      u64 kk = sf ? key[k] : buf[k];
      float e = expf(d0 - unfkey((unsigned)(kk >> 32)));
      ebuf[k] = e; sum += e;
    }
    ssum = sum;
  }
  __syncthreads();
  if (tid < KK) {
    u64 kk = sf ? key[tid] : buf[tid];
    emit[(size_t)q * KK + tid] = ebuf[tid] / ssum;
    topi[(size_t)q * KK + tid] = (int)(kk & 0xFFFFFFFFu);
  }
}

// ---------------------------------------------------------------- k4: transition matrices exp(-d)
__global__ __launch_bounds__(256) void k4_trans(
    const float* __restrict__ T, const int* __restrict__ topi,
    float* __restrict__ trans) {
  const int bt = blockIdx.x;                 // 0..251
  const int b = bt / (NT - 1), t = bt % (NT - 1);
  const int* iA = topi + (size_t)(b * NT + t) * KK;
  const int* iB = topi + (size_t)(b * NT + t + 1) * KK;
  __shared__ float As[KK * 132];
  __shared__ float Bs[20 * 132];
  __shared__ float an[KK];
  __shared__ float bn[20];
  const int tid = threadIdx.x;
  for (int li = tid; li < KK * 32; li += 256) {
    int row = li >> 5, z4 = li & 31;
    float4 v = *(const float4*)&T[(size_t)iA[row] * ZD + z4 * 4];
    *(float4*)&As[row * 132 + z4 * 4] = v;
  }
  __syncthreads();
  if (tid < KK) {
    float s = 0.f;
    for (int z = 0; z < ZD; ++z) s = fmaf(As[tid * 132 + z], As[tid * 132 + z], s);
    an[tid] = s;
  }
  for (int c = 0; c < 5; ++c) {
    __syncthreads();
    for (int li = tid; li < 20 * 32; li += 256) {
      int row = li >> 5, z4 = li & 31;
      float4 v = *(const float4*)&T[(size_t)iB[c * 20 + row] * ZD + z4 * 4];
      *(float4*)&Bs[row * 132 + z4 * 4] = v;
    }
    __syncthreads();
    if (tid < 20) {
      float s = 0.f;
      for (int z = 0; z < ZD; ++z) s = fmaf(Bs[tid * 132 + z], Bs[tid * 132 + z], s);
      bn[tid] = s;
    }
    __syncthreads();
    if (tid < 125) {
      const int i0 = (tid / 5) * 4, j0 = (tid % 5) * 4;
      float acc[16];
      #pragma unroll
      for (int x = 0; x < 16; ++x) acc[x] = 0.f;
      for (int z4 = 0; z4 < 32; ++z4) {
        float4 a[4], bb[4];
        #pragma unroll
        for (int r = 0; r < 4; ++r) a[r] = *(const float4*)&As[(i0 + r) * 132 + z4 * 4];
        #pragma unroll
        for (int s = 0; s < 4; ++s) bb[s] = *(const float4*)&Bs[(j0 + s) * 132 + z4 * 4];
        #pragma unroll
        for (int r = 0; r < 4; ++r) {
          #pragma unroll
          for (int s = 0; s < 4; ++s) {
            acc[r * 4 + s] = fmaf(a[r].x, bb[s].x, acc[r * 4 + s]);
            acc[r * 4 + s] = fmaf(a[r].y, bb[s].y, acc[r * 4 + s]);
            acc[r * 4 + s] = fmaf(a[r].z, bb[s].z, acc[r * 4 + s]);
            acc[r * 4 + s] = fmaf(a[r].w, bb[s].w, acc[r * 4 + s]);
          }
        }
      }
      float* trow = trans + (size_t)bt * KK * KK;
      #pragma unroll
      for (int r = 0; r < 4; ++r)
        for (int s = 0; s < 4; ++s) {
          float d = fmaf(-2.0f, acc[r * 4 + s], an[i0 + r] + bn[j0 + s]);
          trow[(i0 + r) * KK + c * 20 + j0 + s] = expf(-d);
        }
    }
  }
}

// ---------------------------------------------------------------- k5: Viterbi (prefetched trans, LDS backptrs)
__global__ __launch_bounds__(256) void k5_viterbi(
    const float* __restrict__ T, const int* __restrict__ topi,
    const float* __restrict__ emit, const float* __restrict__ trans,
    float* __restrict__ out) {
  const int b = blockIdx.x, tid = threadIdx.x;
  __shared__ float trS[KK * KK];
  __shared__ float v[KK], vn[KK];
  __shared__ float pb[200];
  __shared__ int   pi[200];
  __shared__ int   bpS[(NT - 1) * KK];   // 25.2 KB backptrs in LDS
  __shared__ int   path[NT];
  __shared__ float maxsh;

  float4 r[10];
  {
    const float* tr0 = trans + (size_t)(b * (NT - 1)) * KK * KK;
    #pragma unroll
    for (int i = 0; i < 10; ++i) {
      int li = tid + i * 256;
      if (li < 2500) r[i] = *(const float4*)&tr0[li * 4];
    }
  }
  if (tid < KK) v[tid] = emit[(size_t)(b * NT) * KK + tid];

  for (int t = 1; t < NT; ++t) {
    #pragma unroll
    for (int i = 0; i < 10; ++i) {
      int li = tid + i * 256;
      if (li < 2500) *(float4*)&trS[li * 4] = r[i];
    }
    __syncthreads();
    if (t < NT - 1) {
      const float* trn = trans + (size_t)(b * (NT - 1) + t) * KK * KK;
      #pragma unroll
      for (int i = 0; i < 10; ++i) {
        int li = tid + i * 256;
        if (li < 2500) r[i] = *(const float4*)&trn[li * 4];
      }
    }
    if (tid < 200) {
      const int j = tid % 100, half = tid / 100;
      const int ia = half * 50, ibnd = ia + 50;
      float best = -FLT_MAX; int bi = ia;
      for (int i = ia; i < ibnd; ++i) {
        float s = v[i] * trS[i * KK + j];
        if (s > best) { best = s; bi = i; }     // strict > == argmax-first
      }
      pb[tid] = best; pi[tid] = bi;
    }
    __syncthreads();
    if (tid < KK) {
      float b0 = pb[tid], b1 = pb[100 + tid];
      int   i0 = pi[tid], i1 = pi[100 + tid];
      float best = b0; int bi = i0;
      if (b1 > b0) { best = b1; bi = i1; }      // half-1 indices all larger
      vn[tid] = best * emit[(size_t)(b * NT + t) * KK + tid];
      bpS[(t - 1) * KK + tid] = bi;
    }
    __syncthreads();
    if (tid == 0) {
      float m = vn[0];
      for (int j = 1; j < KK; ++j) m = fmaxf(m, vn[j]);
      maxsh = m;
    }
    __syncthreads();
    if (tid < KK) v[tid] = vn[tid] / fmaxf(maxsh, 1e-30f);
    __syncthreads();
  }
  if (tid == 0) {
    float best = -FLT_MAX; int last = 0;
    for (int j = 0; j < KK; ++j) if (v[j] > best) { best = v[j]; last = j; }
    path[NT - 1] = last;
    for (int tt = NT - 2; tt >= 0; --tt)
      path[tt] = bpS[tt * KK + path[tt + 1]];
  }
  __syncthreads();
  for (int li = tid; li < NT * ZD; li += 256) {
    int t = li >> 7, z = li & 127;
    out[(size_t)(b * NT + t) * ZD + z] =
        T[(size_t)topi[(size_t)(b * NT + t) * KK + path[t]] * ZD + z];
  }
}

// ---------------------------------------------------------------- host
extern "C" void kernel_launch(void* const* d_in, const int* in_sizes, int n_in,
                              void* d_out, int out_size, void* d_ws, size_t ws_size,
                              hipStream_t stream) {
  const float* Q = (const float*)d_in[0];     // (4,64,128) fp32
  const float* T = (const float*)d_in[1];     // (100000,128) fp32
  float* out = (float*)d_out;                 // (4,64,128) fp32
  const int M = in_sizes[1] / ZD;
  const int slabn = (M + SLABS - 1) / SLABS;  // 391 for M=100000

  char* p = (char*)d_ws;
  auto alloc = [&](size_t bytes) -> char* {
    char* r = p; p += (bytes + 511) & ~(size_t)511; return r;
  };
  float* qn     = (float*)alloc((size_t)NQ * 4);
  float* tn     = (float*)alloc((size_t)M * 4);
  float* thr    = (float*)alloc((size_t)NQ * 4);
  int*   cnt2   = (int*)  alloc((size_t)NQ * SLABS * 4);
  int*   sure2  = (int*)  alloc((size_t)NQ * SLABS * 4);
  int*   cand   = (int*)  alloc((size_t)NQ * SLABS * BKT * 4);
  int*   scanx  = (int*)  alloc((size_t)NQ * SLABS * 4);
  int*   totals = (int*)  alloc((size_t)NQ * 4);
  int*   validf = (int*)  alloc((size_t)NQ * 4);
  u64*   keys   = (u64*)  alloc((size_t)NQ * CAP * 8);
  int*   topi   = (int*)  alloc((size_t)NQ * KK * 4);
  float* emit   = (float*)alloc((size_t)NQ * KK * 4);
  float* trans  = (float*)alloc((size_t)NB * (NT - 1) * KK * KK * 4);

  const int g0 = (M + NQ + 255) / 256;
  k0_norms<<<g0, 256, 0, stream>>>(Q, T, M, qn, tn);
  k1_thresh<<<NQ, 256, 0, stream>>>(Q, T, M, qn, tn, thr);
  dim3 g2(SLABS, NQ / QROWS);
  k2_mfma<<<g2, 256, 0, stream>>>(Q, T, M, slabn, qn, tn, thr, cnt2, sure2, cand);
  k3a_scan<<<NQ, 256, 0, stream>>>(cnt2, sure2, scanx, totals, validf);
  dim3 g3b(NQ, 4);
  k3b_rescore<<<g3b, 256, 0, stream>>>(Q, T, qn, tn, cnt2, cand, scanx, validf, keys);
  k3c_select<<<NQ, 256, 0, stream>>>(Q, T, M, qn, tn, totals, validf, keys, topi, emit);
  k4_trans<<<NB * (NT - 1), 256, 0, stream>>>(T, topi, trans);
  k5_viterbi<<<NB, 256, 0, stream>>>(T, topi, emit, trans, out);
}

// Round 6
// 338.231 us; speedup vs baseline: 46.5228x; 1.9573x over previous
//
#include <hip/hip_runtime.h>
#include <cfloat>
#include <climits>
#include <cstdint>
#include <cstddef>

#define ZD    128
#define NQ    256      // 4*64 queries
#define NB    4
#define NT    64
#define KK    100
#define CAP   2048     // R3-verified: per-query candidate totals stay <= 2048
#define NSAMP 4096
#define RANK  24
#define EPS   3.0f     // rigorous |d_bf16 - d_exact| bound (analysis: <= ~2.2)
#define SLABS 256
#define BKT   24       // per-(q,slab) bucket capacity
#define TROWS 64
#define QROWS 128
#define LPAD  136      // bf16 row stride (272 B), keeps 16B alignment

typedef __attribute__((ext_vector_type(8))) short  short8;   // 8 bf16 (4 VGPRs)
typedef __attribute__((ext_vector_type(4))) float  floatx4;  // mfma acc
typedef unsigned long long u64;

__device__ inline unsigned short f2bf(float f) {   // RNE fp32 -> bf16
  unsigned u = __builtin_bit_cast(unsigned, f);
  unsigned r = u + 0x7fffu + ((u >> 16) & 1u);
  return (unsigned short)(r >> 16);
}
__device__ inline unsigned fkey(float f) {         // monotone float->uint
  unsigned u = __builtin_bit_cast(unsigned, f);
  unsigned m = (u & 0x80000000u) ? 0xFFFFFFFFu : 0x80000000u;
  return u ^ m;
}
__device__ inline float unfkey(unsigned k) {       // inverse
  unsigned u = (k & 0x80000000u) ? (k ^ 0x80000000u) : ~k;
  return __builtin_bit_cast(float, u);
}

// ---------------------------------------------------------------- k0: norms
__global__ __launch_bounds__(256) void k0_norms(
    const float* __restrict__ Q, const float* __restrict__ T, int M,
    float* __restrict__ qn, float* __restrict__ tn) {
  int gid = blockIdx.x * 256 + threadIdx.x;
  if (gid < M) {
    const float* r = T + (size_t)gid * ZD;
    float s = 0.f;
    #pragma unroll
    for (int z4 = 0; z4 < 32; ++z4) {
      float4 v = *(const float4*)&r[z4 * 4];
      s = fmaf(v.x, v.x, s); s = fmaf(v.y, v.y, s);
      s = fmaf(v.z, v.z, s); s = fmaf(v.w, v.w, s);
    }
    tn[gid] = s;
  } else if (gid < M + NQ) {
    int q = gid - M;
    const float* r = Q + (size_t)q * ZD;
    float s = 0.f;
    #pragma unroll
    for (int z4 = 0; z4 < 32; ++z4) {
      float4 v = *(const float4*)&r[z4 * 4];
      s = fmaf(v.x, v.x, s); s = fmaf(v.y, v.y, s);
      s = fmaf(v.z, v.z, s); s = fmaf(v.w, v.w, s);
    }
    qn[q] = s;
  }
}

// ---------------------------------------------------------------- k1: per-query threshold (heuristic only)
__global__ __launch_bounds__(256) void k1_thresh(
    const float* __restrict__ Q, const float* __restrict__ T, int M,
    const float* __restrict__ qn, const float* __restrict__ tn,
    float* __restrict__ thr) {
  __shared__ float qv[ZD];
  __shared__ float sd[NSAMP];
  __shared__ float red[256];
  __shared__ int   hist[256];
  const int q = blockIdx.x, tid = threadIdx.x;
  for (int z = tid; z < ZD; z += 256) qv[z] = Q[(size_t)q * ZD + z];
  __syncthreads();
  const float qnv = qn[q];
  for (int s = tid; s < NSAMP; s += 256) {
    const float* r = T + (size_t)s * ZD;
    float d0 = 0.f, d1 = 0.f, d2 = 0.f, d3 = 0.f;
    #pragma unroll 8
    for (int z4 = 0; z4 < 32; ++z4) {
      float4 v = *(const float4*)&r[z4 * 4];
      d0 = fmaf(qv[z4 * 4 + 0], v.x, d0);
      d1 = fmaf(qv[z4 * 4 + 1], v.y, d1);
      d2 = fmaf(qv[z4 * 4 + 2], v.z, d2);
      d3 = fmaf(qv[z4 * 4 + 3], v.w, d3);
    }
    float dot = (d0 + d1) + (d2 + d3);
    sd[s] = fmaf(-2.0f, dot, qnv + tn[s]);
  }
  __syncthreads();
  float lm = FLT_MAX;
  for (int s = tid; s < NSAMP; s += 256) lm = fminf(lm, sd[s]);
  red[tid] = lm;
  __syncthreads();
  for (int o = 128; o > 0; o >>= 1) {
    if (tid < o) red[tid] = fminf(red[tid], red[tid + o]);
    __syncthreads();
  }
  const float dmin = red[0];
  hist[tid] = 0;
  __syncthreads();
  for (int s = tid; s < NSAMP; s += 256) {
    int b = (int)((sd[s] - dmin) * 3.2f);     // bin width 0.3125 over [dmin, dmin+80]
    b = b < 0 ? 0 : (b > 255 ? 255 : b);
    atomicAdd(&hist[b], 1);
  }
  __syncthreads();
  if (tid == 0) {
    int cum = 0; float Tq = dmin + 80.0f;
    for (int b = 0; b < 256; ++b) {
      cum += hist[b];
      if (cum >= RANK) { Tq = dmin + (float)(b + 1) * 0.3125f; break; }
    }
    thr[q] = Tq;
  }
}

// ---------------------------------------------------------------- k2: bf16 MFMA filter, slab-bucketed
__global__ __launch_bounds__(256) void k2_mfma(
    const float* __restrict__ Q, const float* __restrict__ T, int M, int slabn,
    const float* __restrict__ qn, const float* __restrict__ tn,
    const float* __restrict__ thr,
    int* __restrict__ cnt2, int* __restrict__ sure2, int* __restrict__ cand) {
  __shared__ short Ts[TROWS * LPAD];
  __shared__ short Qs[QROWS * LPAD];
  __shared__ int   lcnt[QROWS];
  __shared__ int   lsure[QROWS];
  __shared__ int   lent[QROWS * BKT];
  const int tid = threadIdx.x;
  const int slab = blockIdx.x;
  const int qbase = blockIdx.y * QROWS;
  const int sbeg = slab * slabn;
  const int send = min(sbeg + slabn, M);

  #pragma unroll
  for (int it = 0; it < 16; ++it) {
    int li = tid + it * 256;
    int row = li >> 5, z4 = li & 31;
    float4 v = *(const float4*)&Q[(size_t)(qbase + row) * ZD + z4 * 4];
    unsigned lo = (unsigned)f2bf(v.x) | ((unsigned)f2bf(v.y) << 16);
    unsigned hi = (unsigned)f2bf(v.z) | ((unsigned)f2bf(v.w) << 16);
    *(uint2*)&Qs[row * LPAD + z4 * 4] = make_uint2(lo, hi);
  }
  if (tid < QROWS) { lcnt[tid] = 0; lsure[tid] = 0; }

  const int wave = tid >> 6;
  const int lane = tid & 63;
  const int quad = lane >> 4;
  const int n16  = lane & 15;

  for (int m0 = sbeg; m0 < send; m0 += TROWS) {
    __syncthreads();
    #pragma unroll
    for (int it = 0; it < 8; ++it) {
      int li = tid + it * 256;
      int row = li >> 5, z4 = li & 31;
      int m = m0 + row;
      float4 v = make_float4(0.f, 0.f, 0.f, 0.f);
      if (m < send) v = *(const float4*)&T[(size_t)m * ZD + z4 * 4];
      unsigned lo = (unsigned)f2bf(v.x) | ((unsigned)f2bf(v.y) << 16);
      unsigned hi = (unsigned)f2bf(v.z) | ((unsigned)f2bf(v.w) << 16);
      *(uint2*)&Ts[row * LPAD + z4 * 4] = make_uint2(lo, hi);
    }
    __syncthreads();

    floatx4 acc[8];
    #pragma unroll
    for (int qt = 0; qt < 8; ++qt) acc[qt] = (floatx4)0.f;
    #pragma unroll
    for (int ks = 0; ks < 4; ++ks) {
      short8 a = *(const short8*)&Ts[(wave * 16 + n16) * LPAD + ks * 32 + quad * 8];
      #pragma unroll
      for (int qt = 0; qt < 8; ++qt) {
        short8 b = *(const short8*)&Qs[(qt * 16 + n16) * LPAD + ks * 32 + quad * 8];
        acc[qt] = __builtin_amdgcn_mfma_f32_16x16x32_bf16(a, b, acc[qt], 0, 0, 0);
      }
    }

    const int mbase = m0 + wave * 16 + quad * 4;
    float4 tnv = make_float4(0.f, 0.f, 0.f, 0.f);
    if (mbase + 3 < M) tnv = *(const float4*)&tn[mbase];
    else {
      if (mbase + 0 < M) tnv.x = tn[mbase + 0];
      if (mbase + 1 < M) tnv.y = tn[mbase + 1];
      if (mbase + 2 < M) tnv.z = tn[mbase + 2];
    }
    const float tns[4] = {tnv.x, tnv.y, tnv.z, tnv.w};
    #pragma unroll
    for (int qt = 0; qt < 8; ++qt) {
      const int ql = qt * 16 + n16;
      const int q = qbase + ql;
      const float base = qn[q];
      const float Tq = thr[q];
      #pragma unroll
      for (int r = 0; r < 4; ++r) {
        const int m = mbase + r;
        float dap = fmaf(-2.0f, acc[qt][r], base + tns[r]);
        if (m < send && dap < Tq + EPS) {
          int pos = atomicAdd(&lcnt[ql], 1);
          if (pos < BKT) lent[ql * BKT + pos] = m;
          if (dap < Tq - EPS) atomicAdd(&lsure[ql], 1);
        }
      }
    }
  }
  __syncthreads();
  if (tid < QROWS) {
    cnt2 [(size_t)(qbase + tid) * SLABS + slab] = lcnt[tid];
    sure2[(size_t)(qbase + tid) * SLABS + slab] = lsure[tid];
  }
  for (int li = tid; li < QROWS * BKT; li += 256) {
    int ql = li / BKT, j = li % BKT;
    int c = lcnt[ql]; if (c > BKT) c = BKT;
    if (j < c)
      cand[((size_t)(qbase + ql) * SLABS + slab) * BKT + j] = lent[li];
  }
}

// ---------------------------------------------------------------- k3a: per-query slab scan + validity
__global__ __launch_bounds__(256) void k3a_scan(
    const int* __restrict__ cnt2, const int* __restrict__ sure2,
    int* __restrict__ scanx, int* __restrict__ totals, int* __restrict__ validf) {
  const int q = blockIdx.x, tid = threadIdx.x;
  __shared__ int sscan[256];
  __shared__ int ssure, sovf;
  int c = cnt2[(size_t)q * SLABS + tid];
  int su = sure2[(size_t)q * SLABS + tid];
  if (tid == 0) { ssure = 0; sovf = 0; }
  __syncthreads();
  atomicAdd(&ssure, su);
  if (c > BKT) atomicOr(&sovf, 1);
  int val = c;
  sscan[tid] = val;
  __syncthreads();
  for (int o = 1; o < 256; o <<= 1) {
    int add = (tid >= o) ? sscan[tid - o] : 0;
    __syncthreads();
    val += add;
    sscan[tid] = val;
    __syncthreads();
  }
  scanx[(size_t)q * SLABS + tid] = val - c;   // exclusive offset
  const int total = sscan[255];
  if (tid == 0) {
    totals[q] = total;
    validf[q] = (sovf == 0 && ssure >= KK && total <= CAP) ? 1 : 0;
  }
}

// ---------------------------------------------------------------- k3b: parallel exact rescore -> packed keys
__global__ __launch_bounds__(256) void k3b_rescore(
    const float* __restrict__ Q, const float* __restrict__ T,
    const float* __restrict__ qn, const float* __restrict__ tn,
    const int* __restrict__ cnt2, const int* __restrict__ cand,
    const int* __restrict__ scanx, const int* __restrict__ validf,
    u64* __restrict__ keys) {
  const int q = blockIdx.x, ch = blockIdx.y, tid = threadIdx.x;
  if (!validf[q]) return;                  // uniform
  __shared__ float qv[ZD];
  for (int z = tid; z < ZD; z += 256) qv[z] = Q[(size_t)q * ZD + z];
  __syncthreads();
  const float qnv = qn[q];
  const int slab = ch * 64 + (tid >> 2);
  const int lane = tid & 3;
  const int c = min(cnt2[(size_t)q * SLABS + slab], BKT);
  const int off = scanx[(size_t)q * SLABS + slab];
  for (int k = lane; k < c; k += 4) {
    int idx = cand[((size_t)q * SLABS + slab) * BKT + k];
    const float* r = T + (size_t)idx * ZD;
    float dot = 0.f;     // sequential fmaf chain — matches prior passing rescore
    #pragma unroll 4
    for (int z4 = 0; z4 < 32; ++z4) {
      float4 v = *(const float4*)&r[z4 * 4];
      dot = fmaf(qv[z4 * 4 + 0], v.x, dot);
      dot = fmaf(qv[z4 * 4 + 1], v.y, dot);
      dot = fmaf(qv[z4 * 4 + 2], v.z, dot);
      dot = fmaf(qv[z4 * 4 + 3], v.w, dot);
    }
    float d = fmaf(-2.0f, dot, qnv + tn[idx]);
    keys[(size_t)q * CAP + off + k] = ((u64)fkey(d) << 32) | (unsigned)idx;
  }
}

// ---------------------------------------------------------------- k3c: histogram-select + small sort + softmax
__global__ __launch_bounds__(256) void k3c_select(
    const float* __restrict__ Q, const float* __restrict__ T, int M,
    const float* __restrict__ qn, const float* __restrict__ tn,
    const int* __restrict__ totals, const int* __restrict__ validf,
    const u64* __restrict__ keys_g,
    int* __restrict__ topi, float* __restrict__ emit) {
  __shared__ u64 key[CAP];
  __shared__ u64 buf[256];
  __shared__ unsigned redA[256], redB[256];
  __shared__ int hist[256];
  __shared__ int hscan[256];
  __shared__ float qv[ZD];
  __shared__ float cd[256];
  __shared__ float sdF[KK];
  __shared__ int   siF[KK];
  __shared__ float ebuf[KK];
  __shared__ float ssum;
  __shared__ int Bb, C2, ccnt, srcFlag;
  __shared__ unsigned kminS; __shared__ int shiftS;
  const int q = blockIdx.x, tid = threadIdx.x;
  const int total = totals[q];
  const bool valid = validf[q] != 0;

  if (valid) {
    for (int i = tid; i < CAP; i += 256)
      key[i] = (i < total) ? keys_g[(size_t)q * CAP + i] : ~0ULL;
    unsigned lmin = 0xFFFFFFFFu, lmax = 0u;
    for (int i = tid; i < total; i += 256) {
      unsigned h = (unsigned)(key[i] >> 32);
      lmin = min(lmin, h); lmax = max(lmax, h);
    }
    redA[tid] = lmin; redB[tid] = lmax;
    hist[tid] = 0;
    __syncthreads();
    for (int o = 128; o > 0; o >>= 1) {
      if (tid < o) {
        redA[tid] = min(redA[tid], redA[tid + o]);
        redB[tid] = max(redB[tid], redB[tid + o]);
      }
      __syncthreads();
    }
    if (tid == 0) {
      unsigned range = redB[0] - redA[0];
      int s = 0;
      while ((range >> s) > 255u) ++s;
      kminS = redA[0]; shiftS = s;
      ccnt = 0;
    }
    __syncthreads();
    const unsigned kmin = kminS; const int sh = shiftS;
    for (int i = tid; i < total; i += 256) {
      int b = (int)(((unsigned)(key[i] >> 32) - kmin) >> sh);
      atomicAdd(&hist[b], 1);
    }
    __syncthreads();
    int v0 = hist[tid];
    hscan[tid] = v0;
    __syncthreads();
    for (int o = 1; o < 256; o <<= 1) {
      int add = (tid >= o) ? hscan[tid - o] : 0;
      __syncthreads();
      v0 += add;
      hscan[tid] = v0;
      __syncthreads();
    }
    if (hscan[tid] >= KK && (tid == 0 || hscan[tid - 1] < KK)) {
      Bb = tid; C2 = hscan[tid];
    }
    __syncthreads();
    const int B = Bb, c2 = C2;
    if (c2 <= 256) {
      for (int i = tid; i < total; i += 256) {
        int b = (int)(((unsigned)(key[i] >> 32) - kmin) >> sh);
        if (b <= B) { int pos = atomicAdd(&ccnt, 1); buf[pos] = key[i]; }
      }
      __syncthreads();
      if (tid >= c2) buf[tid] = ~0ULL;
      __syncthreads();
      for (int k = 2; k <= 256; k <<= 1) {
        for (int j = k >> 1; j > 0; j >>= 1) {
          int x = tid ^ j;
          if (x > tid) {
            u64 a = buf[tid], b2 = buf[x];
            bool asc = ((tid & k) == 0);
            if ((a > b2) == asc) { buf[tid] = b2; buf[x] = a; }
          }
          __syncthreads();
        }
      }
      if (tid == 0) srcFlag = 0;
    } else {
      for (int k = 2; k <= CAP; k <<= 1) {
        for (int j = k >> 1; j > 0; j >>= 1) {
          for (int t = tid; t < CAP; t += 256) {
            int x = t ^ j;
            if (x > t) {
              u64 a = key[t], b2 = key[x];
              bool asc = ((t & k) == 0);
              if ((a > b2) == asc) { key[t] = b2; key[x] = a; }
            }
          }
          __syncthreads();
        }
      }
      if (tid == 0) srcFlag = 1;
    }
    __syncthreads();
  } else {
    // brute-force exact fallback (correctness net; ~never taken)
    for (int z = tid; z < ZD; z += 256) qv[z] = Q[(size_t)q * ZD + z];
    if (tid == 0) {
      for (int k = 0; k < KK; ++k) { sdF[k] = FLT_MAX; siF[k] = INT_MAX; }
      srcFlag = 0;
    }
    __syncthreads();
    const float qnv = qn[q];
    for (int base = 0; base < M; base += 256) {
      int m = base + tid; float d = FLT_MAX;
      if (m < M) {
        const float* r = T + (size_t)m * ZD;
        float dot = 0.f;
        for (int z = 0; z < ZD; ++z) dot = fmaf(qv[z], r[z], dot);
        d = fmaf(-2.0f, dot, qnv + tn[m]);
      }
      cd[tid] = d;
      __syncthreads();
      if (tid == 0) {
        for (int e = 0; e < 256; ++e) {
          float dd = cd[e]; int mm = base + e;
          if (dd < sdF[KK - 1] || (dd == sdF[KK - 1] && mm < siF[KK - 1])) {
            int pos = KK - 1;
            while (pos > 0 && (sdF[pos - 1] > dd || (sdF[pos - 1] == dd && siF[pos - 1] > mm))) {
              sdF[pos] = sdF[pos - 1]; siF[pos] = siF[pos - 1]; --pos;
            }
            sdF[pos] = dd; siF[pos] = mm;
          }
        }
      }
      __syncthreads();
    }
    if (tid < KK) buf[tid] = ((u64)fkey(sdF[tid]) << 32) | (unsigned)siF[tid];
    __syncthreads();
  }

  const int sf = srcFlag;
  if (tid == 0) {
    u64 k0v = sf ? key[0] : buf[0];
    float d0 = unfkey((unsigned)(k0v >> 32));
    float sum = 0.f;
    for (int k = 0; k < KK; ++k) {
      u64 kk = sf ? key[k] : buf[k];
      float e = expf(d0 - unfkey((unsigned)(kk >> 32)));
      ebuf[k] = e; sum += e;
    }
    ssum = sum;
  }
  __syncthreads();
  if (tid < KK) {
    u64 kk = sf ? key[tid] : buf[tid];
    emit[(size_t)q * KK + tid] = ebuf[tid] / ssum;
    topi[(size_t)q * KK + tid] = (int)(kk & 0xFFFFFFFFu);
  }
}

// ---------------------------------------------------------------- k4: transition matrices exp(-d)
__global__ __launch_bounds__(256) void k4_trans(
    const float* __restrict__ T, const int* __restrict__ topi,
    float* __restrict__ trans) {
  const int bt = blockIdx.x;                 // 0..251
  const int b = bt / (NT - 1), t = bt % (NT - 1);
  const int* iA = topi + (size_t)(b * NT + t) * KK;
  const int* iB = topi + (size_t)(b * NT + t + 1) * KK;
  __shared__ float As[KK * 132];
  __shared__ float Bs[20 * 132];
  __shared__ float an[KK];
  __shared__ float bn[20];
  const int tid = threadIdx.x;
  for (int li = tid; li < KK * 32; li += 256) {
    int row = li >> 5, z4 = li & 31;
    float4 v = *(const float4*)&T[(size_t)iA[row] * ZD + z4 * 4];
    *(float4*)&As[row * 132 + z4 * 4] = v;
  }
  __syncthreads();
  if (tid < KK) {
    float s = 0.f;
    for (int z = 0; z < ZD; ++z) s = fmaf(As[tid * 132 + z], As[tid * 132 + z], s);
    an[tid] = s;
  }
  for (int c = 0; c < 5; ++c) {
    __syncthreads();
    for (int li = tid; li < 20 * 32; li += 256) {
      int row = li >> 5, z4 = li & 31;
      float4 v = *(const float4*)&T[(size_t)iB[c * 20 + row] * ZD + z4 * 4];
      *(float4*)&Bs[row * 132 + z4 * 4] = v;
    }
    __syncthreads();
    if (tid < 20) {
      float s = 0.f;
      for (int z = 0; z < ZD; ++z) s = fmaf(Bs[tid * 132 + z], Bs[tid * 132 + z], s);
      bn[tid] = s;
    }
    __syncthreads();
    if (tid < 125) {
      const int i0 = (tid / 5) * 4, j0 = (tid % 5) * 4;
      float acc[16];
      #pragma unroll
      for (int x = 0; x < 16; ++x) acc[x] = 0.f;
      for (int z4 = 0; z4 < 32; ++z4) {
        float4 a[4], bb[4];
        #pragma unroll
        for (int r = 0; r < 4; ++r) a[r] = *(const float4*)&As[(i0 + r) * 132 + z4 * 4];
        #pragma unroll
        for (int s = 0; s < 4; ++s) bb[s] = *(const float4*)&Bs[(j0 + s) * 132 + z4 * 4];
        #pragma unroll
        for (int r = 0; r < 4; ++r) {
          #pragma unroll
          for (int s = 0; s < 4; ++s) {
            acc[r * 4 + s] = fmaf(a[r].x, bb[s].x, acc[r * 4 + s]);
            acc[r * 4 + s] = fmaf(a[r].y, bb[s].y, acc[r * 4 + s]);
            acc[r * 4 + s] = fmaf(a[r].z, bb[s].z, acc[r * 4 + s]);
            acc[r * 4 + s] = fmaf(a[r].w, bb[s].w, acc[r * 4 + s]);
          }
        }
      }
      float* trow = trans + (size_t)bt * KK * KK;
      #pragma unroll
      for (int r = 0; r < 4; ++r)
        for (int s = 0; s < 4; ++s) {
          float d = fmaf(-2.0f, acc[r * 4 + s], an[i0 + r] + bn[j0 + s]);
          trow[(i0 + r) * KK + c * 20 + j0 + s] = expf(-d);
        }
    }
  }
}

// ---------------------------------------------------------------- k5: Viterbi (prefetch + LDS backptrs + zflag)
__global__ __launch_bounds__(256) void k5_viterbi(
    const float* __restrict__ T, const int* __restrict__ topi,
    const float* __restrict__ emit, const float* __restrict__ trans,
    float* __restrict__ out) {
  const int b = blockIdx.x, tid = threadIdx.x;
  __shared__ float trS[KK * KK];
  __shared__ float v[KK], vn[KK];
  __shared__ float pb[200];
  __shared__ int   pi[200];
  __shared__ int   bpS[(NT - 1) * KK];   // 25.2 KB backptrs in LDS
  __shared__ int   path[NT];
  __shared__ float maxsh;
  __shared__ int   zflag;

  // preload tile 0 into registers
  float4 r[10];
  {
    const float* tr0 = trans + (size_t)(b * (NT - 1)) * KK * KK;
    #pragma unroll
    for (int i = 0; i < 10; ++i) {
      int li = tid + i * 256;
      if (li < 2500) r[i] = *(const float4*)&tr0[li * 4];
    }
  }
  if (tid < KK) v[tid] = emit[(size_t)(b * NT) * KK + tid];
  if (tid == 0) zflag = 0;
  __syncthreads();

  for (int t = 1; t < NT; ++t) {
    const int zf = zflag;   // uniform: last write precedes >=2 barriers
    if (zf == 0) {
      // commit prefetched tile (t-1) to LDS
      #pragma unroll
      for (int i = 0; i < 10; ++i) {
        int li = tid + i * 256;
        if (li < 2500) *(float4*)&trS[li * 4] = r[i];
      }
      __syncthreads();
      // issue loads for next tile while computing this one
      if (t < NT - 1) {
        const float* trn = trans + (size_t)(b * (NT - 1) + t) * KK * KK;
        #pragma unroll
        for (int i = 0; i < 10; ++i) {
          int li = tid + i * 256;
          if (li < 2500) r[i] = *(const float4*)&trn[li * 4];
        }
      }
      if (tid < 200) {
        const int j = tid % 100, half = tid / 100;
        const int ia = half * 50, ibnd = ia + 50;
        float best = -FLT_MAX; int bi = ia;
        for (int i = ia; i < ibnd; ++i) {
          float s = v[i] * trS[i * KK + j];
          if (s > best) { best = s; bi = i; }     // strict > == argmax-first
        }
        pb[tid] = best; pi[tid] = bi;
      }
      __syncthreads();
      if (tid < KK) {
        float b0 = pb[tid], b1 = pb[100 + tid];
        int   i0 = pi[tid], i1 = pi[100 + tid];
        float best = b0; int bi = i0;
        if (b1 > b0) { best = b1; bi = i1; }      // half-1 indices all larger
        vn[tid] = best * emit[(size_t)(b * NT + t) * KK + tid];
        bpS[(t - 1) * KK + tid] = bi;
      }
      __syncthreads();
      if (tid == 0) {
        float m = vn[0];
        for (int j = 1; j < KK; ++j) m = fmaxf(m, vn[j]);
        maxsh = m;
        if (m == 0.0f) zflag = 1;   // exact shortcut: all-zero v is absorbing
      }
      __syncthreads();
      if (tid < KK) v[tid] = vn[tid] / fmaxf(maxsh, 1e-30f);
    } else {
      // v == 0 everywhere: scores all +0 -> strict > fires only at i=0 -> backp=0, v stays 0
      if (tid < KK) bpS[(t - 1) * KK + tid] = 0;
    }
    __syncthreads();
  }
  if (tid == 0) {
    float best = -FLT_MAX; int last = 0;
    for (int j = 0; j < KK; ++j) if (v[j] > best) { best = v[j]; last = j; }
    path[NT - 1] = last;
    for (int tt = NT - 2; tt >= 0; --tt)
      path[tt] = bpS[tt * KK + path[tt + 1]];
  }
  __syncthreads();
  for (int li = tid; li < NT * ZD; li += 256) {
    int t = li >> 7, z = li & 127;
    out[(size_t)(b * NT + t) * ZD + z] =
        T[(size_t)topi[(size_t)(b * NT + t) * KK + path[t]] * ZD + z];
  }
}

// ---------------------------------------------------------------- host
extern "C" void kernel_launch(void* const* d_in, const int* in_sizes, int n_in,
                              void* d_out, int out_size, void* d_ws, size_t ws_size,
                              hipStream_t stream) {
  const float* Q = (const float*)d_in[0];     // (4,64,128) fp32
  const float* T = (const float*)d_in[1];     // (100000,128) fp32
  float* out = (float*)d_out;                 // (4,64,128) fp32
  const int M = in_sizes[1] / ZD;
  const int slabn = (M + SLABS - 1) / SLABS;  // 391 for M=100000

  char* p = (char*)d_ws;
  auto alloc = [&](size_t bytes) -> char* {
    char* r = p; p += (bytes + 511) & ~(size_t)511; return r;
  };
  float* qn     = (float*)alloc((size_t)NQ * 4);
  float* tn     = (float*)alloc((size_t)M * 4);
  float* thr    = (float*)alloc((size_t)NQ * 4);
  int*   cnt2   = (int*)  alloc((size_t)NQ * SLABS * 4);
  int*   sure2  = (int*)  alloc((size_t)NQ * SLABS * 4);
  int*   cand   = (int*)  alloc((size_t)NQ * SLABS * BKT * 4);
  int*   scanx  = (int*)  alloc((size_t)NQ * SLABS * 4);
  int*   totals = (int*)  alloc((size_t)NQ * 4);
  int*   validf = (int*)  alloc((size_t)NQ * 4);
  u64*   keys   = (u64*)  alloc((size_t)NQ * CAP * 8);
  int*   topi   = (int*)  alloc((size_t)NQ * KK * 4);
  float* emit   = (float*)alloc((size_t)NQ * KK * 4);
  float* trans  = (float*)alloc((size_t)NB * (NT - 1) * KK * KK * 4);

  const int g0 = (M + NQ + 255) / 256;
  k0_norms<<<g0, 256, 0, stream>>>(Q, T, M, qn, tn);
  k1_thresh<<<NQ, 256, 0, stream>>>(Q, T, M, qn, tn, thr);
  dim3 g2(SLABS, NQ / QROWS);
  k2_mfma<<<g2, 256, 0, stream>>>(Q, T, M, slabn, qn, tn, thr, cnt2, sure2, cand);
  k3a_scan<<<NQ, 256, 0, stream>>>(cnt2, sure2, scanx, totals, validf);
  dim3 g3b(NQ, 4);
  k3b_rescore<<<g3b, 256, 0, stream>>>(Q, T, qn, tn, cnt2, cand, scanx, validf, keys);
  k3c_select<<<NQ, 256, 0, stream>>>(Q, T, M, qn, tn, totals, validf, keys, topi, emit);
  k4_trans<<<NB * (NT - 1), 256, 0, stream>>>(T, topi, trans);
  k5_viterbi<<<NB, 256, 0, stream>>>(T, topi, emit, trans, out);
}

// Round 7
// 336.703 us; speedup vs baseline: 46.7338x; 1.0045x over previous
//
#include <hip/hip_runtime.h>
#include <cfloat>
#include <climits>
#include <cstdint>
#include <cstddef>

#define ZD    128
#define NQ    256      // 4*64 queries
#define NB    4
#define NT    64
#define KK    100
#define CAP   2048     // R3-verified: per-query candidate totals stay <= 2048
#define NSAMP 4096
#define RANK  24
#define EPS   3.0f     // rigorous |d_bf16 - d_exact| bound (analysis: <= ~2.2)
#define SLABS 256
#define BKT   24       // per-(q,slab) bucket capacity
#define TROWS 64
#define QROWS 128
#define LPAD  136      // bf16 row stride (272 B), keeps 16B alignment

typedef __attribute__((ext_vector_type(8))) short  short8;   // 8 bf16 (4 VGPRs)
typedef __attribute__((ext_vector_type(4))) float  floatx4;  // mfma acc
typedef unsigned long long u64;

__device__ inline unsigned short f2bf(float f) {   // RNE fp32 -> bf16
  unsigned u = __builtin_bit_cast(unsigned, f);
  unsigned r = u + 0x7fffu + ((u >> 16) & 1u);
  return (unsigned short)(r >> 16);
}
__device__ inline unsigned fkey(float f) {         // monotone float->uint
  unsigned u = __builtin_bit_cast(unsigned, f);
  unsigned m = (u & 0x80000000u) ? 0xFFFFFFFFu : 0x80000000u;
  return u ^ m;
}
__device__ inline float unfkey(unsigned k) {       // inverse
  unsigned u = (k & 0x80000000u) ? (k ^ 0x80000000u) : ~k;
  return __builtin_bit_cast(float, u);
}

// ---------------------------------------------------------------- k0: norms
__global__ __launch_bounds__(256) void k0_norms(
    const float* __restrict__ Q, const float* __restrict__ T, int M,
    float* __restrict__ qn, float* __restrict__ tn) {
  int gid = blockIdx.x * 256 + threadIdx.x;
  if (gid < M) {
    const float* r = T + (size_t)gid * ZD;
    float s = 0.f;
    #pragma unroll
    for (int z4 = 0; z4 < 32; ++z4) {
      float4 v = *(const float4*)&r[z4 * 4];
      s = fmaf(v.x, v.x, s); s = fmaf(v.y, v.y, s);
      s = fmaf(v.z, v.z, s); s = fmaf(v.w, v.w, s);
    }
    tn[gid] = s;
  } else if (gid < M + NQ) {
    int q = gid - M;
    const float* r = Q + (size_t)q * ZD;
    float s = 0.f;
    #pragma unroll
    for (int z4 = 0; z4 < 32; ++z4) {
      float4 v = *(const float4*)&r[z4 * 4];
      s = fmaf(v.x, v.x, s); s = fmaf(v.y, v.y, s);
      s = fmaf(v.z, v.z, s); s = fmaf(v.w, v.w, s);
    }
    qn[q] = s;
  }
}

// ---------------------------------------------------------------- k1a: sample distances (4 blocks/query)
__global__ __launch_bounds__(256) void k1a_sample(
    const float* __restrict__ Q, const float* __restrict__ T,
    const float* __restrict__ qn, const float* __restrict__ tn,
    float* __restrict__ sd_g) {
  __shared__ float qv[ZD];
  const int q = blockIdx.x, ch = blockIdx.y, tid = threadIdx.x;
  for (int z = tid; z < ZD; z += 256) qv[z] = Q[(size_t)q * ZD + z];
  __syncthreads();
  const float qnv = qn[q];
  const int s0 = ch * 1024;
  #pragma unroll
  for (int k = 0; k < 4; ++k) {
    const int s = s0 + k * 256 + tid;
    const float* r = T + (size_t)s * ZD;
    float d0 = 0.f, d1 = 0.f, d2 = 0.f, d3 = 0.f;
    #pragma unroll 8
    for (int z4 = 0; z4 < 32; ++z4) {
      float4 v = *(const float4*)&r[z4 * 4];
      d0 = fmaf(qv[z4 * 4 + 0], v.x, d0);
      d1 = fmaf(qv[z4 * 4 + 1], v.y, d1);
      d2 = fmaf(qv[z4 * 4 + 2], v.z, d2);
      d3 = fmaf(qv[z4 * 4 + 3], v.w, d3);
    }
    float dot = (d0 + d1) + (d2 + d3);
    sd_g[(size_t)q * NSAMP + s] = fmaf(-2.0f, dot, qnv + tn[s]);
  }
}

// ---------------------------------------------------------------- k1b: min + histogram -> per-query threshold
__global__ __launch_bounds__(256) void k1b_pick(
    const float* __restrict__ sd_g, float* __restrict__ thr) {
  __shared__ float red[256];
  __shared__ int   hist[256];
  const int q = blockIdx.x, tid = threadIdx.x;
  const float* sd = sd_g + (size_t)q * NSAMP;
  float vals[16];
  float lm = FLT_MAX;
  #pragma unroll
  for (int k = 0; k < 16; ++k) {
    vals[k] = sd[k * 256 + tid];
    lm = fminf(lm, vals[k]);
  }
  red[tid] = lm;
  hist[tid] = 0;
  __syncthreads();
  for (int o = 128; o > 0; o >>= 1) {
    if (tid < o) red[tid] = fminf(red[tid], red[tid + o]);
    __syncthreads();
  }
  const float dmin = red[0];
  __syncthreads();
  #pragma unroll
  for (int k = 0; k < 16; ++k) {
    int b = (int)((vals[k] - dmin) * 3.2f);   // bin width 0.3125 over [dmin, dmin+80]
    b = b < 0 ? 0 : (b > 255 ? 255 : b);
    atomicAdd(&hist[b], 1);
  }
  __syncthreads();
  if (tid == 0) {
    int cum = 0; float Tq = dmin + 80.0f;
    for (int b = 0; b < 256; ++b) {
      cum += hist[b];
      if (cum >= RANK) { Tq = dmin + (float)(b + 1) * 0.3125f; break; }
    }
    thr[q] = Tq;
  }
}

// ---------------------------------------------------------------- k2: bf16 MFMA filter, slab-bucketed
__global__ __launch_bounds__(256) void k2_mfma(
    const float* __restrict__ Q, const float* __restrict__ T, int M, int slabn,
    const float* __restrict__ qn, const float* __restrict__ tn,
    const float* __restrict__ thr,
    int* __restrict__ cnt2, int* __restrict__ sure2, int* __restrict__ cand) {
  __shared__ short Ts[TROWS * LPAD];
  __shared__ short Qs[QROWS * LPAD];
  __shared__ int   lcnt[QROWS];
  __shared__ int   lsure[QROWS];
  __shared__ int   lent[QROWS * BKT];
  const int tid = threadIdx.x;
  const int slab = blockIdx.x;
  const int qbase = blockIdx.y * QROWS;
  const int sbeg = slab * slabn;
  const int send = min(sbeg + slabn, M);

  #pragma unroll
  for (int it = 0; it < 16; ++it) {
    int li = tid + it * 256;
    int row = li >> 5, z4 = li & 31;
    float4 v = *(const float4*)&Q[(size_t)(qbase + row) * ZD + z4 * 4];
    unsigned lo = (unsigned)f2bf(v.x) | ((unsigned)f2bf(v.y) << 16);
    unsigned hi = (unsigned)f2bf(v.z) | ((unsigned)f2bf(v.w) << 16);
    *(uint2*)&Qs[row * LPAD + z4 * 4] = make_uint2(lo, hi);
  }
  if (tid < QROWS) { lcnt[tid] = 0; lsure[tid] = 0; }

  const int wave = tid >> 6;
  const int lane = tid & 63;
  const int quad = lane >> 4;
  const int n16  = lane & 15;

  for (int m0 = sbeg; m0 < send; m0 += TROWS) {
    __syncthreads();
    #pragma unroll
    for (int it = 0; it < 8; ++it) {
      int li = tid + it * 256;
      int row = li >> 5, z4 = li & 31;
      int m = m0 + row;
      float4 v = make_float4(0.f, 0.f, 0.f, 0.f);
      if (m < send) v = *(const float4*)&T[(size_t)m * ZD + z4 * 4];
      unsigned lo = (unsigned)f2bf(v.x) | ((unsigned)f2bf(v.y) << 16);
      unsigned hi = (unsigned)f2bf(v.z) | ((unsigned)f2bf(v.w) << 16);
      *(uint2*)&Ts[row * LPAD + z4 * 4] = make_uint2(lo, hi);
    }
    __syncthreads();

    floatx4 acc[8];
    #pragma unroll
    for (int qt = 0; qt < 8; ++qt) acc[qt] = (floatx4)0.f;
    #pragma unroll
    for (int ks = 0; ks < 4; ++ks) {
      short8 a = *(const short8*)&Ts[(wave * 16 + n16) * LPAD + ks * 32 + quad * 8];
      #pragma unroll
      for (int qt = 0; qt < 8; ++qt) {
        short8 b = *(const short8*)&Qs[(qt * 16 + n16) * LPAD + ks * 32 + quad * 8];
        acc[qt] = __builtin_amdgcn_mfma_f32_16x16x32_bf16(a, b, acc[qt], 0, 0, 0);
      }
    }

    const int mbase = m0 + wave * 16 + quad * 4;
    float4 tnv = make_float4(0.f, 0.f, 0.f, 0.f);
    if (mbase + 3 < M) tnv = *(const float4*)&tn[mbase];
    else {
      if (mbase + 0 < M) tnv.x = tn[mbase + 0];
      if (mbase + 1 < M) tnv.y = tn[mbase + 1];
      if (mbase + 2 < M) tnv.z = tn[mbase + 2];
    }
    const float tns[4] = {tnv.x, tnv.y, tnv.z, tnv.w};
    #pragma unroll
    for (int qt = 0; qt < 8; ++qt) {
      const int ql = qt * 16 + n16;
      const int q = qbase + ql;
      const float base = qn[q];
      const float Tq = thr[q];
      #pragma unroll
      for (int r = 0; r < 4; ++r) {
        const int m = mbase + r;
        float dap = fmaf(-2.0f, acc[qt][r], base + tns[r]);
        if (m < send && dap < Tq + EPS) {
          int pos = atomicAdd(&lcnt[ql], 1);
          if (pos < BKT) lent[ql * BKT + pos] = m;
          if (dap < Tq - EPS) atomicAdd(&lsure[ql], 1);
        }
      }
    }
  }
  __syncthreads();
  if (tid < QROWS) {
    cnt2 [(size_t)(qbase + tid) * SLABS + slab] = lcnt[tid];
    sure2[(size_t)(qbase + tid) * SLABS + slab] = lsure[tid];
  }
  for (int li = tid; li < QROWS * BKT; li += 256) {
    int ql = li / BKT, j = li % BKT;
    int c = lcnt[ql]; if (c > BKT) c = BKT;
    if (j < c)
      cand[((size_t)(qbase + ql) * SLABS + slab) * BKT + j] = lent[li];
  }
}

// ---------------------------------------------------------------- k3a: per-query slab scan + validity
__global__ __launch_bounds__(256) void k3a_scan(
    const int* __restrict__ cnt2, const int* __restrict__ sure2,
    int* __restrict__ scanx, int* __restrict__ totals, int* __restrict__ validf) {
  const int q = blockIdx.x, tid = threadIdx.x;
  __shared__ int sscan[256];
  __shared__ int ssure, sovf;
  int c = cnt2[(size_t)q * SLABS + tid];
  int su = sure2[(size_t)q * SLABS + tid];
  if (tid == 0) { ssure = 0; sovf = 0; }
  __syncthreads();
  atomicAdd(&ssure, su);
  if (c > BKT) atomicOr(&sovf, 1);
  int val = c;
  sscan[tid] = val;
  __syncthreads();
  for (int o = 1; o < 256; o <<= 1) {
    int add = (tid >= o) ? sscan[tid - o] : 0;
    __syncthreads();
    val += add;
    sscan[tid] = val;
    __syncthreads();
  }
  scanx[(size_t)q * SLABS + tid] = val - c;   // exclusive offset
  const int total = sscan[255];
  if (tid == 0) {
    totals[q] = total;
    validf[q] = (sovf == 0 && ssure >= KK && total <= CAP) ? 1 : 0;
  }
}

// ---------------------------------------------------------------- k3b: parallel exact rescore -> packed keys
__global__ __launch_bounds__(256) void k3b_rescore(
    const float* __restrict__ Q, const float* __restrict__ T,
    const float* __restrict__ qn, const float* __restrict__ tn,
    const int* __restrict__ cnt2, const int* __restrict__ cand,
    const int* __restrict__ scanx, const int* __restrict__ validf,
    u64* __restrict__ keys) {
  const int q = blockIdx.x, ch = blockIdx.y, tid = threadIdx.x;
  if (!validf[q]) return;                  // uniform
  __shared__ float qv[ZD];
  for (int z = tid; z < ZD; z += 256) qv[z] = Q[(size_t)q * ZD + z];
  __syncthreads();
  const float qnv = qn[q];
  const int slab = ch * 64 + (tid >> 2);
  const int lane = tid & 3;
  const int c = min(cnt2[(size_t)q * SLABS + slab], BKT);
  const int off = scanx[(size_t)q * SLABS + slab];
  for (int k = lane; k < c; k += 4) {
    int idx = cand[((size_t)q * SLABS + slab) * BKT + k];
    const float* r = T + (size_t)idx * ZD;
    float dot = 0.f;     // sequential fmaf chain — matches prior passing rescore
    #pragma unroll 4
    for (int z4 = 0; z4 < 32; ++z4) {
      float4 v = *(const float4*)&r[z4 * 4];
      dot = fmaf(qv[z4 * 4 + 0], v.x, dot);
      dot = fmaf(qv[z4 * 4 + 1], v.y, dot);
      dot = fmaf(qv[z4 * 4 + 2], v.z, dot);
      dot = fmaf(qv[z4 * 4 + 3], v.w, dot);
    }
    float d = fmaf(-2.0f, dot, qnv + tn[idx]);
    keys[(size_t)q * CAP + off + k] = ((u64)fkey(d) << 32) | (unsigned)idx;
  }
}

// ---------------------------------------------------------------- k3c: histogram-select + small sort + softmax
__global__ __launch_bounds__(256) void k3c_select(
    const float* __restrict__ Q, const float* __restrict__ T, int M,
    const float* __restrict__ qn, const float* __restrict__ tn,
    const int* __restrict__ totals, const int* __restrict__ validf,
    const u64* __restrict__ keys_g,
    int* __restrict__ topi, float* __restrict__ emit) {
  __shared__ u64 key[CAP];
  __shared__ u64 buf[256];
  __shared__ unsigned redA[256], redB[256];
  __shared__ int hist[256];
  __shared__ int hscan[256];
  __shared__ float qv[ZD];
  __shared__ float cd[256];
  __shared__ float sdF[KK];
  __shared__ int   siF[KK];
  __shared__ float ebuf[KK];
  __shared__ float ssum;
  __shared__ int Bb, C2, ccnt, srcFlag;
  __shared__ unsigned kminS; __shared__ int shiftS;
  const int q = blockIdx.x, tid = threadIdx.x;
  const int total = totals[q];
  const bool valid = validf[q] != 0;

  if (valid) {
    for (int i = tid; i < CAP; i += 256)
      key[i] = (i < total) ? keys_g[(size_t)q * CAP + i] : ~0ULL;
    unsigned lmin = 0xFFFFFFFFu, lmax = 0u;
    for (int i = tid; i < total; i += 256) {
      unsigned h = (unsigned)(key[i] >> 32);
      lmin = min(lmin, h); lmax = max(lmax, h);
    }
    redA[tid] = lmin; redB[tid] = lmax;
    hist[tid] = 0;
    __syncthreads();
    for (int o = 128; o > 0; o >>= 1) {
      if (tid < o) {
        redA[tid] = min(redA[tid], redA[tid + o]);
        redB[tid] = max(redB[tid], redB[tid + o]);
      }
      __syncthreads();
    }
    if (tid == 0) {
      unsigned range = redB[0] - redA[0];
      int s = 0;
      while ((range >> s) > 255u) ++s;
      kminS = redA[0]; shiftS = s;
      ccnt = 0;
    }
    __syncthreads();
    const unsigned kmin = kminS; const int sh = shiftS;
    for (int i = tid; i < total; i += 256) {
      int b = (int)(((unsigned)(key[i] >> 32) - kmin) >> sh);
      atomicAdd(&hist[b], 1);
    }
    __syncthreads();
    int v0 = hist[tid];
    hscan[tid] = v0;
    __syncthreads();
    for (int o = 1; o < 256; o <<= 1) {
      int add = (tid >= o) ? hscan[tid - o] : 0;
      __syncthreads();
      v0 += add;
      hscan[tid] = v0;
      __syncthreads();
    }
    if (hscan[tid] >= KK && (tid == 0 || hscan[tid - 1] < KK)) {
      Bb = tid; C2 = hscan[tid];
    }
    __syncthreads();
    const int B = Bb, c2 = C2;
    if (c2 <= 256) {
      for (int i = tid; i < total; i += 256) {
        int b = (int)(((unsigned)(key[i] >> 32) - kmin) >> sh);
        if (b <= B) { int pos = atomicAdd(&ccnt, 1); buf[pos] = key[i]; }
      }
      __syncthreads();
      if (tid >= c2) buf[tid] = ~0ULL;
      __syncthreads();
      for (int k = 2; k <= 256; k <<= 1) {
        for (int j = k >> 1; j > 0; j >>= 1) {
          int x = tid ^ j;
          if (x > tid) {
            u64 a = buf[tid], b2 = buf[x];
            bool asc = ((tid & k) == 0);
            if ((a > b2) == asc) { buf[tid] = b2; buf[x] = a; }
          }
          __syncthreads();
        }
      }
      if (tid == 0) srcFlag = 0;
    } else {
      for (int k = 2; k <= CAP; k <<= 1) {
        for (int j = k >> 1; j > 0; j >>= 1) {
          for (int t = tid; t < CAP; t += 256) {
            int x = t ^ j;
            if (x > t) {
              u64 a = key[t], b2 = key[x];
              bool asc = ((t & k) == 0);
              if ((a > b2) == asc) { key[t] = b2; key[x] = a; }
            }
          }
          __syncthreads();
        }
      }
      if (tid == 0) srcFlag = 1;
    }
    __syncthreads();
  } else {
    // brute-force exact fallback (correctness net; ~never taken)
    for (int z = tid; z < ZD; z += 256) qv[z] = Q[(size_t)q * ZD + z];
    if (tid == 0) {
      for (int k = 0; k < KK; ++k) { sdF[k] = FLT_MAX; siF[k] = INT_MAX; }
      srcFlag = 0;
    }
    __syncthreads();
    const float qnv = qn[q];
    for (int base = 0; base < M; base += 256) {
      int m = base + tid; float d = FLT_MAX;
      if (m < M) {
        const float* r = T + (size_t)m * ZD;
        float dot = 0.f;
        for (int z = 0; z < ZD; ++z) dot = fmaf(qv[z], r[z], dot);
        d = fmaf(-2.0f, dot, qnv + tn[m]);
      }
      cd[tid] = d;
      __syncthreads();
      if (tid == 0) {
        for (int e = 0; e < 256; ++e) {
          float dd = cd[e]; int mm = base + e;
          if (dd < sdF[KK - 1] || (dd == sdF[KK - 1] && mm < siF[KK - 1])) {
            int pos = KK - 1;
            while (pos > 0 && (sdF[pos - 1] > dd || (sdF[pos - 1] == dd && siF[pos - 1] > mm))) {
              sdF[pos] = sdF[pos - 1]; siF[pos] = siF[pos - 1]; --pos;
            }
            sdF[pos] = dd; siF[pos] = mm;
          }
        }
      }
      __syncthreads();
    }
    if (tid < KK) buf[tid] = ((u64)fkey(sdF[tid]) << 32) | (unsigned)siF[tid];
    __syncthreads();
  }

  const int sf = srcFlag;
  if (tid == 0) {
    u64 k0v = sf ? key[0] : buf[0];
    float d0 = unfkey((unsigned)(k0v >> 32));
    float sum = 0.f;
    for (int k = 0; k < KK; ++k) {
      u64 kk = sf ? key[k] : buf[k];
      float e = expf(d0 - unfkey((unsigned)(kk >> 32)));
      ebuf[k] = e; sum += e;
    }
    ssum = sum;
  }
  __syncthreads();
  if (tid < KK) {
    u64 kk = sf ? key[tid] : buf[tid];
    emit[(size_t)q * KK + tid] = ebuf[tid] / ssum;
    topi[(size_t)q * KK + tid] = (int)(kk & 0xFFFFFFFFu);
  }
}

// ---------------------------------------------------------------- k4: transition matrices exp(-d)
__global__ __launch_bounds__(256) void k4_trans(
    const float* __restrict__ T, const int* __restrict__ topi,
    float* __restrict__ trans) {
  const int bt = blockIdx.x;                 // 0..251
  const int b = bt / (NT - 1), t = bt % (NT - 1);
  const int* iA = topi + (size_t)(b * NT + t) * KK;
  const int* iB = topi + (size_t)(b * NT + t + 1) * KK;
  __shared__ float As[KK * 132];
  __shared__ float Bs[20 * 132];
  __shared__ float an[KK];
  __shared__ float bn[20];
  const int tid = threadIdx.x;
  for (int li = tid; li < KK * 32; li += 256) {
    int row = li >> 5, z4 = li & 31;
    float4 v = *(const float4*)&T[(size_t)iA[row] * ZD + z4 * 4];
    *(float4*)&As[row * 132 + z4 * 4] = v;
  }
  __syncthreads();
  if (tid < KK) {
    float s = 0.f;
    for (int z = 0; z < ZD; ++z) s = fmaf(As[tid * 132 + z], As[tid * 132 + z], s);
    an[tid] = s;
  }
  for (int c = 0; c < 5; ++c) {
    __syncthreads();
    for (int li = tid; li < 20 * 32; li += 256) {
      int row = li >> 5, z4 = li & 31;
      float4 v = *(const float4*)&T[(size_t)iB[c * 20 + row] * ZD + z4 * 4];
      *(float4*)&Bs[row * 132 + z4 * 4] = v;
    }
    __syncthreads();
    if (tid < 20) {
      float s = 0.f;
      for (int z = 0; z < ZD; ++z) s = fmaf(Bs[tid * 132 + z], Bs[tid * 132 + z], s);
      bn[tid] = s;
    }
    __syncthreads();
    if (tid < 125) {
      const int i0 = (tid / 5) * 4, j0 = (tid % 5) * 4;
      float acc[16];
      #pragma unroll
      for (int x = 0; x < 16; ++x) acc[x] = 0.f;
      for (int z4 = 0; z4 < 32; ++z4) {
        float4 a[4], bb[4];
        #pragma unroll
        for (int r = 0; r < 4; ++r) a[r] = *(const float4*)&As[(i0 + r) * 132 + z4 * 4];
        #pragma unroll
        for (int s = 0; s < 4; ++s) bb[s] = *(const float4*)&Bs[(j0 + s) * 132 + z4 * 4];
        #pragma unroll
        for (int r = 0; r < 4; ++r) {
          #pragma unroll
          for (int s = 0; s < 4; ++s) {
            acc[r * 4 + s] = fmaf(a[r].x, bb[s].x, acc[r * 4 + s]);
            acc[r * 4 + s] = fmaf(a[r].y, bb[s].y, acc[r * 4 + s]);
            acc[r * 4 + s] = fmaf(a[r].z, bb[s].z, acc[r * 4 + s]);
            acc[r * 4 + s] = fmaf(a[r].w, bb[s].w, acc[r * 4 + s]);
          }
        }
      }
      float* trow = trans + (size_t)bt * KK * KK;
      #pragma unroll
      for (int r = 0; r < 4; ++r)
        for (int s = 0; s < 4; ++s) {
          float d = fmaf(-2.0f, acc[r * 4 + s], an[i0 + r] + bn[j0 + s]);
          trow[(i0 + r) * KK + c * 20 + j0 + s] = expf(-d);
        }
    }
  }
}

// ---------------------------------------------------------------- k5: Viterbi (prefetch + LDS backptrs + zflag)
__global__ __launch_bounds__(256) void k5_viterbi(
    const float* __restrict__ T, const int* __restrict__ topi,
    const float* __restrict__ emit, const float* __restrict__ trans,
    float* __restrict__ out) {
  const int b = blockIdx.x, tid = threadIdx.x;
  __shared__ float trS[KK * KK];
  __shared__ float v[KK], vn[KK];
  __shared__ float pb[200];
  __shared__ int   pi[200];
  __shared__ int   bpS[(NT - 1) * KK];   // 25.2 KB backptrs in LDS
  __shared__ int   path[NT];
  __shared__ float maxsh;
  __shared__ int   zflag;

  // preload tile 0 into registers
  float4 r[10];
  {
    const float* tr0 = trans + (size_t)(b * (NT - 1)) * KK * KK;
    #pragma unroll
    for (int i = 0; i < 10; ++i) {
      int li = tid + i * 256;
      if (li < 2500) r[i] = *(const float4*)&tr0[li * 4];
    }
  }
  if (tid < KK) v[tid] = emit[(size_t)(b * NT) * KK + tid];
  if (tid == 0) zflag = 0;
  __syncthreads();

  for (int t = 1; t < NT; ++t) {
    const int zf = zflag;   // uniform: last write precedes >=2 barriers
    if (zf == 0) {
      // commit prefetched tile (t-1) to LDS
      #pragma unroll
      for (int i = 0; i < 10; ++i) {
        int li = tid + i * 256;
        if (li < 2500) *(float4*)&trS[li * 4] = r[i];
      }
      __syncthreads();
      // issue loads for next tile while computing this one
      if (t < NT - 1) {
        const float* trn = trans + (size_t)(b * (NT - 1) + t) * KK * KK;
        #pragma unroll
        for (int i = 0; i < 10; ++i) {
          int li = tid + i * 256;
          if (li < 2500) r[i] = *(const float4*)&trn[li * 4];
        }
      }
      if (tid < 200) {
        const int j = tid % 100, half = tid / 100;
        const int ia = half * 50, ibnd = ia + 50;
        float best = -FLT_MAX; int bi = ia;
        for (int i = ia; i < ibnd; ++i) {
          float s = v[i] * trS[i * KK + j];
          if (s > best) { best = s; bi = i; }     // strict > == argmax-first
        }
        pb[tid] = best; pi[tid] = bi;
      }
      __syncthreads();
      if (tid < KK) {
        float b0 = pb[tid], b1 = pb[100 + tid];
        int   i0 = pi[tid], i1 = pi[100 + tid];
        float best = b0; int bi = i0;
        if (b1 > b0) { best = b1; bi = i1; }      // half-1 indices all larger
        vn[tid] = best * emit[(size_t)(b * NT + t) * KK + tid];
        bpS[(t - 1) * KK + tid] = bi;
      }
      __syncthreads();
      if (tid == 0) {
        float m = vn[0];
        for (int j = 1; j < KK; ++j) m = fmaxf(m, vn[j]);
        maxsh = m;
        if (m == 0.0f) zflag = 1;   // exact shortcut: all-zero v is absorbing
      }
      __syncthreads();
      if (tid < KK) v[tid] = vn[tid] / fmaxf(maxsh, 1e-30f);
    } else {
      // v == 0 everywhere: scores all +0 -> strict > fires only at i=0 -> backp=0, v stays 0
      if (tid < KK) bpS[(t - 1) * KK + tid] = 0;
    }
    __syncthreads();
  }
  if (tid == 0) {
    float best = -FLT_MAX; int last = 0;
    for (int j = 0; j < KK; ++j) if (v[j] > best) { best = v[j]; last = j; }
    path[NT - 1] = last;
    for (int tt = NT - 2; tt >= 0; --tt)
      path[tt] = bpS[tt * KK + path[tt + 1]];
  }
  __syncthreads();
  for (int li = tid; li < NT * ZD; li += 256) {
    int t = li >> 7, z = li & 127;
    out[(size_t)(b * NT + t) * ZD + z] =
        T[(size_t)topi[(size_t)(b * NT + t) * KK + path[t]] * ZD + z];
  }
}

// ---------------------------------------------------------------- host
extern "C" void kernel_launch(void* const* d_in, const int* in_sizes, int n_in,
                              void* d_out, int out_size, void* d_ws, size_t ws_size,
                              hipStream_t stream) {
  const float* Q = (const float*)d_in[0];     // (4,64,128) fp32
  const float* T = (const float*)d_in[1];     // (100000,128) fp32
  float* out = (float*)d_out;                 // (4,64,128) fp32
  const int M = in_sizes[1] / ZD;
  const int slabn = (M + SLABS - 1) / SLABS;  // 391 for M=100000

  char* p = (char*)d_ws;
  auto alloc = [&](size_t bytes) -> char* {
    char* r = p; p += (bytes + 511) & ~(size_t)511; return r;
  };
  float* qn     = (float*)alloc((size_t)NQ * 4);
  float* tn     = (float*)alloc((size_t)M * 4);
  float* thr    = (float*)alloc((size_t)NQ * 4);
  float* sd_g   = (float*)alloc((size_t)NQ * NSAMP * 4);
  int*   cnt2   = (int*)  alloc((size_t)NQ * SLABS * 4);
  int*   sure2  = (int*)  alloc((size_t)NQ * SLABS * 4);
  int*   cand   = (int*)  alloc((size_t)NQ * SLABS * BKT * 4);
  int*   scanx  = (int*)  alloc((size_t)NQ * SLABS * 4);
  int*   totals = (int*)  alloc((size_t)NQ * 4);
  int*   validf = (int*)  alloc((size_t)NQ * 4);
  u64*   keys   = (u64*)  alloc((size_t)NQ * CAP * 8);
  int*   topi   = (int*)  alloc((size_t)NQ * KK * 4);
  float* emit   = (float*)alloc((size_t)NQ * KK * 4);
  float* trans  = (float*)alloc((size_t)NB * (NT - 1) * KK * KK * 4);

  const int g0 = (M + NQ + 255) / 256;
  k0_norms<<<g0, 256, 0, stream>>>(Q, T, M, qn, tn);
  dim3 g1a(NQ, 4);
  k1a_sample<<<g1a, 256, 0, stream>>>(Q, T, qn, tn, sd_g);
  k1b_pick<<<NQ, 256, 0, stream>>>(sd_g, thr);
  dim3 g2(SLABS, NQ / QROWS);
  k2_mfma<<<g2, 256, 0, stream>>>(Q, T, M, slabn, qn, tn, thr, cnt2, sure2, cand);
  k3a_scan<<<NQ, 256, 0, stream>>>(cnt2, sure2, scanx, totals, validf);
  dim3 g3b(NQ, 4);
  k3b_rescore<<<g3b, 256, 0, stream>>>(Q, T, qn, tn, cnt2, cand, scanx, validf, keys);
  k3c_select<<<NQ, 256, 0, stream>>>(Q, T, M, qn, tn, totals, validf, keys, topi, emit);
  k4_trans<<<NB * (NT - 1), 256, 0, stream>>>(T, topi, trans);
  k5_viterbi<<<NB, 256, 0, stream>>>(T, topi, emit, trans, out);
}

// Round 8
// 284.137 us; speedup vs baseline: 55.3798x; 1.1850x over previous
//
#include <hip/hip_runtime.h>
#include <cfloat>
#include <climits>
#include <cstdint>
#include <cstddef>

#define ZD    128
#define NQ    256      // 4*64 queries
#define NB    4
#define NT    64
#define KK    100
#define CAP   2048     // R3-verified: per-query candidate totals stay <= 2048
#define NSAMP 4096
#define RANK  24
#define EPS   3.0f     // rigorous |d_bf16 - d_exact| bound (analysis: <= ~2.2)
#define SLABS 256
#define BKT   24       // per-(q,slab) bucket capacity
#define TROWS 64
#define QROWS 128
#define LPAD  136      // bf16 row stride (272 B), keeps 16B alignment

typedef __attribute__((ext_vector_type(8))) short  short8;   // 8 bf16 (4 VGPRs)
typedef __attribute__((ext_vector_type(4))) float  floatx4;  // mfma acc
typedef unsigned long long u64;

__device__ inline unsigned short f2bf(float f) {   // RNE fp32 -> bf16
  unsigned u = __builtin_bit_cast(unsigned, f);
  unsigned r = u + 0x7fffu + ((u >> 16) & 1u);
  return (unsigned short)(r >> 16);
}
__device__ inline unsigned fkey(float f) {         // monotone float->uint
  unsigned u = __builtin_bit_cast(unsigned, f);
  unsigned m = (u & 0x80000000u) ? 0xFFFFFFFFu : 0x80000000u;
  return u ^ m;
}
__device__ inline float unfkey(unsigned k) {       // inverse
  unsigned u = (k & 0x80000000u) ? (k ^ 0x80000000u) : ~k;
  return __builtin_bit_cast(float, u);
}

// ---------------------------------------------------------------- k0: norms
__global__ __launch_bounds__(256) void k0_norms(
    const float* __restrict__ Q, const float* __restrict__ T, int M,
    float* __restrict__ qn, float* __restrict__ tn) {
  int gid = blockIdx.x * 256 + threadIdx.x;
  if (gid < M) {
    const float* r = T + (size_t)gid * ZD;
    float s = 0.f;
    #pragma unroll
    for (int z4 = 0; z4 < 32; ++z4) {
      float4 v = *(const float4*)&r[z4 * 4];
      s = fmaf(v.x, v.x, s); s = fmaf(v.y, v.y, s);
      s = fmaf(v.z, v.z, s); s = fmaf(v.w, v.w, s);
    }
    tn[gid] = s;
  } else if (gid < M + NQ) {
    int q = gid - M;
    const float* r = Q + (size_t)q * ZD;
    float s = 0.f;
    #pragma unroll
    for (int z4 = 0; z4 < 32; ++z4) {
      float4 v = *(const float4*)&r[z4 * 4];
      s = fmaf(v.x, v.x, s); s = fmaf(v.y, v.y, s);
      s = fmaf(v.z, v.z, s); s = fmaf(v.w, v.w, s);
    }
    qn[q] = s;
  }
}

// ---------------------------------------------------------------- k1a: sample distances via MFMA (k2-style)
// 64 sample-targets x 128 queries per block; writes raw bf16-approx distances to sd_g.
__global__ __launch_bounds__(256) void k1a_mfma(
    const float* __restrict__ Q, const float* __restrict__ T,
    const float* __restrict__ qn, const float* __restrict__ tn,
    float* __restrict__ sd_g) {
  __shared__ short Ts[TROWS * LPAD];
  __shared__ short Qs[QROWS * LPAD];
  const int tid = threadIdx.x;
  const int m0 = blockIdx.x * TROWS;        // within [0, NSAMP)
  const int qbase = blockIdx.y * QROWS;

  #pragma unroll
  for (int it = 0; it < 16; ++it) {
    int li = tid + it * 256;
    int row = li >> 5, z4 = li & 31;
    float4 v = *(const float4*)&Q[(size_t)(qbase + row) * ZD + z4 * 4];
    unsigned lo = (unsigned)f2bf(v.x) | ((unsigned)f2bf(v.y) << 16);
    unsigned hi = (unsigned)f2bf(v.z) | ((unsigned)f2bf(v.w) << 16);
    *(uint2*)&Qs[row * LPAD + z4 * 4] = make_uint2(lo, hi);
  }
  #pragma unroll
  for (int it = 0; it < 8; ++it) {
    int li = tid + it * 256;
    int row = li >> 5, z4 = li & 31;
    float4 v = *(const float4*)&T[(size_t)(m0 + row) * ZD + z4 * 4];
    unsigned lo = (unsigned)f2bf(v.x) | ((unsigned)f2bf(v.y) << 16);
    unsigned hi = (unsigned)f2bf(v.z) | ((unsigned)f2bf(v.w) << 16);
    *(uint2*)&Ts[row * LPAD + z4 * 4] = make_uint2(lo, hi);
  }
  __syncthreads();

  const int wave = tid >> 6;
  const int lane = tid & 63;
  const int quad = lane >> 4;
  const int n16  = lane & 15;

  floatx4 acc[8];
  #pragma unroll
  for (int qt = 0; qt < 8; ++qt) acc[qt] = (floatx4)0.f;
  #pragma unroll
  for (int ks = 0; ks < 4; ++ks) {
    short8 a = *(const short8*)&Ts[(wave * 16 + n16) * LPAD + ks * 32 + quad * 8];
    #pragma unroll
    for (int qt = 0; qt < 8; ++qt) {
      short8 b = *(const short8*)&Qs[(qt * 16 + n16) * LPAD + ks * 32 + quad * 8];
      acc[qt] = __builtin_amdgcn_mfma_f32_16x16x32_bf16(a, b, acc[qt], 0, 0, 0);
    }
  }

  const int mbase = m0 + wave * 16 + quad * 4;   // sample index base, r=0..3 consecutive
  const float4 tnv = *(const float4*)&tn[mbase];
  #pragma unroll
  for (int qt = 0; qt < 8; ++qt) {
    const int q = qbase + qt * 16 + n16;
    const float base = qn[q];
    float4 dv;
    dv.x = fmaf(-2.0f, acc[qt][0], base + tnv.x);
    dv.y = fmaf(-2.0f, acc[qt][1], base + tnv.y);
    dv.z = fmaf(-2.0f, acc[qt][2], base + tnv.z);
    dv.w = fmaf(-2.0f, acc[qt][3], base + tnv.w);
    *(float4*)&sd_g[(size_t)q * NSAMP + mbase] = dv;
  }
}

// ---------------------------------------------------------------- k1b: min + histogram -> per-query threshold
__global__ __launch_bounds__(256) void k1b_pick(
    const float* __restrict__ sd_g, float* __restrict__ thr) {
  __shared__ float red[256];
  __shared__ int   hist[256];
  const int q = blockIdx.x, tid = threadIdx.x;
  const float* sd = sd_g + (size_t)q * NSAMP;
  float vals[16];
  float lm = FLT_MAX;
  #pragma unroll
  for (int k = 0; k < 16; ++k) {
    vals[k] = sd[k * 256 + tid];
    lm = fminf(lm, vals[k]);
  }
  red[tid] = lm;
  hist[tid] = 0;
  __syncthreads();
  for (int o = 128; o > 0; o >>= 1) {
    if (tid < o) red[tid] = fminf(red[tid], red[tid + o]);
    __syncthreads();
  }
  const float dmin = red[0];
  __syncthreads();
  #pragma unroll
  for (int k = 0; k < 16; ++k) {
    int b = (int)((vals[k] - dmin) * 3.2f);   // bin width 0.3125 over [dmin, dmin+80]
    b = b < 0 ? 0 : (b > 255 ? 255 : b);
    atomicAdd(&hist[b], 1);
  }
  __syncthreads();
  if (tid == 0) {
    int cum = 0; float Tq = dmin + 80.0f;
    for (int b = 0; b < 256; ++b) {
      cum += hist[b];
      if (cum >= RANK) { Tq = dmin + (float)(b + 1) * 0.3125f; break; }
    }
    thr[q] = Tq;
  }
}

// ---------------------------------------------------------------- k2: bf16 MFMA filter, slab-bucketed
__global__ __launch_bounds__(256) void k2_mfma(
    const float* __restrict__ Q, const float* __restrict__ T, int M, int slabn,
    const float* __restrict__ qn, const float* __restrict__ tn,
    const float* __restrict__ thr,
    int* __restrict__ cnt2, int* __restrict__ sure2, int* __restrict__ cand) {
  __shared__ short Ts[TROWS * LPAD];
  __shared__ short Qs[QROWS * LPAD];
  __shared__ int   lcnt[QROWS];
  __shared__ int   lsure[QROWS];
  __shared__ int   lent[QROWS * BKT];
  const int tid = threadIdx.x;
  const int slab = blockIdx.x;
  const int qbase = blockIdx.y * QROWS;
  const int sbeg = slab * slabn;
  const int send = min(sbeg + slabn, M);

  #pragma unroll
  for (int it = 0; it < 16; ++it) {
    int li = tid + it * 256;
    int row = li >> 5, z4 = li & 31;
    float4 v = *(const float4*)&Q[(size_t)(qbase + row) * ZD + z4 * 4];
    unsigned lo = (unsigned)f2bf(v.x) | ((unsigned)f2bf(v.y) << 16);
    unsigned hi = (unsigned)f2bf(v.z) | ((unsigned)f2bf(v.w) << 16);
    *(uint2*)&Qs[row * LPAD + z4 * 4] = make_uint2(lo, hi);
  }
  if (tid < QROWS) { lcnt[tid] = 0; lsure[tid] = 0; }

  const int wave = tid >> 6;
  const int lane = tid & 63;
  const int quad = lane >> 4;
  const int n16  = lane & 15;

  for (int m0 = sbeg; m0 < send; m0 += TROWS) {
    __syncthreads();
    #pragma unroll
    for (int it = 0; it < 8; ++it) {
      int li = tid + it * 256;
      int row = li >> 5, z4 = li & 31;
      int m = m0 + row;
      float4 v = make_float4(0.f, 0.f, 0.f, 0.f);
      if (m < send) v = *(const float4*)&T[(size_t)m * ZD + z4 * 4];
      unsigned lo = (unsigned)f2bf(v.x) | ((unsigned)f2bf(v.y) << 16);
      unsigned hi = (unsigned)f2bf(v.z) | ((unsigned)f2bf(v.w) << 16);
      *(uint2*)&Ts[row * LPAD + z4 * 4] = make_uint2(lo, hi);
    }
    __syncthreads();

    floatx4 acc[8];
    #pragma unroll
    for (int qt = 0; qt < 8; ++qt) acc[qt] = (floatx4)0.f;
    #pragma unroll
    for (int ks = 0; ks < 4; ++ks) {
      short8 a = *(const short8*)&Ts[(wave * 16 + n16) * LPAD + ks * 32 + quad * 8];
      #pragma unroll
      for (int qt = 0; qt < 8; ++qt) {
        short8 b = *(const short8*)&Qs[(qt * 16 + n16) * LPAD + ks * 32 + quad * 8];
        acc[qt] = __builtin_amdgcn_mfma_f32_16x16x32_bf16(a, b, acc[qt], 0, 0, 0);
      }
    }

    const int mbase = m0 + wave * 16 + quad * 4;
    float4 tnv = make_float4(0.f, 0.f, 0.f, 0.f);
    if (mbase + 3 < M) tnv = *(const float4*)&tn[mbase];
    else {
      if (mbase + 0 < M) tnv.x = tn[mbase + 0];
      if (mbase + 1 < M) tnv.y = tn[mbase + 1];
      if (mbase + 2 < M) tnv.z = tn[mbase + 2];
    }
    const float tns[4] = {tnv.x, tnv.y, tnv.z, tnv.w};
    #pragma unroll
    for (int qt = 0; qt < 8; ++qt) {
      const int ql = qt * 16 + n16;
      const int q = qbase + ql;
      const float base = qn[q];
      const float Tq = thr[q];
      #pragma unroll
      for (int r = 0; r < 4; ++r) {
        const int m = mbase + r;
        float dap = fmaf(-2.0f, acc[qt][r], base + tns[r]);
        if (m < send && dap < Tq + EPS) {
          int pos = atomicAdd(&lcnt[ql], 1);
          if (pos < BKT) lent[ql * BKT + pos] = m;
          if (dap < Tq - EPS) atomicAdd(&lsure[ql], 1);
        }
      }
    }
  }
  __syncthreads();
  if (tid < QROWS) {
    cnt2 [(size_t)(qbase + tid) * SLABS + slab] = lcnt[tid];
    sure2[(size_t)(qbase + tid) * SLABS + slab] = lsure[tid];
  }
  for (int li = tid; li < QROWS * BKT; li += 256) {
    int ql = li / BKT, j = li % BKT;
    int c = lcnt[ql]; if (c > BKT) c = BKT;
    if (j < c)
      cand[((size_t)(qbase + ql) * SLABS + slab) * BKT + j] = lent[li];
  }
}

// ---------------------------------------------------------------- k3a: per-query slab scan + validity
__global__ __launch_bounds__(256) void k3a_scan(
    const int* __restrict__ cnt2, const int* __restrict__ sure2,
    int* __restrict__ scanx, int* __restrict__ totals, int* __restrict__ validf) {
  const int q = blockIdx.x, tid = threadIdx.x;
  __shared__ int sscan[256];
  __shared__ int ssure, sovf;
  int c = cnt2[(size_t)q * SLABS + tid];
  int su = sure2[(size_t)q * SLABS + tid];
  if (tid == 0) { ssure = 0; sovf = 0; }
  __syncthreads();
  atomicAdd(&ssure, su);
  if (c > BKT) atomicOr(&sovf, 1);
  int val = c;
  sscan[tid] = val;
  __syncthreads();
  for (int o = 1; o < 256; o <<= 1) {
    int add = (tid >= o) ? sscan[tid - o] : 0;
    __syncthreads();
    val += add;
    sscan[tid] = val;
    __syncthreads();
  }
  scanx[(size_t)q * SLABS + tid] = val - c;   // exclusive offset
  const int total = sscan[255];
  if (tid == 0) {
    totals[q] = total;
    validf[q] = (sovf == 0 && ssure >= KK && total <= CAP) ? 1 : 0;
  }
}

// ---------------------------------------------------------------- k3b: parallel exact rescore -> packed keys
__global__ __launch_bounds__(256) void k3b_rescore(
    const float* __restrict__ Q, const float* __restrict__ T,
    const float* __restrict__ qn, const float* __restrict__ tn,
    const int* __restrict__ cnt2, const int* __restrict__ cand,
    const int* __restrict__ scanx, const int* __restrict__ validf,
    u64* __restrict__ keys) {
  const int q = blockIdx.x, ch = blockIdx.y, tid = threadIdx.x;
  if (!validf[q]) return;                  // uniform
  __shared__ float qv[ZD];
  for (int z = tid; z < ZD; z += 256) qv[z] = Q[(size_t)q * ZD + z];
  __syncthreads();
  const float qnv = qn[q];
  const int slab = ch * 64 + (tid >> 2);
  const int lane = tid & 3;
  const int c = min(cnt2[(size_t)q * SLABS + slab], BKT);
  const int off = scanx[(size_t)q * SLABS + slab];
  for (int k = lane; k < c; k += 4) {
    int idx = cand[((size_t)q * SLABS + slab) * BKT + k];
    const float* r = T + (size_t)idx * ZD;
    float dot = 0.f;     // sequential fmaf chain — matches prior passing rescore
    #pragma unroll 4
    for (int z4 = 0; z4 < 32; ++z4) {
      float4 v = *(const float4*)&r[z4 * 4];
      dot = fmaf(qv[z4 * 4 + 0], v.x, dot);
      dot = fmaf(qv[z4 * 4 + 1], v.y, dot);
      dot = fmaf(qv[z4 * 4 + 2], v.z, dot);
      dot = fmaf(qv[z4 * 4 + 3], v.w, dot);
    }
    float d = fmaf(-2.0f, dot, qnv + tn[idx]);
    keys[(size_t)q * CAP + off + k] = ((u64)fkey(d) << 32) | (unsigned)idx;
  }
}

// ---------------------------------------------------------------- k3c: histogram-select + small sort + softmax
__global__ __launch_bounds__(256) void k3c_select(
    const float* __restrict__ Q, const float* __restrict__ T, int M,
    const float* __restrict__ qn, const float* __restrict__ tn,
    const int* __restrict__ totals, const int* __restrict__ validf,
    const u64* __restrict__ keys_g,
    int* __restrict__ topi, float* __restrict__ emit) {
  __shared__ u64 key[CAP];
  __shared__ u64 buf[256];
  __shared__ unsigned redA[256], redB[256];
  __shared__ int hist[256];
  __shared__ int hscan[256];
  __shared__ float qv[ZD];
  __shared__ float cd[256];
  __shared__ float sdF[KK];
  __shared__ int   siF[KK];
  __shared__ float ebuf[KK];
  __shared__ float ssum;
  __shared__ int Bb, C2, ccnt, srcFlag;
  __shared__ unsigned kminS; __shared__ int shiftS;
  const int q = blockIdx.x, tid = threadIdx.x;
  const int total = totals[q];
  const bool valid = validf[q] != 0;

  if (valid) {
    for (int i = tid; i < CAP; i += 256)
      key[i] = (i < total) ? keys_g[(size_t)q * CAP + i] : ~0ULL;
    unsigned lmin = 0xFFFFFFFFu, lmax = 0u;
    for (int i = tid; i < total; i += 256) {
      unsigned h = (unsigned)(key[i] >> 32);
      lmin = min(lmin, h); lmax = max(lmax, h);
    }
    redA[tid] = lmin; redB[tid] = lmax;
    hist[tid] = 0;
    __syncthreads();
    for (int o = 128; o > 0; o >>= 1) {
      if (tid < o) {
        redA[tid] = min(redA[tid], redA[tid + o]);
        redB[tid] = max(redB[tid], redB[tid + o]);
      }
      __syncthreads();
    }
    if (tid == 0) {
      unsigned range = redB[0] - redA[0];
      int s = 0;
      while ((range >> s) > 255u) ++s;
      kminS = redA[0]; shiftS = s;
      ccnt = 0;
    }
    __syncthreads();
    const unsigned kmin = kminS; const int sh = shiftS;
    for (int i = tid; i < total; i += 256) {
      int b = (int)(((unsigned)(key[i] >> 32) - kmin) >> sh);
      atomicAdd(&hist[b], 1);
    }
    __syncthreads();
    int v0 = hist[tid];
    hscan[tid] = v0;
    __syncthreads();
    for (int o = 1; o < 256; o <<= 1) {
      int add = (tid >= o) ? hscan[tid - o] : 0;
      __syncthreads();
      v0 += add;
      hscan[tid] = v0;
      __syncthreads();
    }
    if (hscan[tid] >= KK && (tid == 0 || hscan[tid - 1] < KK)) {
      Bb = tid; C2 = hscan[tid];
    }
    __syncthreads();
    const int B = Bb, c2 = C2;
    if (c2 <= 256) {
      for (int i = tid; i < total; i += 256) {
        int b = (int)(((unsigned)(key[i] >> 32) - kmin) >> sh);
        if (b <= B) { int pos = atomicAdd(&ccnt, 1); buf[pos] = key[i]; }
      }
      __syncthreads();
      if (tid >= c2) buf[tid] = ~0ULL;
      __syncthreads();
      for (int k = 2; k <= 256; k <<= 1) {
        for (int j = k >> 1; j > 0; j >>= 1) {
          int x = tid ^ j;
          if (x > tid) {
            u64 a = buf[tid], b2 = buf[x];
            bool asc = ((tid & k) == 0);
            if ((a > b2) == asc) { buf[tid] = b2; buf[x] = a; }
          }
          __syncthreads();
        }
      }
      if (tid == 0) srcFlag = 0;
    } else {
      for (int k = 2; k <= CAP; k <<= 1) {
        for (int j = k >> 1; j > 0; j >>= 1) {
          for (int t = tid; t < CAP; t += 256) {
            int x = t ^ j;
            if (x > t) {
              u64 a = key[t], b2 = key[x];
              bool asc = ((t & k) == 0);
              if ((a > b2) == asc) { key[t] = b2; key[x] = a; }
            }
          }
          __syncthreads();
        }
      }
      if (tid == 0) srcFlag = 1;
    }
    __syncthreads();
  } else {
    // brute-force exact fallback (correctness net; ~never taken)
    for (int z = tid; z < ZD; z += 256) qv[z] = Q[(size_t)q * ZD + z];
    if (tid == 0) {
      for (int k = 0; k < KK; ++k) { sdF[k] = FLT_MAX; siF[k] = INT_MAX; }
      srcFlag = 0;
    }
    __syncthreads();
    const float qnv = qn[q];
    for (int base = 0; base < M; base += 256) {
      int m = base + tid; float d = FLT_MAX;
      if (m < M) {
        const float* r = T + (size_t)m * ZD;
        float dot = 0.f;
        for (int z = 0; z < ZD; ++z) dot = fmaf(qv[z], r[z], dot);
        d = fmaf(-2.0f, dot, qnv + tn[m]);
      }
      cd[tid] = d;
      __syncthreads();
      if (tid == 0) {
        for (int e = 0; e < 256; ++e) {
          float dd = cd[e]; int mm = base + e;
          if (dd < sdF[KK - 1] || (dd == sdF[KK - 1] && mm < siF[KK - 1])) {
            int pos = KK - 1;
            while (pos > 0 && (sdF[pos - 1] > dd || (sdF[pos - 1] == dd && siF[pos - 1] > mm))) {
              sdF[pos] = sdF[pos - 1]; siF[pos] = siF[pos - 1]; --pos;
            }
            sdF[pos] = dd; siF[pos] = mm;
          }
        }
      }
      __syncthreads();
    }
    if (tid < KK) buf[tid] = ((u64)fkey(sdF[tid]) << 32) | (unsigned)siF[tid];
    __syncthreads();
  }

  const int sf = srcFlag;
  if (tid == 0) {
    u64 k0v = sf ? key[0] : buf[0];
    float d0 = unfkey((unsigned)(k0v >> 32));
    float sum = 0.f;
    for (int k = 0; k < KK; ++k) {
      u64 kk = sf ? key[k] : buf[k];
      float e = expf(d0 - unfkey((unsigned)(kk >> 32)));
      ebuf[k] = e; sum += e;
    }
    ssum = sum;
  }
  __syncthreads();
  if (tid < KK) {
    u64 kk = sf ? key[tid] : buf[tid];
    emit[(size_t)q * KK + tid] = ebuf[tid] / ssum;
    topi[(size_t)q * KK + tid] = (int)(kk & 0xFFFFFFFFu);
  }
}

// ---------------------------------------------------------------- k4: transition matrices exp(-d)
__global__ __launch_bounds__(256) void k4_trans(
    const float* __restrict__ T, const int* __restrict__ topi,
    float* __restrict__ trans) {
  const int bt = blockIdx.x;                 // 0..251
  const int b = bt / (NT - 1), t = bt % (NT - 1);
  const int* iA = topi + (size_t)(b * NT + t) * KK;
  const int* iB = topi + (size_t)(b * NT + t + 1) * KK;
  __shared__ float As[KK * 132];
  __shared__ float Bs[20 * 132];
  __shared__ float an[KK];
  __shared__ float bn[20];
  const int tid = threadIdx.x;
  for (int li = tid; li < KK * 32; li += 256) {
    int row = li >> 5, z4 = li & 31;
    float4 v = *(const float4*)&T[(size_t)iA[row] * ZD + z4 * 4];
    *(float4*)&As[row * 132 + z4 * 4] = v;
  }
  __syncthreads();
  if (tid < KK) {
    float s = 0.f;
    for (int z = 0; z < ZD; ++z) s = fmaf(As[tid * 132 + z], As[tid * 132 + z], s);
    an[tid] = s;
  }
  for (int c = 0; c < 5; ++c) {
    __syncthreads();
    for (int li = tid; li < 20 * 32; li += 256) {
      int row = li >> 5, z4 = li & 31;
      float4 v = *(const float4*)&T[(size_t)iB[c * 20 + row] * ZD + z4 * 4];
      *(float4*)&Bs[row * 132 + z4 * 4] = v;
    }
    __syncthreads();
    if (tid < 20) {
      float s = 0.f;
      for (int z = 0; z < ZD; ++z) s = fmaf(Bs[tid * 132 + z], Bs[tid * 132 + z], s);
      bn[tid] = s;
    }
    __syncthreads();
    if (tid < 125) {
      const int i0 = (tid / 5) * 4, j0 = (tid % 5) * 4;
      float acc[16];
      #pragma unroll
      for (int x = 0; x < 16; ++x) acc[x] = 0.f;
      for (int z4 = 0; z4 < 32; ++z4) {
        float4 a[4], bb[4];
        #pragma unroll
        for (int r = 0; r < 4; ++r) a[r] = *(const float4*)&As[(i0 + r) * 132 + z4 * 4];
        #pragma unroll
        for (int s = 0; s < 4; ++s) bb[s] = *(const float4*)&Bs[(j0 + s) * 132 + z4 * 4];
        #pragma unroll
        for (int r = 0; r < 4; ++r) {
          #pragma unroll
          for (int s = 0; s < 4; ++s) {
            acc[r * 4 + s] = fmaf(a[r].x, bb[s].x, acc[r * 4 + s]);
            acc[r * 4 + s] = fmaf(a[r].y, bb[s].y, acc[r * 4 + s]);
            acc[r * 4 + s] = fmaf(a[r].z, bb[s].z, acc[r * 4 + s]);
            acc[r * 4 + s] = fmaf(a[r].w, bb[s].w, acc[r * 4 + s]);
          }
        }
      }
      float* trow = trans + (size_t)bt * KK * KK;
      #pragma unroll
      for (int r = 0; r < 4; ++r)
        for (int s = 0; s < 4; ++s) {
          float d = fmaf(-2.0f, acc[r * 4 + s], an[i0 + r] + bn[j0 + s]);
          trow[(i0 + r) * KK + c * 20 + j0 + s] = expf(-d);
        }
    }
  }
}

// ---------------------------------------------------------------- k5: Viterbi (prefetch + LDS backptrs + zflag)
__global__ __launch_bounds__(256) void k5_viterbi(
    const float* __restrict__ T, const int* __restrict__ topi,
    const float* __restrict__ emit, const float* __restrict__ trans,
    float* __restrict__ out) {
  const int b = blockIdx.x, tid = threadIdx.x;
  __shared__ float trS[KK * KK];
  __shared__ float v[KK], vn[KK];
  __shared__ float pb[200];
  __shared__ int   pi[200];
  __shared__ int   bpS[(NT - 1) * KK];   // 25.2 KB backptrs in LDS
  __shared__ int   path[NT];
  __shared__ float maxsh;
  __shared__ int   zflag;

  // preload tile 0 into registers
  float4 r[10];
  {
    const float* tr0 = trans + (size_t)(b * (NT - 1)) * KK * KK;
    #pragma unroll
    for (int i = 0; i < 10; ++i) {
      int li = tid + i * 256;
      if (li < 2500) r[i] = *(const float4*)&tr0[li * 4];
    }
  }
  if (tid < KK) v[tid] = emit[(size_t)(b * NT) * KK + tid];
  if (tid == 0) zflag = 0;
  __syncthreads();

  for (int t = 1; t < NT; ++t) {
    const int zf = zflag;   // uniform: last write precedes >=2 barriers
    if (zf == 0) {
      // commit prefetched tile (t-1) to LDS
      #pragma unroll
      for (int i = 0; i < 10; ++i) {
        int li = tid + i * 256;
        if (li < 2500) *(float4*)&trS[li * 4] = r[i];
      }
      __syncthreads();
      // issue loads for next tile while computing this one
      if (t < NT - 1) {
        const float* trn = trans + (size_t)(b * (NT - 1) + t) * KK * KK;
        #pragma unroll
        for (int i = 0; i < 10; ++i) {
          int li = tid + i * 256;
          if (li < 2500) r[i] = *(const float4*)&trn[li * 4];
        }
      }
      if (tid < 200) {
        const int j = tid % 100, half = tid / 100;
        const int ia = half * 50, ibnd = ia + 50;
        float best = -FLT_MAX; int bi = ia;
        for (int i = ia; i < ibnd; ++i) {
          float s = v[i] * trS[i * KK + j];
          if (s > best) { best = s; bi = i; }     // strict > == argmax-first
        }
        pb[tid] = best; pi[tid] = bi;
      }
      __syncthreads();
      if (tid < KK) {
        float b0 = pb[tid], b1 = pb[100 + tid];
        int   i0 = pi[tid], i1 = pi[100 + tid];
        float best = b0; int bi = i0;
        if (b1 > b0) { best = b1; bi = i1; }      // half-1 indices all larger
        vn[tid] = best * emit[(size_t)(b * NT + t) * KK + tid];
        bpS[(t - 1) * KK + tid] = bi;
      }
      __syncthreads();
      if (tid == 0) {
        float m = vn[0];
        for (int j = 1; j < KK; ++j) m = fmaxf(m, vn[j]);
        maxsh = m;
        if (m == 0.0f) zflag = 1;   // exact shortcut: all-zero v is absorbing
      }
      __syncthreads();
      if (tid < KK) v[tid] = vn[tid] / fmaxf(maxsh, 1e-30f);
    } else {
      // v == 0 everywhere: scores all +0 -> strict > fires only at i=0 -> backp=0, v stays 0
      if (tid < KK) bpS[(t - 1) * KK + tid] = 0;
    }
    __syncthreads();
  }
  if (tid == 0) {
    float best = -FLT_MAX; int last = 0;
    for (int j = 0; j < KK; ++j) if (v[j] > best) { best = v[j]; last = j; }
    path[NT - 1] = last;
    for (int tt = NT - 2; tt >= 0; --tt)
      path[tt] = bpS[tt * KK + path[tt + 1]];
  }
  __syncthreads();
  for (int li = tid; li < NT * ZD; li += 256) {
    int t = li >> 7, z = li & 127;
    out[(size_t)(b * NT + t) * ZD + z] =
        T[(size_t)topi[(size_t)(b * NT + t) * KK + path[t]] * ZD + z];
  }
}

// ---------------------------------------------------------------- host
extern "C" void kernel_launch(void* const* d_in, const int* in_sizes, int n_in,
                              void* d_out, int out_size, void* d_ws, size_t ws_size,
                              hipStream_t stream) {
  const float* Q = (const float*)d_in[0];     // (4,64,128) fp32
  const float* T = (const float*)d_in[1];     // (100000,128) fp32
  float* out = (float*)d_out;                 // (4,64,128) fp32
  const int M = in_sizes[1] / ZD;
  const int slabn = (M + SLABS - 1) / SLABS;  // 391 for M=100000

  char* p = (char*)d_ws;
  auto alloc = [&](size_t bytes) -> char* {
    char* r = p; p += (bytes + 511) & ~(size_t)511; return r;
  };
  float* qn     = (float*)alloc((size_t)NQ * 4);
  float* tn     = (float*)alloc((size_t)M * 4);
  float* thr    = (float*)alloc((size_t)NQ * 4);
  float* sd_g   = (float*)alloc((size_t)NQ * NSAMP * 4);
  int*   cnt2   = (int*)  alloc((size_t)NQ * SLABS * 4);
  int*   sure2  = (int*)  alloc((size_t)NQ * SLABS * 4);
  int*   cand   = (int*)  alloc((size_t)NQ * SLABS * BKT * 4);
  int*   scanx  = (int*)  alloc((size_t)NQ * SLABS * 4);
  int*   totals = (int*)  alloc((size_t)NQ * 4);
  int*   validf = (int*)  alloc((size_t)NQ * 4);
  u64*   keys   = (u64*)  alloc((size_t)NQ * CAP * 8);
  int*   topi   = (int*)  alloc((size_t)NQ * KK * 4);
  float* emit   = (float*)alloc((size_t)NQ * KK * 4);
  float* trans  = (float*)alloc((size_t)NB * (NT - 1) * KK * KK * 4);

  const int g0 = (M + NQ + 255) / 256;
  k0_norms<<<g0, 256, 0, stream>>>(Q, T, M, qn, tn);
  dim3 g1a(NSAMP / TROWS, NQ / QROWS);
  k1a_mfma<<<g1a, 256, 0, stream>>>(Q, T, qn, tn, sd_g);
  k1b_pick<<<NQ, 256, 0, stream>>>(sd_g, thr);
  dim3 g2(SLABS, NQ / QROWS);
  k2_mfma<<<g2, 256, 0, stream>>>(Q, T, M, slabn, qn, tn, thr, cnt2, sure2, cand);
  k3a_scan<<<NQ, 256, 0, stream>>>(cnt2, sure2, scanx, totals, validf);
  dim3 g3b(NQ, 4);
  k3b_rescore<<<g3b, 256, 0, stream>>>(Q, T, qn, tn, cnt2, cand, scanx, validf, keys);
  k3c_select<<<NQ, 256, 0, stream>>>(Q, T, M, qn, tn, totals, validf, keys, topi, emit);
  k4_trans<<<NB * (NT - 1), 256, 0, stream>>>(T, topi, trans);
  k5_viterbi<<<NB, 256, 0, stream>>>(T, topi, emit, trans, out);
}

// Round 9
// 255.288 us; speedup vs baseline: 61.6380x; 1.1130x over previous
//
#include <hip/hip_runtime.h>
#include <cfloat>
#include <climits>
#include <cstdint>
#include <cstddef>

#define ZD    128
#define NQ    256      // 4*64 queries
#define NB    4
#define NT    64
#define KK    100
#define CAP   2048     // R3-verified: per-query candidate totals stay <= 2048
#define NSAMP 4096
#define RANK  24
#define EPS   3.0f     // rigorous |d_bf16 - d_exact| bound (analysis: <= ~2.2)
#define SLABS 256
#define BKT   24       // per-(q,slab) bucket capacity
#define TROWS 64
#define QROWS 128
#define LPAD  136      // bf16 row stride (272 B), keeps 16B alignment

typedef __attribute__((ext_vector_type(8))) short  short8;   // 8 bf16 (4 VGPRs)
typedef __attribute__((ext_vector_type(4))) float  floatx4;  // mfma acc
typedef unsigned long long u64;

__device__ inline unsigned short f2bf(float f) {   // RNE fp32 -> bf16
  unsigned u = __builtin_bit_cast(unsigned, f);
  unsigned r = u + 0x7fffu + ((u >> 16) & 1u);
  return (unsigned short)(r >> 16);
}
__device__ inline unsigned fkey(float f) {         // monotone float->uint
  unsigned u = __builtin_bit_cast(unsigned, f);
  unsigned m = (u & 0x80000000u) ? 0xFFFFFFFFu : 0x80000000u;
  return u ^ m;
}
__device__ inline float unfkey(unsigned k) {       // inverse
  unsigned u = (k & 0x80000000u) ? (k ^ 0x80000000u) : ~k;
  return __builtin_bit_cast(float, u);
}

// ---------------------------------------------------------------- k0: norms
__global__ __launch_bounds__(256) void k0_norms(
    const float* __restrict__ Q, const float* __restrict__ T, int M,
    float* __restrict__ qn, float* __restrict__ tn) {
  int gid = blockIdx.x * 256 + threadIdx.x;
  if (gid < M) {
    const float* r = T + (size_t)gid * ZD;
    float s = 0.f;
    #pragma unroll
    for (int z4 = 0; z4 < 32; ++z4) {
      float4 v = *(const float4*)&r[z4 * 4];
      s = fmaf(v.x, v.x, s); s = fmaf(v.y, v.y, s);
      s = fmaf(v.z, v.z, s); s = fmaf(v.w, v.w, s);
    }
    tn[gid] = s;
  } else if (gid < M + NQ) {
    int q = gid - M;
    const float* r = Q + (size_t)q * ZD;
    float s = 0.f;
    #pragma unroll
    for (int z4 = 0; z4 < 32; ++z4) {
      float4 v = *(const float4*)&r[z4 * 4];
      s = fmaf(v.x, v.x, s); s = fmaf(v.y, v.y, s);
      s = fmaf(v.z, v.z, s); s = fmaf(v.w, v.w, s);
    }
    qn[q] = s;
  }
}

// ---------------------------------------------------------------- k1a: sample distances via MFMA (k2-style)
__global__ __launch_bounds__(256) void k1a_mfma(
    const float* __restrict__ Q, const float* __restrict__ T,
    const float* __restrict__ qn, const float* __restrict__ tn,
    float* __restrict__ sd_g) {
  __shared__ short Ts[TROWS * LPAD];
  __shared__ short Qs[QROWS * LPAD];
  const int tid = threadIdx.x;
  const int m0 = blockIdx.x * TROWS;        // within [0, NSAMP)
  const int qbase = blockIdx.y * QROWS;

  #pragma unroll
  for (int it = 0; it < 16; ++it) {
    int li = tid + it * 256;
    int row = li >> 5, z4 = li & 31;
    float4 v = *(const float4*)&Q[(size_t)(qbase + row) * ZD + z4 * 4];
    unsigned lo = (unsigned)f2bf(v.x) | ((unsigned)f2bf(v.y) << 16);
    unsigned hi = (unsigned)f2bf(v.z) | ((unsigned)f2bf(v.w) << 16);
    *(uint2*)&Qs[row * LPAD + z4 * 4] = make_uint2(lo, hi);
  }
  #pragma unroll
  for (int it = 0; it < 8; ++it) {
    int li = tid + it * 256;
    int row = li >> 5, z4 = li & 31;
    float4 v = *(const float4*)&T[(size_t)(m0 + row) * ZD + z4 * 4];
    unsigned lo = (unsigned)f2bf(v.x) | ((unsigned)f2bf(v.y) << 16);
    unsigned hi = (unsigned)f2bf(v.z) | ((unsigned)f2bf(v.w) << 16);
    *(uint2*)&Ts[row * LPAD + z4 * 4] = make_uint2(lo, hi);
  }
  __syncthreads();

  const int wave = tid >> 6;
  const int lane = tid & 63;
  const int quad = lane >> 4;
  const int n16  = lane & 15;

  floatx4 acc[8];
  #pragma unroll
  for (int qt = 0; qt < 8; ++qt) acc[qt] = (floatx4)0.f;
  #pragma unroll
  for (int ks = 0; ks < 4; ++ks) {
    short8 a = *(const short8*)&Ts[(wave * 16 + n16) * LPAD + ks * 32 + quad * 8];
    #pragma unroll
    for (int qt = 0; qt < 8; ++qt) {
      short8 b = *(const short8*)&Qs[(qt * 16 + n16) * LPAD + ks * 32 + quad * 8];
      acc[qt] = __builtin_amdgcn_mfma_f32_16x16x32_bf16(a, b, acc[qt], 0, 0, 0);
    }
  }

  const int mbase = m0 + wave * 16 + quad * 4;
  const float4 tnv = *(const float4*)&tn[mbase];
  #pragma unroll
  for (int qt = 0; qt < 8; ++qt) {
    const int q = qbase + qt * 16 + n16;
    const float base = qn[q];
    float4 dv;
    dv.x = fmaf(-2.0f, acc[qt][0], base + tnv.x);
    dv.y = fmaf(-2.0f, acc[qt][1], base + tnv.y);
    dv.z = fmaf(-2.0f, acc[qt][2], base + tnv.z);
    dv.w = fmaf(-2.0f, acc[qt][3], base + tnv.w);
    *(float4*)&sd_g[(size_t)q * NSAMP + mbase] = dv;
  }
}

// ---------------------------------------------------------------- k1b: min + histogram -> per-query threshold
__global__ __launch_bounds__(256) void k1b_pick(
    const float* __restrict__ sd_g, float* __restrict__ thr) {
  __shared__ float red[256];
  __shared__ int   hist[256];
  const int q = blockIdx.x, tid = threadIdx.x;
  const float* sd = sd_g + (size_t)q * NSAMP;
  float vals[16];
  float lm = FLT_MAX;
  #pragma unroll
  for (int k = 0; k < 16; ++k) {
    vals[k] = sd[k * 256 + tid];
    lm = fminf(lm, vals[k]);
  }
  red[tid] = lm;
  hist[tid] = 0;
  __syncthreads();
  for (int o = 128; o > 0; o >>= 1) {
    if (tid < o) red[tid] = fminf(red[tid], red[tid + o]);
    __syncthreads();
  }
  const float dmin = red[0];
  __syncthreads();
  #pragma unroll
  for (int k = 0; k < 16; ++k) {
    int b = (int)((vals[k] - dmin) * 3.2f);   // bin width 0.3125 over [dmin, dmin+80]
    b = b < 0 ? 0 : (b > 255 ? 255 : b);
    atomicAdd(&hist[b], 1);
  }
  __syncthreads();
  if (tid == 0) {
    int cum = 0; float Tq = dmin + 80.0f;
    for (int b = 0; b < 256; ++b) {
      cum += hist[b];
      if (cum >= RANK) { Tq = dmin + (float)(b + 1) * 0.3125f; break; }
    }
    thr[q] = Tq;
  }
}

// ---------------------------------------------------------------- k2: bf16 MFMA filter, reg-prefetch dbuf
__global__ __launch_bounds__(256, 4) void k2_mfma(
    const float* __restrict__ Q, const float* __restrict__ T, int M, int slabn,
    const float* __restrict__ qn, const float* __restrict__ tn,
    const float* __restrict__ thr,
    int* __restrict__ cnt2, int* __restrict__ sure2, int* __restrict__ cand) {
  __shared__ short Ts[TROWS * LPAD];
  __shared__ short Qs[QROWS * LPAD];
  __shared__ int   lcnt[QROWS];
  __shared__ int   lsure[QROWS];
  __shared__ int   lent[QROWS * BKT];
  const int tid = threadIdx.x;
  const int slab = blockIdx.x;
  const int qbase = blockIdx.y * QROWS;
  const int sbeg = slab * slabn;
  const int send = min(sbeg + slabn, M);

  #pragma unroll
  for (int it = 0; it < 16; ++it) {
    int li = tid + it * 256;
    int row = li >> 5, z4 = li & 31;
    float4 v = *(const float4*)&Q[(size_t)(qbase + row) * ZD + z4 * 4];
    unsigned lo = (unsigned)f2bf(v.x) | ((unsigned)f2bf(v.y) << 16);
    unsigned hi = (unsigned)f2bf(v.z) | ((unsigned)f2bf(v.w) << 16);
    *(uint2*)&Qs[row * LPAD + z4 * 4] = make_uint2(lo, hi);
  }
  if (tid < QROWS) { lcnt[tid] = 0; lsure[tid] = 0; }

  const int wave = tid >> 6;
  const int lane = tid & 63;
  const int quad = lane >> 4;
  const int n16  = lane & 15;

  // register prefetch of first T tile (8 float4/thread)
  float4 pf[8];
  #pragma unroll
  for (int it = 0; it < 8; ++it) {
    int li = tid + it * 256;
    int row = li >> 5, z4 = li & 31;
    int m = sbeg + row;
    pf[it] = make_float4(0.f, 0.f, 0.f, 0.f);
    if (m < send) pf[it] = *(const float4*)&T[(size_t)m * ZD + z4 * 4];
  }

  for (int m0 = sbeg; m0 < send; m0 += TROWS) {
    __syncthreads();   // prev tile's readers done (and Qs published on iter 0)
    // commit prefetched tile: fp32->bf16 convert + LDS write
    #pragma unroll
    for (int it = 0; it < 8; ++it) {
      int li = tid + it * 256;
      int row = li >> 5, z4 = li & 31;
      unsigned lo = (unsigned)f2bf(pf[it].x) | ((unsigned)f2bf(pf[it].y) << 16);
      unsigned hi = (unsigned)f2bf(pf[it].z) | ((unsigned)f2bf(pf[it].w) << 16);
      *(uint2*)&Ts[row * LPAD + z4 * 4] = make_uint2(lo, hi);
    }
    __syncthreads();
    // issue next tile's global loads — overlap with MFMA below
    if (m0 + TROWS < send) {
      #pragma unroll
      for (int it = 0; it < 8; ++it) {
        int li = tid + it * 256;
        int row = li >> 5, z4 = li & 31;
        int m = m0 + TROWS + row;
        pf[it] = make_float4(0.f, 0.f, 0.f, 0.f);
        if (m < send) pf[it] = *(const float4*)&T[(size_t)m * ZD + z4 * 4];
      }
    }

    floatx4 acc[8];
    #pragma unroll
    for (int qt = 0; qt < 8; ++qt) acc[qt] = (floatx4)0.f;
    #pragma unroll
    for (int ks = 0; ks < 4; ++ks) {
      short8 a = *(const short8*)&Ts[(wave * 16 + n16) * LPAD + ks * 32 + quad * 8];
      #pragma unroll
      for (int qt = 0; qt < 8; ++qt) {
        short8 b = *(const short8*)&Qs[(qt * 16 + n16) * LPAD + ks * 32 + quad * 8];
        acc[qt] = __builtin_amdgcn_mfma_f32_16x16x32_bf16(a, b, acc[qt], 0, 0, 0);
      }
    }

    const int mbase = m0 + wave * 16 + quad * 4;
    float4 tnv = make_float4(0.f, 0.f, 0.f, 0.f);
    if (mbase + 3 < M) tnv = *(const float4*)&tn[mbase];
    else {
      if (mbase + 0 < M) tnv.x = tn[mbase + 0];
      if (mbase + 1 < M) tnv.y = tn[mbase + 1];
      if (mbase + 2 < M) tnv.z = tn[mbase + 2];
    }
    const float tns[4] = {tnv.x, tnv.y, tnv.z, tnv.w};
    #pragma unroll
    for (int qt = 0; qt < 8; ++qt) {
      const int ql = qt * 16 + n16;
      const int q = qbase + ql;
      const float base = qn[q];
      const float Tq = thr[q];
      #pragma unroll
      for (int r = 0; r < 4; ++r) {
        const int m = mbase + r;
        float dap = fmaf(-2.0f, acc[qt][r], base + tns[r]);
        if (m < send && dap < Tq + EPS) {
          int pos = atomicAdd(&lcnt[ql], 1);
          if (pos < BKT) lent[ql * BKT + pos] = m;
          if (dap < Tq - EPS) atomicAdd(&lsure[ql], 1);
        }
      }
    }
  }
  __syncthreads();
  if (tid < QROWS) {
    cnt2 [(size_t)(qbase + tid) * SLABS + slab] = lcnt[tid];
    sure2[(size_t)(qbase + tid) * SLABS + slab] = lsure[tid];
  }
  for (int li = tid; li < QROWS * BKT; li += 256) {
    int ql = li / BKT, j = li % BKT;
    int c = lcnt[ql]; if (c > BKT) c = BKT;
    if (j < c)
      cand[((size_t)(qbase + ql) * SLABS + slab) * BKT + j] = lent[li];
  }
}

// ---------------------------------------------------------------- k3a: per-query slab scan + validity
__global__ __launch_bounds__(256) void k3a_scan(
    const int* __restrict__ cnt2, const int* __restrict__ sure2,
    int* __restrict__ scanx, int* __restrict__ totals, int* __restrict__ validf) {
  const int q = blockIdx.x, tid = threadIdx.x;
  __shared__ int sscan[256];
  __shared__ int ssure, sovf;
  int c = cnt2[(size_t)q * SLABS + tid];
  int su = sure2[(size_t)q * SLABS + tid];
  if (tid == 0) { ssure = 0; sovf = 0; }
  __syncthreads();
  atomicAdd(&ssure, su);
  if (c > BKT) atomicOr(&sovf, 1);
  int val = c;
  sscan[tid] = val;
  __syncthreads();
  for (int o = 1; o < 256; o <<= 1) {
    int add = (tid >= o) ? sscan[tid - o] : 0;
    __syncthreads();
    val += add;
    sscan[tid] = val;
    __syncthreads();
  }
  scanx[(size_t)q * SLABS + tid] = val - c;   // exclusive offset
  const int total = sscan[255];
  if (tid == 0) {
    totals[q] = total;
    validf[q] = (sovf == 0 && ssure >= KK && total <= CAP) ? 1 : 0;
  }
}

// ---------------------------------------------------------------- k3b: parallel exact rescore -> packed keys
__global__ __launch_bounds__(256) void k3b_rescore(
    const float* __restrict__ Q, const float* __restrict__ T,
    const float* __restrict__ qn, const float* __restrict__ tn,
    const int* __restrict__ cnt2, const int* __restrict__ cand,
    const int* __restrict__ scanx, const int* __restrict__ validf,
    u64* __restrict__ keys) {
  const int q = blockIdx.x, ch = blockIdx.y, tid = threadIdx.x;
  if (!validf[q]) return;                  // uniform
  __shared__ float qv[ZD];
  for (int z = tid; z < ZD; z += 256) qv[z] = Q[(size_t)q * ZD + z];
  __syncthreads();
  const float qnv = qn[q];
  const int slab = ch * 64 + (tid >> 2);
  const int lane = tid & 3;
  const int c = min(cnt2[(size_t)q * SLABS + slab], BKT);
  const int off = scanx[(size_t)q * SLABS + slab];
  for (int k = lane; k < c; k += 4) {
    int idx = cand[((size_t)q * SLABS + slab) * BKT + k];
    const float* r = T + (size_t)idx * ZD;
    float dot = 0.f;     // sequential fmaf chain — matches prior passing rescore
    #pragma unroll 4
    for (int z4 = 0; z4 < 32; ++z4) {
      float4 v = *(const float4*)&r[z4 * 4];
      dot = fmaf(qv[z4 * 4 + 0], v.x, dot);
      dot = fmaf(qv[z4 * 4 + 1], v.y, dot);
      dot = fmaf(qv[z4 * 4 + 2], v.z, dot);
      dot = fmaf(qv[z4 * 4 + 3], v.w, dot);
    }
    float d = fmaf(-2.0f, dot, qnv + tn[idx]);
    keys[(size_t)q * CAP + off + k] = ((u64)fkey(d) << 32) | (unsigned)idx;
  }
}

// ---------------------------------------------------------------- k3c: histogram-select + small sort + softmax
__global__ __launch_bounds__(256) void k3c_select(
    const float* __restrict__ Q, const float* __restrict__ T, int M,
    const float* __restrict__ qn, const float* __restrict__ tn,
    const int* __restrict__ totals, const int* __restrict__ validf,
    const u64* __restrict__ keys_g,
    int* __restrict__ topi, float* __restrict__ emit) {
  __shared__ u64 key[CAP];
  __shared__ u64 buf[256];
  __shared__ unsigned redA[256], redB[256];
  __shared__ int hist[256];
  __shared__ int hscan[256];
  __shared__ float qv[ZD];
  __shared__ float cd[256];
  __shared__ float sdF[KK];
  __shared__ int   siF[KK];
  __shared__ float ebuf[KK];
  __shared__ float ssum;
  __shared__ int Bb, C2, ccnt, srcFlag;
  __shared__ unsigned kminS; __shared__ int shiftS;
  const int q = blockIdx.x, tid = threadIdx.x;
  const int total = totals[q];
  const bool valid = validf[q] != 0;

  if (valid) {
    for (int i = tid; i < CAP; i += 256)
      key[i] = (i < total) ? keys_g[(size_t)q * CAP + i] : ~0ULL;
    unsigned lmin = 0xFFFFFFFFu, lmax = 0u;
    for (int i = tid; i < total; i += 256) {
      unsigned h = (unsigned)(key[i] >> 32);
      lmin = min(lmin, h); lmax = max(lmax, h);
    }
    redA[tid] = lmin; redB[tid] = lmax;
    hist[tid] = 0;
    __syncthreads();
    for (int o = 128; o > 0; o >>= 1) {
      if (tid < o) {
        redA[tid] = min(redA[tid], redA[tid + o]);
        redB[tid] = max(redB[tid], redB[tid + o]);
      }
      __syncthreads();
    }
    if (tid == 0) {
      unsigned range = redB[0] - redA[0];
      int s = 0;
      while ((range >> s) > 255u) ++s;
      kminS = redA[0]; shiftS = s;
      ccnt = 0;
    }
    __syncthreads();
    const unsigned kmin = kminS; const int sh = shiftS;
    for (int i = tid; i < total; i += 256) {
      int b = (int)(((unsigned)(key[i] >> 32) - kmin) >> sh);
      atomicAdd(&hist[b], 1);
    }
    __syncthreads();
    int v0 = hist[tid];
    hscan[tid] = v0;
    __syncthreads();
    for (int o = 1; o < 256; o <<= 1) {
      int add = (tid >= o) ? hscan[tid - o] : 0;
      __syncthreads();
      v0 += add;
      hscan[tid] = v0;
      __syncthreads();
    }
    if (hscan[tid] >= KK && (tid == 0 || hscan[tid - 1] < KK)) {
      Bb = tid; C2 = hscan[tid];
    }
    __syncthreads();
    const int B = Bb, c2 = C2;
    if (c2 <= 256) {
      for (int i = tid; i < total; i += 256) {
        int b = (int)(((unsigned)(key[i] >> 32) - kmin) >> sh);
        if (b <= B) { int pos = atomicAdd(&ccnt, 1); buf[pos] = key[i]; }
      }
      __syncthreads();
      if (tid >= c2) buf[tid] = ~0ULL;
      __syncthreads();
      for (int k = 2; k <= 256; k <<= 1) {
        for (int j = k >> 1; j > 0; j >>= 1) {
          int x = tid ^ j;
          if (x > tid) {
            u64 a = buf[tid], b2 = buf[x];
            bool asc = ((tid & k) == 0);
            if ((a > b2) == asc) { buf[tid] = b2; buf[x] = a; }
          }
          __syncthreads();
        }
      }
      if (tid == 0) srcFlag = 0;
    } else {
      for (int k = 2; k <= CAP; k <<= 1) {
        for (int j = k >> 1; j > 0; j >>= 1) {
          for (int t = tid; t < CAP; t += 256) {
            int x = t ^ j;
            if (x > t) {
              u64 a = key[t], b2 = key[x];
              bool asc = ((t & k) == 0);
              if ((a > b2) == asc) { key[t] = b2; key[x] = a; }
            }
          }
          __syncthreads();
        }
      }
      if (tid == 0) srcFlag = 1;
    }
    __syncthreads();
  } else {
    // brute-force exact fallback (correctness net; ~never taken)
    for (int z = tid; z < ZD; z += 256) qv[z] = Q[(size_t)q * ZD + z];
    if (tid == 0) {
      for (int k = 0; k < KK; ++k) { sdF[k] = FLT_MAX; siF[k] = INT_MAX; }
      srcFlag = 0;
    }
    __syncthreads();
    const float qnv = qn[q];
    for (int base = 0; base < M; base += 256) {
      int m = base + tid; float d = FLT_MAX;
      if (m < M) {
        const float* r = T + (size_t)m * ZD;
        float dot = 0.f;
        for (int z = 0; z < ZD; ++z) dot = fmaf(qv[z], r[z], dot);
        d = fmaf(-2.0f, dot, qnv + tn[m]);
      }
      cd[tid] = d;
      __syncthreads();
      if (tid == 0) {
        for (int e = 0; e < 256; ++e) {
          float dd = cd[e]; int mm = base + e;
          if (dd < sdF[KK - 1] || (dd == sdF[KK - 1] && mm < siF[KK - 1])) {
            int pos = KK - 1;
            while (pos > 0 && (sdF[pos - 1] > dd || (sdF[pos - 1] == dd && siF[pos - 1] > mm))) {
              sdF[pos] = sdF[pos - 1]; siF[pos] = siF[pos - 1]; --pos;
            }
            sdF[pos] = dd; siF[pos] = mm;
          }
        }
      }
      __syncthreads();
    }
    if (tid < KK) buf[tid] = ((u64)fkey(sdF[tid]) << 32) | (unsigned)siF[tid];
    __syncthreads();
  }

  const int sf = srcFlag;
  if (tid == 0) {
    u64 k0v = sf ? key[0] : buf[0];
    float d0 = unfkey((unsigned)(k0v >> 32));
    float sum = 0.f;
    for (int k = 0; k < KK; ++k) {
      u64 kk = sf ? key[k] : buf[k];
      float e = expf(d0 - unfkey((unsigned)(kk >> 32)));
      ebuf[k] = e; sum += e;
    }
    ssum = sum;
  }
  __syncthreads();
  if (tid < KK) {
    u64 kk = sf ? key[tid] : buf[tid];
    emit[(size_t)q * KK + tid] = ebuf[tid] / ssum;
    topi[(size_t)q * KK + tid] = (int)(kk & 0xFFFFFFFFu);
  }
}

// ---------------------------------------------------------------- k4: transitions — full 256-thread, 7x7 reg tiles
__global__ __launch_bounds__(256) void k4_trans(
    const float* __restrict__ T, const int* __restrict__ topi,
    float* __restrict__ trans) {
  const int bt = blockIdx.x;                 // 0..251
  const int b = bt / (NT - 1), t = bt % (NT - 1);
  const int* iA = topi + (size_t)(b * NT + t) * KK;
  const int* iB = topi + (size_t)(b * NT + t + 1) * KK;
  __shared__ float As[KK * 132];             // 52.8 KB
  __shared__ float Bs[KK * 132];             // 52.8 KB (1 block/CU anyway: grid=252)
  __shared__ float an[KK];
  __shared__ float bn[KK];
  const int tid = threadIdx.x;
  for (int li = tid; li < KK * 32; li += 256) {
    int row = li >> 5, z4 = li & 31;
    *(float4*)&As[row * 132 + z4 * 4] = *(const float4*)&T[(size_t)iA[row] * ZD + z4 * 4];
    *(float4*)&Bs[row * 132 + z4 * 4] = *(const float4*)&T[(size_t)iB[row] * ZD + z4 * 4];
  }
  __syncthreads();
  if (tid < KK) {                            // same sequential-z chain as before
    float s = 0.f;
    for (int z = 0; z < ZD; ++z) s = fmaf(As[tid * 132 + z], As[tid * 132 + z], s);
    an[tid] = s;
  } else if (tid < 2 * KK) {
    int r = tid - KK;
    float s = 0.f;
    for (int z = 0; z < ZD; ++z) s = fmaf(Bs[r * 132 + z], Bs[r * 132 + z], s);
    bn[r] = s;
  }
  __syncthreads();
  const int tx = tid & 15, ty = tid >> 4;    // 16x16 grid; rows ty+16k, cols tx+16m (k,m<7)
  float acc[7][7];
  #pragma unroll
  for (int k = 0; k < 7; ++k)
    #pragma unroll
    for (int m = 0; m < 7; ++m) acc[k][m] = 0.f;
  int rr[7], cc[7];
  #pragma unroll
  for (int k = 0; k < 7; ++k) { rr[k] = min(ty + 16 * k, KK - 1); cc[k] = min(tx + 16 * k, KK - 1); }
  for (int z4 = 0; z4 < 32; ++z4) {
    float4 a[7], bb[7];
    #pragma unroll
    for (int k = 0; k < 7; ++k) a[k] = *(const float4*)&As[rr[k] * 132 + z4 * 4];
    #pragma unroll
    for (int m = 0; m < 7; ++m) bb[m] = *(const float4*)&Bs[cc[m] * 132 + z4 * 4];
    #pragma unroll
    for (int k = 0; k < 7; ++k)
      #pragma unroll
      for (int m = 0; m < 7; ++m) {         // sequential-z fmaf order preserved
        acc[k][m] = fmaf(a[k].x, bb[m].x, acc[k][m]);
        acc[k][m] = fmaf(a[k].y, bb[m].y, acc[k][m]);
        acc[k][m] = fmaf(a[k].z, bb[m].z, acc[k][m]);
        acc[k][m] = fmaf(a[k].w, bb[m].w, acc[k][m]);
      }
  }
  float* trow = trans + (size_t)bt * KK * KK;
  #pragma unroll
  for (int k = 0; k < 7; ++k) {
    int r = ty + 16 * k;
    if (r < KK) {
      #pragma unroll
      for (int m = 0; m < 7; ++m) {
        int c = tx + 16 * m;
        if (c < KK) {
          float d = fmaf(-2.0f, acc[k][m], an[r] + bn[c]);
          trow[r * KK + c] = expf(-d);
        }
      }
    }
  }
}

// ---------------------------------------------------------------- k5: Viterbi (prefetch + LDS backptrs + zflag)
__global__ __launch_bounds__(256) void k5_viterbi(
    const float* __restrict__ T, const int* __restrict__ topi,
    const float* __restrict__ emit, const float* __restrict__ trans,
    float* __restrict__ out) {
  const int b = blockIdx.x, tid = threadIdx.x;
  __shared__ float trS[KK * KK];
  __shared__ float v[KK], vn[KK];
  __shared__ float pb[200];
  __shared__ int   pi[200];
  __shared__ int   bpS[(NT - 1) * KK];   // 25.2 KB backptrs in LDS
  __shared__ int   path[NT];
  __shared__ float maxsh;
  __shared__ int   zflag;

  float4 r[10];
  {
    const float* tr0 = trans + (size_t)(b * (NT - 1)) * KK * KK;
    #pragma unroll
    for (int i = 0; i < 10; ++i) {
      int li = tid + i * 256;
      if (li < 2500) r[i] = *(const float4*)&tr0[li * 4];
    }
  }
  if (tid < KK) v[tid] = emit[(size_t)(b * NT) * KK + tid];
  if (tid == 0) zflag = 0;
  __syncthreads();

  for (int t = 1; t < NT; ++t) {
    const int zf = zflag;   // uniform: last write precedes >=2 barriers
    if (zf == 0) {
      #pragma unroll
      for (int i = 0; i < 10; ++i) {
        int li = tid + i * 256;
        if (li < 2500) *(float4*)&trS[li * 4] = r[i];
      }
      __syncthreads();
      if (t < NT - 1) {
        const float* trn = trans + (size_t)(b * (NT - 1) + t) * KK * KK;
        #pragma unroll
        for (int i = 0; i < 10; ++i) {
          int li = tid + i * 256;
          if (li < 2500) r[i] = *(const float4*)&trn[li * 4];
        }
      }
      if (tid < 200) {
        const int j = tid % 100, half = tid / 100;
        const int ia = half * 50, ibnd = ia + 50;
        float best = -FLT_MAX; int bi = ia;
        for (int i = ia; i < ibnd; ++i) {
          float s = v[i] * trS[i * KK + j];
          if (s > best) { best = s; bi = i; }     // strict > == argmax-first
        }
        pb[tid] = best; pi[tid] = bi;
      }
      __syncthreads();
      if (tid < KK) {
        float b0 = pb[tid], b1 = pb[100 + tid];
        int   i0 = pi[tid], i1 = pi[100 + tid];
        float best = b0; int bi = i0;
        if (b1 > b0) { best = b1; bi = i1; }      // half-1 indices all larger
        vn[tid] = best * emit[(size_t)(b * NT + t) * KK + tid];
        bpS[(t - 1) * KK + tid] = bi;
      }
      __syncthreads();
      if (tid == 0) {
        float m = vn[0];
        for (int j = 1; j < KK; ++j) m = fmaxf(m, vn[j]);
        maxsh = m;
        if (m == 0.0f) zflag = 1;   // exact shortcut: all-zero v is absorbing
      }
      __syncthreads();
      if (tid < KK) v[tid] = vn[tid] / fmaxf(maxsh, 1e-30f);
    } else {
      if (tid < KK) bpS[(t - 1) * KK + tid] = 0;
    }
    __syncthreads();
  }
  if (tid == 0) {
    float best = -FLT_MAX; int last = 0;
    for (int j = 0; j < KK; ++j) if (v[j] > best) { best = v[j]; last = j; }
    path[NT - 1] = last;
    for (int tt = NT - 2; tt >= 0; --tt)
      path[tt] = bpS[tt * KK + path[tt + 1]];
  }
  __syncthreads();
  for (int li = tid; li < NT * ZD; li += 256) {
    int t = li >> 7, z = li & 127;
    out[(size_t)(b * NT + t) * ZD + z] =
        T[(size_t)topi[(size_t)(b * NT + t) * KK + path[t]] * ZD + z];
  }
}

// ---------------------------------------------------------------- host
extern "C" void kernel_launch(void* const* d_in, const int* in_sizes, int n_in,
                              void* d_out, int out_size, void* d_ws, size_t ws_size,
                              hipStream_t stream) {
  const float* Q = (const float*)d_in[0];     // (4,64,128) fp32
  const float* T = (const float*)d_in[1];     // (100000,128) fp32
  float* out = (float*)d_out;                 // (4,64,128) fp32
  const int M = in_sizes[1] / ZD;
  const int slabn = (M + SLABS - 1) / SLABS;  // 391 for M=100000

  char* p = (char*)d_ws;
  auto alloc = [&](size_t bytes) -> char* {
    char* r = p; p += (bytes + 511) & ~(size_t)511; return r;
  };
  float* qn     = (float*)alloc((size_t)NQ * 4);
  float* tn     = (float*)alloc((size_t)M * 4);
  float* thr    = (float*)alloc((size_t)NQ * 4);
  float* sd_g   = (float*)alloc((size_t)NQ * NSAMP * 4);
  int*   cnt2   = (int*)  alloc((size_t)NQ * SLABS * 4);
  int*   sure2  = (int*)  alloc((size_t)NQ * SLABS * 4);
  int*   cand   = (int*)  alloc((size_t)NQ * SLABS * BKT * 4);
  int*   scanx  = (int*)  alloc((size_t)NQ * SLABS * 4);
  int*   totals = (int*)  alloc((size_t)NQ * 4);
  int*   validf = (int*)  alloc((size_t)NQ * 4);
  u64*   keys   = (u64*)  alloc((size_t)NQ * CAP * 8);
  int*   topi   = (int*)  alloc((size_t)NQ * KK * 4);
  float* emit   = (float*)alloc((size_t)NQ * KK * 4);
  float* trans  = (float*)alloc((size_t)NB * (NT - 1) * KK * KK * 4);

  const int g0 = (M + NQ + 255) / 256;
  k0_norms<<<g0, 256, 0, stream>>>(Q, T, M, qn, tn);
  dim3 g1a(NSAMP / TROWS, NQ / QROWS);
  k1a_mfma<<<g1a, 256, 0, stream>>>(Q, T, qn, tn, sd_g);
  k1b_pick<<<NQ, 256, 0, stream>>>(sd_g, thr);
  dim3 g2(SLABS, NQ / QROWS);
  k2_mfma<<<g2, 256, 0, stream>>>(Q, T, M, slabn, qn, tn, thr, cnt2, sure2, cand);
  k3a_scan<<<NQ, 256, 0, stream>>>(cnt2, sure2, scanx, totals, validf);
  dim3 g3b(NQ, 4);
  k3b_rescore<<<g3b, 256, 0, stream>>>(Q, T, qn, tn, cnt2, cand, scanx, validf, keys);
  k3c_select<<<NQ, 256, 0, stream>>>(Q, T, M, qn, tn, totals, validf, keys, topi, emit);
  k4_trans<<<NB * (NT - 1), 256, 0, stream>>>(T, topi, trans);
  k5_viterbi<<<NB, 256, 0, stream>>>(T, topi, emit, trans, out);
}

// Round 10
// 250.829 us; speedup vs baseline: 62.7336x; 1.0178x over previous
//
#include <hip/hip_runtime.h>
#include <cfloat>
#include <climits>
#include <cstdint>
#include <cstddef>

#define ZD    128
#define NQ    256      // 4*64 queries
#define NB    4
#define NT    64
#define KK    100
#define CAP   2048     // R3-verified: per-query candidate totals stay <= 2048
#define NSAMP 4096
#define RANK  24
#define EPS   3.0f     // rigorous |d_bf16 - d_exact| bound (analysis: <= ~2.2)
#define SLABS 256
#define BKT   24       // per-(q,slab) bucket capacity
#define TROWS 64
#define QROWS 128
#define LPAD  136      // bf16 row stride (272 B), keeps 16B alignment

typedef __attribute__((ext_vector_type(8))) short  short8;   // 8 bf16 (4 VGPRs)
typedef __attribute__((ext_vector_type(4))) float  floatx4;  // mfma acc
typedef unsigned long long u64;

__device__ inline unsigned short f2bf(float f) {   // RNE fp32 -> bf16
  unsigned u = __builtin_bit_cast(unsigned, f);
  unsigned r = u + 0x7fffu + ((u >> 16) & 1u);
  return (unsigned short)(r >> 16);
}
__device__ inline unsigned fkey(float f) {         // monotone float->uint
  unsigned u = __builtin_bit_cast(unsigned, f);
  unsigned m = (u & 0x80000000u) ? 0xFFFFFFFFu : 0x80000000u;
  return u ^ m;
}
__device__ inline float unfkey(unsigned k) {       // inverse
  unsigned u = (k & 0x80000000u) ? (k ^ 0x80000000u) : ~k;
  return __builtin_bit_cast(float, u);
}

// ---------------------------------------------------------------- k0: norms
__global__ __launch_bounds__(256) void k0_norms(
    const float* __restrict__ Q, const float* __restrict__ T, int M,
    float* __restrict__ qn, float* __restrict__ tn) {
  int gid = blockIdx.x * 256 + threadIdx.x;
  if (gid < M) {
    const float* r = T + (size_t)gid * ZD;
    float s = 0.f;
    #pragma unroll
    for (int z4 = 0; z4 < 32; ++z4) {
      float4 v = *(const float4*)&r[z4 * 4];
      s = fmaf(v.x, v.x, s); s = fmaf(v.y, v.y, s);
      s = fmaf(v.z, v.z, s); s = fmaf(v.w, v.w, s);
    }
    tn[gid] = s;
  } else if (gid < M + NQ) {
    int q = gid - M;
    const float* r = Q + (size_t)q * ZD;
    float s = 0.f;
    #pragma unroll
    for (int z4 = 0; z4 < 32; ++z4) {
      float4 v = *(const float4*)&r[z4 * 4];
      s = fmaf(v.x, v.x, s); s = fmaf(v.y, v.y, s);
      s = fmaf(v.z, v.z, s); s = fmaf(v.w, v.w, s);
    }
    qn[q] = s;
  }
}

// ---------------------------------------------------------------- k1a: sample distances via MFMA (k2-style)
__global__ __launch_bounds__(256) void k1a_mfma(
    const float* __restrict__ Q, const float* __restrict__ T,
    const float* __restrict__ qn, const float* __restrict__ tn,
    float* __restrict__ sd_g) {
  __shared__ short Ts[TROWS * LPAD];
  __shared__ short Qs[QROWS * LPAD];
  const int tid = threadIdx.x;
  const int m0 = blockIdx.x * TROWS;        // within [0, NSAMP)
  const int qbase = blockIdx.y * QROWS;

  #pragma unroll
  for (int it = 0; it < 16; ++it) {
    int li = tid + it * 256;
    int row = li >> 5, z4 = li & 31;
    float4 v = *(const float4*)&Q[(size_t)(qbase + row) * ZD + z4 * 4];
    unsigned lo = (unsigned)f2bf(v.x) | ((unsigned)f2bf(v.y) << 16);
    unsigned hi = (unsigned)f2bf(v.z) | ((unsigned)f2bf(v.w) << 16);
    *(uint2*)&Qs[row * LPAD + z4 * 4] = make_uint2(lo, hi);
  }
  #pragma unroll
  for (int it = 0; it < 8; ++it) {
    int li = tid + it * 256;
    int row = li >> 5, z4 = li & 31;
    float4 v = *(const float4*)&T[(size_t)(m0 + row) * ZD + z4 * 4];
    unsigned lo = (unsigned)f2bf(v.x) | ((unsigned)f2bf(v.y) << 16);
    unsigned hi = (unsigned)f2bf(v.z) | ((unsigned)f2bf(v.w) << 16);
    *(uint2*)&Ts[row * LPAD + z4 * 4] = make_uint2(lo, hi);
  }
  __syncthreads();

  const int wave = tid >> 6;
  const int lane = tid & 63;
  const int quad = lane >> 4;
  const int n16  = lane & 15;

  floatx4 acc[8];
  #pragma unroll
  for (int qt = 0; qt < 8; ++qt) acc[qt] = (floatx4)0.f;
  #pragma unroll
  for (int ks = 0; ks < 4; ++ks) {
    short8 a = *(const short8*)&Ts[(wave * 16 + n16) * LPAD + ks * 32 + quad * 8];
    #pragma unroll
    for (int qt = 0; qt < 8; ++qt) {
      short8 b = *(const short8*)&Qs[(qt * 16 + n16) * LPAD + ks * 32 + quad * 8];
      acc[qt] = __builtin_amdgcn_mfma_f32_16x16x32_bf16(a, b, acc[qt], 0, 0, 0);
    }
  }

  const int mbase = m0 + wave * 16 + quad * 4;
  const float4 tnv = *(const float4*)&tn[mbase];
  #pragma unroll
  for (int qt = 0; qt < 8; ++qt) {
    const int q = qbase + qt * 16 + n16;
    const float base = qn[q];
    float4 dv;
    dv.x = fmaf(-2.0f, acc[qt][0], base + tnv.x);
    dv.y = fmaf(-2.0f, acc[qt][1], base + tnv.y);
    dv.z = fmaf(-2.0f, acc[qt][2], base + tnv.z);
    dv.w = fmaf(-2.0f, acc[qt][3], base + tnv.w);
    *(float4*)&sd_g[(size_t)q * NSAMP + mbase] = dv;
  }
}

// ---------------------------------------------------------------- k1b: min + histogram -> per-query threshold
__global__ __launch_bounds__(256) void k1b_pick(
    const float* __restrict__ sd_g, float* __restrict__ thr) {
  __shared__ float red[256];
  __shared__ int   hist[256];
  const int q = blockIdx.x, tid = threadIdx.x;
  const float* sd = sd_g + (size_t)q * NSAMP;
  float vals[16];
  float lm = FLT_MAX;
  #pragma unroll
  for (int k = 0; k < 16; ++k) {
    vals[k] = sd[k * 256 + tid];
    lm = fminf(lm, vals[k]);
  }
  red[tid] = lm;
  hist[tid] = 0;
  __syncthreads();
  for (int o = 128; o > 0; o >>= 1) {
    if (tid < o) red[tid] = fminf(red[tid], red[tid + o]);
    __syncthreads();
  }
  const float dmin = red[0];
  __syncthreads();
  #pragma unroll
  for (int k = 0; k < 16; ++k) {
    int b = (int)((vals[k] - dmin) * 3.2f);   // bin width 0.3125 over [dmin, dmin+80]
    b = b < 0 ? 0 : (b > 255 ? 255 : b);
    atomicAdd(&hist[b], 1);
  }
  __syncthreads();
  if (tid == 0) {
    int cum = 0; float Tq = dmin + 80.0f;
    for (int b = 0; b < 256; ++b) {
      cum += hist[b];
      if (cum >= RANK) { Tq = dmin + (float)(b + 1) * 0.3125f; break; }
    }
    thr[q] = Tq;
  }
}

// ---------------------------------------------------------------- k2: bf16 MFMA filter, reg-prefetch dbuf
__global__ __launch_bounds__(256, 4) void k2_mfma(
    const float* __restrict__ Q, const float* __restrict__ T, int M, int slabn,
    const float* __restrict__ qn, const float* __restrict__ tn,
    const float* __restrict__ thr,
    int* __restrict__ cnt2, int* __restrict__ sure2, int* __restrict__ cand) {
  __shared__ short Ts[TROWS * LPAD];
  __shared__ short Qs[QROWS * LPAD];
  __shared__ int   lcnt[QROWS];
  __shared__ int   lsure[QROWS];
  __shared__ int   lent[QROWS * BKT];
  const int tid = threadIdx.x;
  const int slab = blockIdx.x;
  const int qbase = blockIdx.y * QROWS;
  const int sbeg = slab * slabn;
  const int send = min(sbeg + slabn, M);

  #pragma unroll
  for (int it = 0; it < 16; ++it) {
    int li = tid + it * 256;
    int row = li >> 5, z4 = li & 31;
    float4 v = *(const float4*)&Q[(size_t)(qbase + row) * ZD + z4 * 4];
    unsigned lo = (unsigned)f2bf(v.x) | ((unsigned)f2bf(v.y) << 16);
    unsigned hi = (unsigned)f2bf(v.z) | ((unsigned)f2bf(v.w) << 16);
    *(uint2*)&Qs[row * LPAD + z4 * 4] = make_uint2(lo, hi);
  }
  if (tid < QROWS) { lcnt[tid] = 0; lsure[tid] = 0; }

  const int wave = tid >> 6;
  const int lane = tid & 63;
  const int quad = lane >> 4;
  const int n16  = lane & 15;

  // hoisted per-thread invariants: q = qbase + qt*16 + n16 is loop-invariant
  float baseq[8], tqp[8], tqm[8];
  #pragma unroll
  for (int qt = 0; qt < 8; ++qt) {
    const int q = qbase + qt * 16 + n16;
    float b = qn[q], Tq = thr[q];
    baseq[qt] = b; tqp[qt] = Tq + EPS; tqm[qt] = Tq - EPS;
  }

  // register prefetch of first T tile (8 float4/thread)
  float4 pf[8];
  #pragma unroll
  for (int it = 0; it < 8; ++it) {
    int li = tid + it * 256;
    int row = li >> 5, z4 = li & 31;
    int m = sbeg + row;
    pf[it] = make_float4(0.f, 0.f, 0.f, 0.f);
    if (m < send) pf[it] = *(const float4*)&T[(size_t)m * ZD + z4 * 4];
  }

  for (int m0 = sbeg; m0 < send; m0 += TROWS) {
    __syncthreads();   // prev tile's readers done (and Qs published on iter 0)
    // commit prefetched tile: fp32->bf16 convert + LDS write
    #pragma unroll
    for (int it = 0; it < 8; ++it) {
      int li = tid + it * 256;
      int row = li >> 5, z4 = li & 31;
      unsigned lo = (unsigned)f2bf(pf[it].x) | ((unsigned)f2bf(pf[it].y) << 16);
      unsigned hi = (unsigned)f2bf(pf[it].z) | ((unsigned)f2bf(pf[it].w) << 16);
      *(uint2*)&Ts[row * LPAD + z4 * 4] = make_uint2(lo, hi);
    }
    __syncthreads();
    // issue next tile's global loads — overlap with MFMA below
    if (m0 + TROWS < send) {
      #pragma unroll
      for (int it = 0; it < 8; ++it) {
        int li = tid + it * 256;
        int row = li >> 5, z4 = li & 31;
        int m = m0 + TROWS + row;
        pf[it] = make_float4(0.f, 0.f, 0.f, 0.f);
        if (m < send) pf[it] = *(const float4*)&T[(size_t)m * ZD + z4 * 4];
      }
    }

    floatx4 acc[8];
    #pragma unroll
    for (int qt = 0; qt < 8; ++qt) acc[qt] = (floatx4)0.f;
    #pragma unroll
    for (int ks = 0; ks < 4; ++ks) {
      short8 a = *(const short8*)&Ts[(wave * 16 + n16) * LPAD + ks * 32 + quad * 8];
      #pragma unroll
      for (int qt = 0; qt < 8; ++qt) {
        short8 b = *(const short8*)&Qs[(qt * 16 + n16) * LPAD + ks * 32 + quad * 8];
        acc[qt] = __builtin_amdgcn_mfma_f32_16x16x32_bf16(a, b, acc[qt], 0, 0, 0);
      }
    }

    const int mbase = m0 + wave * 16 + quad * 4;
    float4 tnv = make_float4(0.f, 0.f, 0.f, 0.f);
    if (mbase + 3 < M) tnv = *(const float4*)&tn[mbase];
    else {
      if (mbase + 0 < M) tnv.x = tn[mbase + 0];
      if (mbase + 1 < M) tnv.y = tn[mbase + 1];
      if (mbase + 2 < M) tnv.z = tn[mbase + 2];
    }
    const float tns[4] = {tnv.x, tnv.y, tnv.z, tnv.w};
    #pragma unroll
    for (int qt = 0; qt < 8; ++qt) {
      const int ql = qt * 16 + n16;
      #pragma unroll
      for (int r = 0; r < 4; ++r) {
        const int m = mbase + r;
        float dap = fmaf(-2.0f, acc[qt][r], baseq[qt] + tns[r]);
        if (m < send && dap < tqp[qt]) {
          int pos = atomicAdd(&lcnt[ql], 1);
          if (pos < BKT) lent[ql * BKT + pos] = m;
          if (dap < tqm[qt]) atomicAdd(&lsure[ql], 1);
        }
      }
    }
  }
  __syncthreads();
  if (tid < QROWS) {
    cnt2 [(size_t)(qbase + tid) * SLABS + slab] = lcnt[tid];
    sure2[(size_t)(qbase + tid) * SLABS + slab] = lsure[tid];
  }
  for (int li = tid; li < QROWS * BKT; li += 256) {
    int ql = li / BKT, j = li % BKT;
    int c = lcnt[ql]; if (c > BKT) c = BKT;
    if (j < c)
      cand[((size_t)(qbase + ql) * SLABS + slab) * BKT + j] = lent[li];
  }
}

// ---------------------------------------------------------------- k3a: per-query slab scan + validity
__global__ __launch_bounds__(256) void k3a_scan(
    const int* __restrict__ cnt2, const int* __restrict__ sure2,
    int* __restrict__ scanx, int* __restrict__ totals, int* __restrict__ validf) {
  const int q = blockIdx.x, tid = threadIdx.x;
  __shared__ int sscan[256];
  __shared__ int ssure, sovf;
  int c = cnt2[(size_t)q * SLABS + tid];
  int su = sure2[(size_t)q * SLABS + tid];
  if (tid == 0) { ssure = 0; sovf = 0; }
  __syncthreads();
  atomicAdd(&ssure, su);
  if (c > BKT) atomicOr(&sovf, 1);
  int val = c;
  sscan[tid] = val;
  __syncthreads();
  for (int o = 1; o < 256; o <<= 1) {
    int add = (tid >= o) ? sscan[tid - o] : 0;
    __syncthreads();
    val += add;
    sscan[tid] = val;
    __syncthreads();
  }
  scanx[(size_t)q * SLABS + tid] = val - c;   // exclusive offset
  const int total = sscan[255];
  if (tid == 0) {
    totals[q] = total;
    validf[q] = (sovf == 0 && ssure >= KK && total <= CAP) ? 1 : 0;
  }
}

// ---------------------------------------------------------------- k3b: parallel exact rescore -> packed keys
__global__ __launch_bounds__(256) void k3b_rescore(
    const float* __restrict__ Q, const float* __restrict__ T,
    const float* __restrict__ qn, const float* __restrict__ tn,
    const int* __restrict__ cnt2, const int* __restrict__ cand,
    const int* __restrict__ scanx, const int* __restrict__ validf,
    u64* __restrict__ keys) {
  const int q = blockIdx.x, ch = blockIdx.y, tid = threadIdx.x;
  if (!validf[q]) return;                  // uniform
  __shared__ float qv[ZD];
  for (int z = tid; z < ZD; z += 256) qv[z] = Q[(size_t)q * ZD + z];
  __syncthreads();
  const float qnv = qn[q];
  const int slab = ch * 64 + (tid >> 2);
  const int lane = tid & 3;
  const int c = min(cnt2[(size_t)q * SLABS + slab], BKT);
  const int off = scanx[(size_t)q * SLABS + slab];
  for (int k = lane; k < c; k += 4) {
    int idx = cand[((size_t)q * SLABS + slab) * BKT + k];
    const float* r = T + (size_t)idx * ZD;
    float dot = 0.f;     // sequential fmaf chain — matches prior passing rescore
    #pragma unroll 4
    for (int z4 = 0; z4 < 32; ++z4) {
      float4 v = *(const float4*)&r[z4 * 4];
      dot = fmaf(qv[z4 * 4 + 0], v.x, dot);
      dot = fmaf(qv[z4 * 4 + 1], v.y, dot);
      dot = fmaf(qv[z4 * 4 + 2], v.z, dot);
      dot = fmaf(qv[z4 * 4 + 3], v.w, dot);
    }
    float d = fmaf(-2.0f, dot, qnv + tn[idx]);
    keys[(size_t)q * CAP + off + k] = ((u64)fkey(d) << 32) | (unsigned)idx;
  }
}

// ---------------------------------------------------------------- k3c: histogram-select + small sort + softmax
__global__ __launch_bounds__(256) void k3c_select(
    const float* __restrict__ Q, const float* __restrict__ T, int M,
    const float* __restrict__ qn, const float* __restrict__ tn,
    const int* __restrict__ totals, const int* __restrict__ validf,
    const u64* __restrict__ keys_g,
    int* __restrict__ topi, float* __restrict__ emit) {
  __shared__ u64 key[CAP];
  __shared__ u64 buf[256];
  __shared__ unsigned redA[256], redB[256];
  __shared__ int hist[256];
  __shared__ int hscan[256];
  __shared__ float qv[ZD];
  __shared__ float cd[256];
  __shared__ float sdF[KK];
  __shared__ int   siF[KK];
  __shared__ float ebuf[KK];
  __shared__ float ssum;
  __shared__ int Bb, C2, ccnt, srcFlag;
  __shared__ unsigned kminS; __shared__ int shiftS;
  const int q = blockIdx.x, tid = threadIdx.x;
  const int total = totals[q];
  const bool valid = validf[q] != 0;

  if (valid) {
    for (int i = tid; i < CAP; i += 256)
      key[i] = (i < total) ? keys_g[(size_t)q * CAP + i] : ~0ULL;
    unsigned lmin = 0xFFFFFFFFu, lmax = 0u;
    for (int i = tid; i < total; i += 256) {
      unsigned h = (unsigned)(key[i] >> 32);
      lmin = min(lmin, h); lmax = max(lmax, h);
    }
    redA[tid] = lmin; redB[tid] = lmax;
    hist[tid] = 0;
    __syncthreads();
    for (int o = 128; o > 0; o >>= 1) {
      if (tid < o) {
        redA[tid] = min(redA[tid], redA[tid + o]);
        redB[tid] = max(redB[tid], redB[tid + o]);
      }
      __syncthreads();
    }
    if (tid == 0) {
      unsigned range = redB[0] - redA[0];
      int s = 0;
      while ((range >> s) > 255u) ++s;
      kminS = redA[0]; shiftS = s;
      ccnt = 0;
    }
    __syncthreads();
    const unsigned kmin = kminS; const int sh = shiftS;
    for (int i = tid; i < total; i += 256) {
      int b = (int)(((unsigned)(key[i] >> 32) - kmin) >> sh);
      atomicAdd(&hist[b], 1);
    }
    __syncthreads();
    int v0 = hist[tid];
    hscan[tid] = v0;
    __syncthreads();
    for (int o = 1; o < 256; o <<= 1) {
      int add = (tid >= o) ? hscan[tid - o] : 0;
      __syncthreads();
      v0 += add;
      hscan[tid] = v0;
      __syncthreads();
    }
    if (hscan[tid] >= KK && (tid == 0 || hscan[tid - 1] < KK)) {
      Bb = tid; C2 = hscan[tid];
    }
    __syncthreads();
    const int B = Bb, c2 = C2;
    if (c2 <= 256) {
      for (int i = tid; i < total; i += 256) {
        int b = (int)(((unsigned)(key[i] >> 32) - kmin) >> sh);
        if (b <= B) { int pos = atomicAdd(&ccnt, 1); buf[pos] = key[i]; }
      }
      __syncthreads();
      if (tid >= c2) buf[tid] = ~0ULL;
      __syncthreads();
      for (int k = 2; k <= 256; k <<= 1) {
        for (int j = k >> 1; j > 0; j >>= 1) {
          int x = tid ^ j;
          if (x > tid) {
            u64 a = buf[tid], b2 = buf[x];
            bool asc = ((tid & k) == 0);
            if ((a > b2) == asc) { buf[tid] = b2; buf[x] = a; }
          }
          __syncthreads();
        }
      }
      if (tid == 0) srcFlag = 0;
    } else {
      for (int k = 2; k <= CAP; k <<= 1) {
        for (int j = k >> 1; j > 0; j >>= 1) {
          for (int t = tid; t < CAP; t += 256) {
            int x = t ^ j;
            if (x > t) {
              u64 a = key[t], b2 = key[x];
              bool asc = ((t & k) == 0);
              if ((a > b2) == asc) { key[t] = b2; key[x] = a; }
            }
          }
          __syncthreads();
        }
      }
      if (tid == 0) srcFlag = 1;
    }
    __syncthreads();
  } else {
    // brute-force exact fallback (correctness net; ~never taken)
    for (int z = tid; z < ZD; z += 256) qv[z] = Q[(size_t)q * ZD + z];
    if (tid == 0) {
      for (int k = 0; k < KK; ++k) { sdF[k] = FLT_MAX; siF[k] = INT_MAX; }
      srcFlag = 0;
    }
    __syncthreads();
    const float qnv = qn[q];
    for (int base = 0; base < M; base += 256) {
      int m = base + tid; float d = FLT_MAX;
      if (m < M) {
        const float* r = T + (size_t)m * ZD;
        float dot = 0.f;
        for (int z = 0; z < ZD; ++z) dot = fmaf(qv[z], r[z], dot);
        d = fmaf(-2.0f, dot, qnv + tn[m]);
      }
      cd[tid] = d;
      __syncthreads();
      if (tid == 0) {
        for (int e = 0; e < 256; ++e) {
          float dd = cd[e]; int mm = base + e;
          if (dd < sdF[KK - 1] || (dd == sdF[KK - 1] && mm < siF[KK - 1])) {
            int pos = KK - 1;
            while (pos > 0 && (sdF[pos - 1] > dd || (sdF[pos - 1] == dd && siF[pos - 1] > mm))) {
              sdF[pos] = sdF[pos - 1]; siF[pos] = siF[pos - 1]; --pos;
            }
            sdF[pos] = dd; siF[pos] = mm;
          }
        }
      }
      __syncthreads();
    }
    if (tid < KK) buf[tid] = ((u64)fkey(sdF[tid]) << 32) | (unsigned)siF[tid];
    __syncthreads();
  }

  const int sf = srcFlag;
  if (tid == 0) {
    u64 k0v = sf ? key[0] : buf[0];
    float d0 = unfkey((unsigned)(k0v >> 32));
    float sum = 0.f;
    for (int k = 0; k < KK; ++k) {
      u64 kk = sf ? key[k] : buf[k];
      float e = expf(d0 - unfkey((unsigned)(kk >> 32)));
      ebuf[k] = e; sum += e;
    }
    ssum = sum;
  }
  __syncthreads();
  if (tid < KK) {
    u64 kk = sf ? key[tid] : buf[tid];
    emit[(size_t)q * KK + tid] = ebuf[tid] / ssum;
    topi[(size_t)q * KK + tid] = (int)(kk & 0xFFFFFFFFu);
  }
}

// ---------------------------------------------------------------- k4: transitions — full 256-thread, 7x7 reg tiles
__global__ __launch_bounds__(256) void k4_trans(
    const float* __restrict__ T, const int* __restrict__ topi,
    float* __restrict__ trans) {
  const int bt = blockIdx.x;                 // 0..251
  const int b = bt / (NT - 1), t = bt % (NT - 1);
  const int* iA = topi + (size_t)(b * NT + t) * KK;
  const int* iB = topi + (size_t)(b * NT + t + 1) * KK;
  __shared__ float As[KK * 132];             // 52.8 KB
  __shared__ float Bs[KK * 132];             // 52.8 KB (1 block/CU anyway: grid=252)
  __shared__ float an[KK];
  __shared__ float bn[KK];
  const int tid = threadIdx.x;
  for (int li = tid; li < KK * 32; li += 256) {
    int row = li >> 5, z4 = li & 31;
    *(float4*)&As[row * 132 + z4 * 4] = *(const float4*)&T[(size_t)iA[row] * ZD + z4 * 4];
    *(float4*)&Bs[row * 132 + z4 * 4] = *(const float4*)&T[(size_t)iB[row] * ZD + z4 * 4];
  }
  __syncthreads();
  if (tid < KK) {                            // same sequential-z chain as before
    float s = 0.f;
    for (int z = 0; z < ZD; ++z) s = fmaf(As[tid * 132 + z], As[tid * 132 + z], s);
    an[tid] = s;
  } else if (tid < 2 * KK) {
    int r = tid - KK;
    float s = 0.f;
    for (int z = 0; z < ZD; ++z) s = fmaf(Bs[r * 132 + z], Bs[r * 132 + z], s);
    bn[r] = s;
  }
  __syncthreads();
  const int tx = tid & 15, ty = tid >> 4;    // 16x16 grid; rows ty+16k, cols tx+16m (k,m<7)
  float acc[7][7];
  #pragma unroll
  for (int k = 0; k < 7; ++k)
    #pragma unroll
    for (int m = 0; m < 7; ++m) acc[k][m] = 0.f;
  int rr[7], cc[7];
  #pragma unroll
  for (int k = 0; k < 7; ++k) { rr[k] = min(ty + 16 * k, KK - 1); cc[k] = min(tx + 16 * k, KK - 1); }
  for (int z4 = 0; z4 < 32; ++z4) {
    float4 a[7], bb[7];
    #pragma unroll
    for (int k = 0; k < 7; ++k) a[k] = *(const float4*)&As[rr[k] * 132 + z4 * 4];
    #pragma unroll
    for (int m = 0; m < 7; ++m) bb[m] = *(const float4*)&Bs[cc[m] * 132 + z4 * 4];
    #pragma unroll
    for (int k = 0; k < 7; ++k)
      #pragma unroll
      for (int m = 0; m < 7; ++m) {         // sequential-z fmaf order preserved
        acc[k][m] = fmaf(a[k].x, bb[m].x, acc[k][m]);
        acc[k][m] = fmaf(a[k].y, bb[m].y, acc[k][m]);
        acc[k][m] = fmaf(a[k].z, bb[m].z, acc[k][m]);
        acc[k][m] = fmaf(a[k].w, bb[m].w, acc[k][m]);
      }
  }
  float* trow = trans + (size_t)bt * KK * KK;
  #pragma unroll
  for (int k = 0; k < 7; ++k) {
    int r = ty + 16 * k;
    if (r < KK) {
      #pragma unroll
      for (int m = 0; m < 7; ++m) {
        int c = tx + 16 * m;
        if (c < KK) {
          float d = fmaf(-2.0f, acc[k][m], an[r] + bn[c]);
          trow[r * KK + c] = expf(-d);
        }
      }
    }
  }
}

// ---------------------------------------------------------------- k5: Viterbi (prefetch + LDS backptrs + zflag fast-exit)
__global__ __launch_bounds__(256) void k5_viterbi(
    const float* __restrict__ T, const int* __restrict__ topi,
    const float* __restrict__ emit, const float* __restrict__ trans,
    float* __restrict__ out) {
  const int b = blockIdx.x, tid = threadIdx.x;
  __shared__ float trS[KK * KK];
  __shared__ float v[KK], vn[KK];
  __shared__ float pb[200];
  __shared__ int   pi[200];
  __shared__ int   bpS[(NT - 1) * KK];   // 25.2 KB backptrs in LDS
  __shared__ int   path[NT];
  __shared__ float maxsh;
  __shared__ int   zflag;

  float4 r[10];
  {
    const float* tr0 = trans + (size_t)(b * (NT - 1)) * KK * KK;
    #pragma unroll
    for (int i = 0; i < 10; ++i) {
      int li = tid + i * 256;
      if (li < 2500) r[i] = *(const float4*)&tr0[li * 4];
    }
  }
  if (tid < KK) v[tid] = emit[(size_t)(b * NT) * KK + tid];
  if (tid == 0) zflag = 0;
  __syncthreads();

  for (int t = 1; t < NT; ++t) {
    // commit prefetched tile (t-1) to LDS
    #pragma unroll
    for (int i = 0; i < 10; ++i) {
      int li = tid + i * 256;
      if (li < 2500) *(float4*)&trS[li * 4] = r[i];
    }
    __syncthreads();
    if (t < NT - 1) {
      const float* trn = trans + (size_t)(b * (NT - 1) + t) * KK * KK;
      #pragma unroll
      for (int i = 0; i < 10; ++i) {
        int li = tid + i * 256;
        if (li < 2500) r[i] = *(const float4*)&trn[li * 4];
      }
    }
    if (tid < 200) {
      const int j = tid % 100, half = tid / 100;
      const int ia = half * 50, ibnd = ia + 50;
      float best = -FLT_MAX; int bi = ia;
      for (int i = ia; i < ibnd; ++i) {
        float s = v[i] * trS[i * KK + j];
        if (s > best) { best = s; bi = i; }     // strict > == argmax-first
      }
      pb[tid] = best; pi[tid] = bi;
    }
    __syncthreads();
    if (tid < KK) {
      float b0 = pb[tid], b1 = pb[100 + tid];
      int   i0 = pi[tid], i1 = pi[100 + tid];
      float best = b0; int bi = i0;
      if (b1 > b0) { best = b1; bi = i1; }      // half-1 indices all larger
      vn[tid] = best * emit[(size_t)(b * NT + t) * KK + tid];
      bpS[(t - 1) * KK + tid] = bi;
    }
    __syncthreads();
    if (tid == 0) {
      float m = vn[0];
      for (int j = 1; j < KK; ++j) m = fmaxf(m, vn[j]);
      maxsh = m;
      if (m == 0.0f) zflag = 1;   // all-zero v is absorbing
    }
    __syncthreads();
    if (tid < KK) v[tid] = vn[tid] / fmaxf(maxsh, 1e-30f);
    __syncthreads();
    if (zflag) {
      // v == 0 everywhere from here on: every remaining step writes backp=0 and
      // leaves v at 0 (scores all +0, strict > fires only at i=0) — bulk-fill & exit.
      for (int li = tid; li < (NT - 1 - t) * KK; li += 256)
        bpS[t * KK + li] = 0;
      __syncthreads();
      break;
    }
  }
  if (tid == 0) {
    float best = -FLT_MAX; int last = 0;
    for (int j = 0; j < KK; ++j) if (v[j] > best) { best = v[j]; last = j; }
    path[NT - 1] = last;
    for (int tt = NT - 2; tt >= 0; --tt)
      path[tt] = bpS[tt * KK + path[tt + 1]];
  }
  __syncthreads();
  for (int li = tid; li < NT * ZD; li += 256) {
    int t = li >> 7, z = li & 127;
    out[(size_t)(b * NT + t) * ZD + z] =
        T[(size_t)topi[(size_t)(b * NT + t) * KK + path[t]] * ZD + z];
  }
}

// ---------------------------------------------------------------- host
extern "C" void kernel_launch(void* const* d_in, const int* in_sizes, int n_in,
                              void* d_out, int out_size, void* d_ws, size_t ws_size,
                              hipStream_t stream) {
  const float* Q = (const float*)d_in[0];     // (4,64,128) fp32
  const float* T = (const float*)d_in[1];     // (100000,128) fp32
  float* out = (float*)d_out;                 // (4,64,128) fp32
  const int M = in_sizes[1] / ZD;
  const int slabn = (M + SLABS - 1) / SLABS;  // 391 for M=100000

  char* p = (char*)d_ws;
  auto alloc = [&](size_t bytes) -> char* {
    char* r = p; p += (bytes + 511) & ~(size_t)511; return r;
  };
  float* qn     = (float*)alloc((size_t)NQ * 4);
  float* tn     = (float*)alloc((size_t)M * 4);
  float* thr    = (float*)alloc((size_t)NQ * 4);
  float* sd_g   = (float*)alloc((size_t)NQ * NSAMP * 4);
  int*   cnt2   = (int*)  alloc((size_t)NQ * SLABS * 4);
  int*   sure2  = (int*)  alloc((size_t)NQ * SLABS * 4);
  int*   cand   = (int*)  alloc((size_t)NQ * SLABS * BKT * 4);
  int*   scanx  = (int*)  alloc((size_t)NQ * SLABS * 4);
  int*   totals = (int*)  alloc((size_t)NQ * 4);
  int*   validf = (int*)  alloc((size_t)NQ * 4);
  u64*   keys   = (u64*)  alloc((size_t)NQ * CAP * 8);
  int*   topi   = (int*)  alloc((size_t)NQ * KK * 4);
  float* emit   = (float*)alloc((size_t)NQ * KK * 4);
  float* trans  = (float*)alloc((size_t)NB * (NT - 1) * KK * KK * 4);

  const int g0 = (M + NQ + 255) / 256;
  k0_norms<<<g0, 256, 0, stream>>>(Q, T, M, qn, tn);
  dim3 g1a(NSAMP / TROWS, NQ / QROWS);
  k1a_mfma<<<g1a, 256, 0, stream>>>(Q, T, qn, tn, sd_g);
  k1b_pick<<<NQ, 256, 0, stream>>>(sd_g, thr);
  dim3 g2(SLABS, NQ / QROWS);
  k2_mfma<<<g2, 256, 0, stream>>>(Q, T, M, slabn, qn, tn, thr, cnt2, sure2, cand);
  k3a_scan<<<NQ, 256, 0, stream>>>(cnt2, sure2, scanx, totals, validf);
  dim3 g3b(NQ, 4);
  k3b_rescore<<<g3b, 256, 0, stream>>>(Q, T, qn, tn, cnt2, cand, scanx, validf, keys);
  k3c_select<<<NQ, 256, 0, stream>>>(Q, T, M, qn, tn, totals, validf, keys, topi, emit);
  k4_trans<<<NB * (NT - 1), 256, 0, stream>>>(T, topi, trans);
  k5_viterbi<<<NB, 256, 0, stream>>>(T, topi, emit, trans, out);
}